// Round 1
// baseline (5144.453 us; speedup 1.0000x reference)
//
#include <hip/hip_runtime.h>

// SSHA block, fp32 baseline implementation.
// Shapes: N=16, T=288, V=25, C=128, S=8, IC=16, W=3, U=W*V=75, TP=T+2=290.
// Data layout everywhere: [n][t][v][c] with c contiguous (matches input x and output).
//
// Pipeline:
//  k_qk      : kfull[n,t,v,128]=conv1x1(x,w_k)+b_k ; qfull[n,tp,v,128] (tp=0..289, pad rows = b_q)
//  k_scores  : partial[n,s,tc,u,v] = sum over 32-t chunk of q.k   (9 chunks)
//  k_softmax : att[n,s,u,v] = softmax_u(sum partial /4608)*alpha_s + att0
//  k_attn_out: per (n,t): Y_s[c,v]=sum_u X[u,c]A_s[u,v]; O[o,v]+=sum_c W_s[o,c]Y_s[c,v];
//              y1 = leaky(x + BN(O + b_out))
//  k_ff      : y2 = leaky(x + BN(conv1x1(y1,w_ff)+b_ff))
//  k_wt_tr   : transpose w_t (C,C,7) -> (7,C,C) for coalesced staging
//  k_tconv   : z = BN(tconv7(y2)+b_t); z = leaky(y2+z); out = relu(z+x)

#define NN 16
#define TT 288
#define VV 25
#define CC 128
#define SS 8
#define UU 75
#define TP 290
#define EPSF 1e-5f

static __device__ __forceinline__ void fma4(float4& a, float s, const float4 b) {
  a.x += s * b.x; a.y += s * b.y; a.z += s * b.z; a.w += s * b.w;
}

// ---------------- K1: k/q 1x1 convs ----------------
// grid 3625, block 256. Covers q-row space (n,tp,v), 32 rows/block.
__global__ __launch_bounds__(256) void k_qk(
    const float* __restrict__ x,
    const float* __restrict__ w_k, const float* __restrict__ b_k,
    const float* __restrict__ w_q, const float* __restrict__ b_q,
    float* __restrict__ kfull, float* __restrict__ qfull) {
  __shared__ float wk[128 * 129];
  __shared__ float wq[128 * 129];
  __shared__ float xt[128 * 36];  // x rows transposed [c][r], pad 36
  const int tid = threadIdx.x;
  for (int i = tid; i < 128 * 128; i += 256) {
    int o = i >> 7, c = i & 127;
    wk[o * 129 + c] = w_k[i];
    wq[o * 129 + c] = w_q[i];
  }
  const int base = blockIdx.x * 32;
  for (int i = tid; i < 32 * 128; i += 256) {
    int r = i >> 7, c = i & 127;
    int row = base + r;
    int n = row / (TP * VV);
    int rem = row - n * (TP * VV);
    int tp = rem / VV, v = rem - tp * VV;
    float val = 0.f;
    if (tp >= 1 && tp <= TT) val = x[(((n * TT + (tp - 1)) * VV + v) << 7) + c];
    xt[c * 36 + r] = val;
  }
  __syncthreads();
  const int o = tid & 127;
  const int rh = tid >> 7;  // row half: rows rh*16 .. rh*16+15
  float acck[16], accq[16];
#pragma unroll
  for (int r = 0; r < 16; ++r) { acck[r] = 0.f; accq[r] = 0.f; }
  const float* wkp = wk + o * 129;
  const float* wqp = wq + o * 129;
  for (int c = 0; c < 128; ++c) {
    float wv0 = wkp[c];
    float wv1 = wqp[c];
    const float4* xp = (const float4*)(xt + c * 36 + rh * 16);
#pragma unroll
    for (int r4 = 0; r4 < 4; ++r4) {
      float4 xv = xp[r4];
      acck[r4 * 4 + 0] += wv0 * xv.x; acck[r4 * 4 + 1] += wv0 * xv.y;
      acck[r4 * 4 + 2] += wv0 * xv.z; acck[r4 * 4 + 3] += wv0 * xv.w;
      accq[r4 * 4 + 0] += wv1 * xv.x; accq[r4 * 4 + 1] += wv1 * xv.y;
      accq[r4 * 4 + 2] += wv1 * xv.z; accq[r4 * 4 + 3] += wv1 * xv.w;
    }
  }
  const float bk = b_k[o], bq = b_q[o];
  for (int r = 0; r < 16; ++r) {
    int row = base + rh * 16 + r;
    int n = row / (TP * VV);
    int rem = row - n * (TP * VV);
    int tp = rem / VV, v = rem - tp * VV;
    qfull[(((n * TP + tp) * VV + v) << 7) + o] = accq[r] + bq;
    if (tp >= 1 && tp <= TT)
      kfull[(((n * TT + (tp - 1)) * VV + v) << 7) + o] = acck[r] + bk;
  }
}

// ---------------- K2a: partial scores ----------------
// grid (9, 8, 16) = (t-chunk, s, n), block 128.
__global__ __launch_bounds__(128) void k_scores(
    const float* __restrict__ kfull, const float* __restrict__ qfull,
    float* __restrict__ partial) {
  __shared__ float kl[32 * 16 * 28];  // [tt][ic][v pad28]
  __shared__ float ql[34 * 25 * 17];  // [tt][vp][ic pad17]
  const int tc = blockIdx.x, s = blockIdx.y, n = blockIdx.z;
  const int t0 = tc * 32;
  const int tid = threadIdx.x;
  for (int i = tid; i < 32 * 16 * 28; i += 128) {
    int tt = i / 448;
    int rem = i - tt * 448;
    int ic = rem / 28, v = rem - ic * 28;
    float val = 0.f;
    if (v < 25) val = kfull[(((n * TT + t0 + tt) * VV + v) << 7) + s * 16 + ic];
    kl[i] = val;
  }
  for (int i = tid; i < 34 * 25 * 16; i += 128) {
    int tt = i / 400;
    int rem = i - tt * 400;
    int vp = rem >> 4, ic = rem & 15;
    ql[(tt * 25 + vp) * 17 + ic] =
        qfull[(((n * TP + t0 + tt) * VV + vp) << 7) + s * 16 + ic];
  }
  __syncthreads();
  if (tid < 75) {
    const int w = tid / 25, vp = tid - w * 25;
    float4 acc[7];
#pragma unroll
    for (int j = 0; j < 7; ++j) acc[j] = make_float4(0.f, 0.f, 0.f, 0.f);
    for (int tt = 0; tt < 32; ++tt) {
      const float* qp = ql + ((tt + w) * 25 + vp) * 17;
      const float* kb = kl + tt * 448;
#pragma unroll
      for (int ic = 0; ic < 16; ++ic) {
        float qv = qp[ic];
        const float4* kq = (const float4*)(kb + ic * 28);
#pragma unroll
        for (int j = 0; j < 7; ++j) fma4(acc[j], qv, kq[j]);
      }
    }
    float av[28];
#pragma unroll
    for (int j = 0; j < 7; ++j) *(float4*)(av + 4 * j) = acc[j];
    float* op = partial + ((((n * SS + s) * 9 + tc) * UU) + tid) * VV;
#pragma unroll
    for (int v = 0; v < 25; ++v) op[v] = av[v];
  }
}

// ---------------- K2b: reduce + softmax + att ----------------
// grid 128 (n*S+s), block 128.
__global__ __launch_bounds__(128) void k_softmax(
    const float* __restrict__ partial, const float* __restrict__ alphas,
    const float* __restrict__ att0, float* __restrict__ att) {
  __shared__ float sc[1875];
  __shared__ float mx[25];
  __shared__ float den[25];
  const int ns = blockIdx.x;
  const int s = ns & 7;
  const int tid = threadIdx.x;
  const float inv = 1.0f / 4608.0f;  // 1/(IC*T)
  for (int i = tid; i < 1875; i += 128) {
    float a = 0.f;
    const float* p = partial + ns * 9 * 1875 + i;
#pragma unroll
    for (int j = 0; j < 9; ++j) a += p[j * 1875];
    sc[i] = a * inv;
  }
  __syncthreads();
  if (tid < 25) {
    float m = -1e30f;
    for (int u = 0; u < 75; ++u) m = fmaxf(m, sc[u * 25 + tid]);
    float d = 0.f;
    for (int u = 0; u < 75; ++u) d += expf(sc[u * 25 + tid] - m);
    mx[tid] = m;
    den[tid] = d;
  }
  __syncthreads();
  const float alpha = alphas[s];
  for (int i = tid; i < 1875; i += 128) {
    int v = i % 25;
    att[ns * 1875 + i] = expf(sc[i] - mx[v]) / den[v] * alpha + att0[s * 1875 + i];
  }
}

// ---------------- K3: attention-apply + out conv + BN + leaky residual ----------------
// grid (288, 16), block 256.
__global__ __launch_bounds__(256) void k_attn_out(
    const float* __restrict__ x, const float* __restrict__ att,
    const float* __restrict__ w_out, const float* __restrict__ b_out,
    const float* __restrict__ g_out, const float* __restrict__ beta_out,
    const float* __restrict__ m_out, const float* __restrict__ v_out,
    float* __restrict__ y1) {
  __shared__ float xs[75 * 128];   // [u][c]
  __shared__ float al[75 * 32];    // [u][v pad32] zero-padded
  __shared__ float yl[128 * 36];   // [c][v pad36]
  __shared__ float wl[128 * 129];  // [o][c pad129]
  const int t = blockIdx.x, n = blockIdx.y;
  const int tid = threadIdx.x;
  for (int i = tid; i < 75 * 128; i += 256) {
    int u = i >> 7, c = i & 127;
    int w = u / 25, vp = u - w * 25;
    int tr = t + w - 1;
    float val = 0.f;
    if (tr >= 0 && tr < TT) val = x[(((n * TT + tr) * VV + vp) << 7) + c];
    xs[i] = val;
  }
  const int l2 = tid & 63;  // c2 in Y-phase, o2 in out-phase
  const int h = tid >> 6;   // quad-pair group: v in [8h, 8h+8)
  float4 oacc[2][2];
  oacc[0][0] = make_float4(0, 0, 0, 0); oacc[0][1] = make_float4(0, 0, 0, 0);
  oacc[1][0] = make_float4(0, 0, 0, 0); oacc[1][1] = make_float4(0, 0, 0, 0);
  for (int s = 0; s < SS; ++s) {
    __syncthreads();  // protect al/wl/yl from previous iteration's readers
    for (int i = tid; i < 75 * 32; i += 256) {
      int u = i >> 5, v = i & 31;
      al[i] = (v < 25) ? att[(((n * SS + s) * UU) + u) * VV + v] : 0.f;
    }
    for (int i = tid; i < 128 * 128; i += 256) {
      int o = i >> 7, c = i & 127;
      wl[o * 129 + c] = w_out[(o << 10) + (s << 7) + c];
    }
    __syncthreads();
    // Y phase: Y[c,v] = sum_u X[u,c]*A[u,v]; this thread: c in {l2, l2+64}, quads {2h,2h+1}
    {
      float4 ya00 = make_float4(0, 0, 0, 0), ya01 = make_float4(0, 0, 0, 0);
      float4 ya10 = make_float4(0, 0, 0, 0), ya11 = make_float4(0, 0, 0, 0);
      for (int u = 0; u < 75; ++u) {
        float xv0 = xs[(u << 7) + l2];
        float xv1 = xs[(u << 7) + l2 + 64];
        const float4* ap = (const float4*)(al + (u << 5)) + 2 * h;
        float4 a0 = ap[0], a1 = ap[1];
        fma4(ya00, xv0, a0); fma4(ya01, xv0, a1);
        fma4(ya10, xv1, a0); fma4(ya11, xv1, a1);
      }
      *(float4*)(yl + l2 * 36 + h * 8) = ya00;
      *(float4*)(yl + l2 * 36 + h * 8 + 4) = ya01;
      *(float4*)(yl + (l2 + 64) * 36 + h * 8) = ya10;
      *(float4*)(yl + (l2 + 64) * 36 + h * 8 + 4) = ya11;
    }
    __syncthreads();
    // out phase: O[o,v] += sum_c W_s[o,c]*Y[c,v]; o in {l2, l2+64}, same quads
    const float* w0 = wl + l2 * 129;
    const float* w1 = wl + (l2 + 64) * 129;
    for (int c = 0; c < 128; ++c) {
      float wv0 = w0[c], wv1 = w1[c];
      const float4* yp = (const float4*)(yl + c * 36) + 2 * h;
      float4 yq0 = yp[0], yq1 = yp[1];
      fma4(oacc[0][0], wv0, yq0); fma4(oacc[0][1], wv0, yq1);
      fma4(oacc[1][0], wv1, yq0); fma4(oacc[1][1], wv1, yq1);
    }
  }
  // epilogue: BN + leaky(x + .)
#pragma unroll
  for (int oi = 0; oi < 2; ++oi) {
    int o = l2 + 64 * oi;
    float scale = g_out[o] * rsqrtf(v_out[o] + EPSF);
    float sh = beta_out[o] - m_out[o] * scale;
    float bb = b_out[o];
    float av[8];
    *(float4*)(av) = oacc[oi][0];
    *(float4*)(av + 4) = oacc[oi][1];
#pragma unroll
    for (int j = 0; j < 8; ++j) {
      int v = 8 * h + j;
      if (v < 25) {
        float a = (av[j] + bb) * scale + sh;
        int idx = (((n * TT + t) * VV + v) << 7) + o;
        float r = x[idx] + a;
        y1[idx] = r > 0.f ? r : 0.1f * r;
      }
    }
  }
}

// ---------------- K4: ff conv + BN + leaky residual ----------------
// grid 3600, block 256.
__global__ __launch_bounds__(256) void k_ff(
    const float* __restrict__ y1, const float* __restrict__ x,
    const float* __restrict__ w_ff, const float* __restrict__ b_ff,
    const float* __restrict__ g_ff, const float* __restrict__ beta_ff,
    const float* __restrict__ m_ff, const float* __restrict__ v_ff,
    float* __restrict__ y2) {
  __shared__ float wl[128 * 129];
  __shared__ float yt[128 * 36];
  const int tid = threadIdx.x;
  for (int i = tid; i < 128 * 128; i += 256)
    wl[(i >> 7) * 129 + (i & 127)] = w_ff[i];
  const int base = blockIdx.x * 32;
  for (int i = tid; i < 32 * 128; i += 256) {
    int r = i >> 7, c = i & 127;
    yt[c * 36 + r] = y1[((base + r) << 7) + c];
  }
  __syncthreads();
  const int o2 = tid & 63;
  const int rq = tid >> 6;  // row quarter: rows rq*8 .. rq*8+7
  float acc[2][8];
#pragma unroll
  for (int i = 0; i < 8; ++i) { acc[0][i] = 0.f; acc[1][i] = 0.f; }
  const float* w0 = wl + o2 * 129;
  const float* w1 = wl + (o2 + 64) * 129;
  for (int c = 0; c < 128; ++c) {
    float wv0 = w0[c], wv1 = w1[c];
    const float4* yp = (const float4*)(yt + c * 36 + rq * 8);
    float4 a = yp[0], b = yp[1];
    acc[0][0] += wv0 * a.x; acc[0][1] += wv0 * a.y; acc[0][2] += wv0 * a.z; acc[0][3] += wv0 * a.w;
    acc[0][4] += wv0 * b.x; acc[0][5] += wv0 * b.y; acc[0][6] += wv0 * b.z; acc[0][7] += wv0 * b.w;
    acc[1][0] += wv1 * a.x; acc[1][1] += wv1 * a.y; acc[1][2] += wv1 * a.z; acc[1][3] += wv1 * a.w;
    acc[1][4] += wv1 * b.x; acc[1][5] += wv1 * b.y; acc[1][6] += wv1 * b.z; acc[1][7] += wv1 * b.w;
  }
#pragma unroll
  for (int oi = 0; oi < 2; ++oi) {
    int o = o2 + 64 * oi;
    float scale = g_ff[o] * rsqrtf(v_ff[o] + EPSF);
    float sh = beta_ff[o] - m_ff[o] * scale;
    float bb = b_ff[o];
#pragma unroll
    for (int r = 0; r < 8; ++r) {
      int row = base + rq * 8 + r;
      float a = (acc[oi][r] + bb) * scale + sh;
      float rr = x[(row << 7) + o] + a;
      y2[(row << 7) + o] = rr > 0.f ? rr : 0.1f * rr;
    }
  }
}

// ---------------- K5a: transpose w_t -> [kt][o][c] ----------------
__global__ __launch_bounds__(256) void k_wt_tr(const float* __restrict__ w_t,
                                               float* __restrict__ wt_tr) {
  int i = blockIdx.x * 256 + threadIdx.x;
  if (i < 128 * 128 * 7) {
    int o = i / 896;
    int rem = i - o * 896;
    int c = rem / 7, kt = rem - c * 7;
    wt_tr[(kt * 128 + o) * 128 + c] = w_t[i];
  }
}

// ---------------- K5: temporal conv 7x1 + BN + leaky + relu residual ----------------
// grid (144, 16), block 128: two t per block.
__global__ __launch_bounds__(128) void k_tconv(
    const float* __restrict__ y2, const float* __restrict__ x,
    const float* __restrict__ wt_tr, const float* __restrict__ b_t,
    const float* __restrict__ g_t, const float* __restrict__ beta_t,
    const float* __restrict__ m_t, const float* __restrict__ v_t,
    float* __restrict__ out) {
  __shared__ float wl[128 * 129];
  __shared__ float yt[2 * 128 * 36];  // [th][c][v pad36]
  const int t0 = blockIdx.x * 2, n = blockIdx.y;
  const int tid = threadIdx.x;
  const int o2 = tid & 63;
  const int th = tid >> 6;
  float4 acc[2][7];
#pragma unroll
  for (int oi = 0; oi < 2; ++oi)
#pragma unroll
    for (int j = 0; j < 7; ++j) acc[oi][j] = make_float4(0, 0, 0, 0);
  for (int kt = 0; kt < 7; ++kt) {
    __syncthreads();
    for (int i = tid; i < 128 * 128; i += 128)
      wl[(i >> 7) * 129 + (i & 127)] = wt_tr[kt * 16384 + i];
    for (int i = tid; i < 2 * 28 * 128; i += 128) {
      int thh = i / 3584;
      int rem = i - thh * 3584;
      int v = rem >> 7, c = rem & 127;
      int tr = t0 + thh + kt - 3;
      float val = 0.f;
      if (v < 25 && tr >= 0 && tr < TT)
        val = y2[(((n * TT + tr) * VV + v) << 7) + c];
      yt[(thh * 128 + c) * 36 + v] = val;
    }
    __syncthreads();
    const float* w0 = wl + o2 * 129;
    const float* w1 = wl + (o2 + 64) * 129;
    const float* yb = yt + th * 128 * 36;
    for (int c = 0; c < 128; ++c) {
      float wv0 = w0[c], wv1 = w1[c];
      const float4* yp = (const float4*)(yb + c * 36);
#pragma unroll
      for (int j = 0; j < 7; ++j) {
        float4 yv = yp[j];
        fma4(acc[0][j], wv0, yv);
        fma4(acc[1][j], wv1, yv);
      }
    }
  }
  const int t = t0 + th;
#pragma unroll
  for (int oi = 0; oi < 2; ++oi) {
    int o = o2 + 64 * oi;
    float scale = g_t[o] * rsqrtf(v_t[o] + EPSF);
    float sh = beta_t[o] - m_t[o] * scale;
    float bb = b_t[o];
    float av[28];
#pragma unroll
    for (int j = 0; j < 7; ++j) *(float4*)(av + 4 * j) = acc[oi][j];
#pragma unroll
    for (int v = 0; v < 25; ++v) {
      float z = (av[v] + bb) * scale + sh;
      int idx = (((n * TT + t) * VV + v) << 7) + o;
      float zz = y2[idx] + z;
      zz = zz > 0.f ? zz : 0.1f * zz;  // leaky(y + z)
      zz = zz + x[idx];                // + xc
      out[idx] = zz > 0.f ? zz : 0.f;  // relu
    }
  }
}

extern "C" void kernel_launch(void* const* d_in, const int* in_sizes, int n_in,
                              void* d_out, int out_size, void* d_ws, size_t ws_size,
                              hipStream_t stream) {
  const float* x      = (const float*)d_in[0];
  const float* w_k    = (const float*)d_in[1];
  const float* b_k    = (const float*)d_in[2];
  const float* w_q    = (const float*)d_in[3];
  const float* b_q    = (const float*)d_in[4];
  const float* alphas = (const float*)d_in[5];
  const float* att0   = (const float*)d_in[6];
  const float* w_out  = (const float*)d_in[7];
  const float* b_out  = (const float*)d_in[8];
  const float* g_out  = (const float*)d_in[9];
  const float* be_out = (const float*)d_in[10];
  const float* m_out  = (const float*)d_in[11];
  const float* v_out  = (const float*)d_in[12];
  const float* w_ff   = (const float*)d_in[13];
  const float* b_ff   = (const float*)d_in[14];
  const float* g_ff   = (const float*)d_in[15];
  const float* be_ff  = (const float*)d_in[16];
  const float* m_ff   = (const float*)d_in[17];
  const float* v_ff   = (const float*)d_in[18];
  const float* w_t    = (const float*)d_in[19];
  const float* b_t    = (const float*)d_in[20];
  const float* g_t    = (const float*)d_in[21];
  const float* be_t   = (const float*)d_in[22];
  const float* m_t    = (const float*)d_in[23];
  const float* v_t    = (const float*)d_in[24];

  float* ws = (float*)d_ws;
  // Workspace layout (floats). Total 32,108,288 floats = ~122.5 MiB.
  float* qfull = ws;                   // 16*290*25*128 = 14,848,000 (reused as y2)
  float* kfull = qfull + 14848000;     // 16*288*25*128 = 14,745,600 (reused as y1)
  float* part  = kfull + 14745600;     // 128*9*1875    =  2,160,000
  float* att   = part + 2160000;       // 128*1875      =    240,000
  float* wt_tr = att + 240000;         // 128*128*7     =    114,688
  float* y1 = kfull;  // kfull dead after k_scores
  float* y2 = qfull;  // qfull dead after k_scores
  float* outp = (float*)d_out;

  k_qk<<<3625, 256, 0, stream>>>(x, w_k, b_k, w_q, b_q, kfull, qfull);
  k_scores<<<dim3(9, 8, 16), 128, 0, stream>>>(kfull, qfull, part);
  k_softmax<<<128, 128, 0, stream>>>(part, alphas, att0, att);
  k_attn_out<<<dim3(288, 16), 256, 0, stream>>>(x, att, w_out, b_out, g_out,
                                                be_out, m_out, v_out, y1);
  k_ff<<<3600, 256, 0, stream>>>(y1, x, w_ff, b_ff, g_ff, be_ff, m_ff, v_ff, y2);
  k_wt_tr<<<448, 256, 0, stream>>>(w_t, wt_tr);
  k_tconv<<<dim3(144, 16), 128, 0, stream>>>(y2, x, wt_tr, b_t, g_t, be_t, m_t,
                                             v_t, outp);
}

// Round 2
// 3981.580 us; speedup vs baseline: 1.2921x; 1.2921x over previous
//
#include <hip/hip_runtime.h>

// SSHA block, fp32. Round 2: k_tconv rewritten (register-tiled, weights-only LDS,
// global broadcast activation reads); k_wt_tr now emits [kt][c][o].
// Shapes: N=16, T=288, V=25, C=128, S=8, IC=16, W=3, U=W*V=75, TP=290.
// Layout everywhere: [n][t][v][c], c contiguous.

#define NN 16
#define TT 288
#define VV 25
#define CC 128
#define SS 8
#define UU 75
#define TP 290
#define EPSF 1e-5f

static __device__ __forceinline__ void fma4(float4& a, float s, const float4 b) {
  a.x += s * b.x; a.y += s * b.y; a.z += s * b.z; a.w += s * b.w;
}

// ---------------- K1: k/q 1x1 convs ----------------
__global__ __launch_bounds__(256) void k_qk(
    const float* __restrict__ x,
    const float* __restrict__ w_k, const float* __restrict__ b_k,
    const float* __restrict__ w_q, const float* __restrict__ b_q,
    float* __restrict__ kfull, float* __restrict__ qfull) {
  __shared__ float wk[128 * 129];
  __shared__ float wq[128 * 129];
  __shared__ float xt[128 * 36];
  const int tid = threadIdx.x;
  for (int i = tid; i < 128 * 128; i += 256) {
    int o = i >> 7, c = i & 127;
    wk[o * 129 + c] = w_k[i];
    wq[o * 129 + c] = w_q[i];
  }
  const int base = blockIdx.x * 32;
  for (int i = tid; i < 32 * 128; i += 256) {
    int r = i >> 7, c = i & 127;
    int row = base + r;
    int n = row / (TP * VV);
    int rem = row - n * (TP * VV);
    int tp = rem / VV, v = rem - tp * VV;
    float val = 0.f;
    if (tp >= 1 && tp <= TT) val = x[(((n * TT + (tp - 1)) * VV + v) << 7) + c];
    xt[c * 36 + r] = val;
  }
  __syncthreads();
  const int o = tid & 127;
  const int rh = tid >> 7;
  float acck[16], accq[16];
#pragma unroll
  for (int r = 0; r < 16; ++r) { acck[r] = 0.f; accq[r] = 0.f; }
  const float* wkp = wk + o * 129;
  const float* wqp = wq + o * 129;
  for (int c = 0; c < 128; ++c) {
    float wv0 = wkp[c];
    float wv1 = wqp[c];
    const float4* xp = (const float4*)(xt + c * 36 + rh * 16);
#pragma unroll
    for (int r4 = 0; r4 < 4; ++r4) {
      float4 xv = xp[r4];
      acck[r4 * 4 + 0] += wv0 * xv.x; acck[r4 * 4 + 1] += wv0 * xv.y;
      acck[r4 * 4 + 2] += wv0 * xv.z; acck[r4 * 4 + 3] += wv0 * xv.w;
      accq[r4 * 4 + 0] += wv1 * xv.x; accq[r4 * 4 + 1] += wv1 * xv.y;
      accq[r4 * 4 + 2] += wv1 * xv.z; accq[r4 * 4 + 3] += wv1 * xv.w;
    }
  }
  const float bk = b_k[o], bq = b_q[o];
  for (int r = 0; r < 16; ++r) {
    int row = base + rh * 16 + r;
    int n = row / (TP * VV);
    int rem = row - n * (TP * VV);
    int tp = rem / VV, v = rem - tp * VV;
    qfull[(((n * TP + tp) * VV + v) << 7) + o] = accq[r] + bq;
    if (tp >= 1 && tp <= TT)
      kfull[(((n * TT + (tp - 1)) * VV + v) << 7) + o] = acck[r] + bk;
  }
}

// ---------------- K2a: partial scores ----------------
__global__ __launch_bounds__(128) void k_scores(
    const float* __restrict__ kfull, const float* __restrict__ qfull,
    float* __restrict__ partial) {
  __shared__ float kl[32 * 16 * 28];
  __shared__ float ql[34 * 25 * 17];
  const int tc = blockIdx.x, s = blockIdx.y, n = blockIdx.z;
  const int t0 = tc * 32;
  const int tid = threadIdx.x;
  for (int i = tid; i < 32 * 16 * 28; i += 128) {
    int tt = i / 448;
    int rem = i - tt * 448;
    int ic = rem / 28, v = rem - ic * 28;
    float val = 0.f;
    if (v < 25) val = kfull[(((n * TT + t0 + tt) * VV + v) << 7) + s * 16 + ic];
    kl[i] = val;
  }
  for (int i = tid; i < 34 * 25 * 16; i += 128) {
    int tt = i / 400;
    int rem = i - tt * 400;
    int vp = rem >> 4, ic = rem & 15;
    ql[(tt * 25 + vp) * 17 + ic] =
        qfull[(((n * TP + t0 + tt) * VV + vp) << 7) + s * 16 + ic];
  }
  __syncthreads();
  if (tid < 75) {
    const int w = tid / 25, vp = tid - w * 25;
    float4 acc[7];
#pragma unroll
    for (int j = 0; j < 7; ++j) acc[j] = make_float4(0.f, 0.f, 0.f, 0.f);
    for (int tt = 0; tt < 32; ++tt) {
      const float* qp = ql + ((tt + w) * 25 + vp) * 17;
      const float* kb = kl + tt * 448;
#pragma unroll
      for (int ic = 0; ic < 16; ++ic) {
        float qv = qp[ic];
        const float4* kq = (const float4*)(kb + ic * 28);
#pragma unroll
        for (int j = 0; j < 7; ++j) fma4(acc[j], qv, kq[j]);
      }
    }
    float av[28];
#pragma unroll
    for (int j = 0; j < 7; ++j) *(float4*)(av + 4 * j) = acc[j];
    float* op = partial + ((((n * SS + s) * 9 + tc) * UU) + tid) * VV;
#pragma unroll
    for (int v = 0; v < 25; ++v) op[v] = av[v];
  }
}

// ---------------- K2b: reduce + softmax + att ----------------
__global__ __launch_bounds__(128) void k_softmax(
    const float* __restrict__ partial, const float* __restrict__ alphas,
    const float* __restrict__ att0, float* __restrict__ att) {
  __shared__ float sc[1875];
  __shared__ float mx[25];
  __shared__ float den[25];
  const int ns = blockIdx.x;
  const int s = ns & 7;
  const int tid = threadIdx.x;
  const float inv = 1.0f / 4608.0f;
  for (int i = tid; i < 1875; i += 128) {
    float a = 0.f;
    const float* p = partial + ns * 9 * 1875 + i;
#pragma unroll
    for (int j = 0; j < 9; ++j) a += p[j * 1875];
    sc[i] = a * inv;
  }
  __syncthreads();
  if (tid < 25) {
    float m = -1e30f;
    for (int u = 0; u < 75; ++u) m = fmaxf(m, sc[u * 25 + tid]);
    float d = 0.f;
    for (int u = 0; u < 75; ++u) d += expf(sc[u * 25 + tid] - m);
    mx[tid] = m;
    den[tid] = d;
  }
  __syncthreads();
  const float alpha = alphas[s];
  for (int i = tid; i < 1875; i += 128) {
    int v = i % 25;
    att[ns * 1875 + i] = expf(sc[i] - mx[v]) / den[v] * alpha + att0[s * 1875 + i];
  }
}

// ---------------- K3: attention-apply + out conv + BN + leaky residual ----------------
__global__ __launch_bounds__(256) void k_attn_out(
    const float* __restrict__ x, const float* __restrict__ att,
    const float* __restrict__ w_out, const float* __restrict__ b_out,
    const float* __restrict__ g_out, const float* __restrict__ beta_out,
    const float* __restrict__ m_out, const float* __restrict__ v_out,
    float* __restrict__ y1) {
  __shared__ float xs[75 * 128];
  __shared__ float al[75 * 32];
  __shared__ float yl[128 * 36];
  __shared__ float wl[128 * 129];
  const int t = blockIdx.x, n = blockIdx.y;
  const int tid = threadIdx.x;
  for (int i = tid; i < 75 * 128; i += 256) {
    int u = i >> 7, c = i & 127;
    int w = u / 25, vp = u - w * 25;
    int tr = t + w - 1;
    float val = 0.f;
    if (tr >= 0 && tr < TT) val = x[(((n * TT + tr) * VV + vp) << 7) + c];
    xs[i] = val;
  }
  const int l2 = tid & 63;
  const int h = tid >> 6;
  float4 oacc[2][2];
  oacc[0][0] = make_float4(0, 0, 0, 0); oacc[0][1] = make_float4(0, 0, 0, 0);
  oacc[1][0] = make_float4(0, 0, 0, 0); oacc[1][1] = make_float4(0, 0, 0, 0);
  for (int s = 0; s < SS; ++s) {
    __syncthreads();
    for (int i = tid; i < 75 * 32; i += 256) {
      int u = i >> 5, v = i & 31;
      al[i] = (v < 25) ? att[(((n * SS + s) * UU) + u) * VV + v] : 0.f;
    }
    for (int i = tid; i < 128 * 128; i += 256) {
      int o = i >> 7, c = i & 127;
      wl[o * 129 + c] = w_out[(o << 10) + (s << 7) + c];
    }
    __syncthreads();
    {
      float4 ya00 = make_float4(0, 0, 0, 0), ya01 = make_float4(0, 0, 0, 0);
      float4 ya10 = make_float4(0, 0, 0, 0), ya11 = make_float4(0, 0, 0, 0);
      for (int u = 0; u < 75; ++u) {
        float xv0 = xs[(u << 7) + l2];
        float xv1 = xs[(u << 7) + l2 + 64];
        const float4* ap = (const float4*)(al + (u << 5)) + 2 * h;
        float4 a0 = ap[0], a1 = ap[1];
        fma4(ya00, xv0, a0); fma4(ya01, xv0, a1);
        fma4(ya10, xv1, a0); fma4(ya11, xv1, a1);
      }
      *(float4*)(yl + l2 * 36 + h * 8) = ya00;
      *(float4*)(yl + l2 * 36 + h * 8 + 4) = ya01;
      *(float4*)(yl + (l2 + 64) * 36 + h * 8) = ya10;
      *(float4*)(yl + (l2 + 64) * 36 + h * 8 + 4) = ya11;
    }
    __syncthreads();
    const float* w0 = wl + l2 * 129;
    const float* w1 = wl + (l2 + 64) * 129;
    for (int c = 0; c < 128; ++c) {
      float wv0 = w0[c], wv1 = w1[c];
      const float4* yp = (const float4*)(yl + c * 36) + 2 * h;
      float4 yq0 = yp[0], yq1 = yp[1];
      fma4(oacc[0][0], wv0, yq0); fma4(oacc[0][1], wv0, yq1);
      fma4(oacc[1][0], wv1, yq0); fma4(oacc[1][1], wv1, yq1);
    }
  }
#pragma unroll
  for (int oi = 0; oi < 2; ++oi) {
    int o = l2 + 64 * oi;
    float scale = g_out[o] * rsqrtf(v_out[o] + EPSF);
    float sh = beta_out[o] - m_out[o] * scale;
    float bb = b_out[o];
    float av[8];
    *(float4*)(av) = oacc[oi][0];
    *(float4*)(av + 4) = oacc[oi][1];
#pragma unroll
    for (int j = 0; j < 8; ++j) {
      int v = 8 * h + j;
      if (v < 25) {
        float a = (av[j] + bb) * scale + sh;
        int idx = (((n * TT + t) * VV + v) << 7) + o;
        float r = x[idx] + a;
        y1[idx] = r > 0.f ? r : 0.1f * r;
      }
    }
  }
}

// ---------------- K4: ff conv + BN + leaky residual ----------------
__global__ __launch_bounds__(256) void k_ff(
    const float* __restrict__ y1, const float* __restrict__ x,
    const float* __restrict__ w_ff, const float* __restrict__ b_ff,
    const float* __restrict__ g_ff, const float* __restrict__ beta_ff,
    const float* __restrict__ m_ff, const float* __restrict__ v_ff,
    float* __restrict__ y2) {
  __shared__ float wl[128 * 129];
  __shared__ float yt[128 * 36];
  const int tid = threadIdx.x;
  for (int i = tid; i < 128 * 128; i += 256)
    wl[(i >> 7) * 129 + (i & 127)] = w_ff[i];
  const int base = blockIdx.x * 32;
  for (int i = tid; i < 32 * 128; i += 256) {
    int r = i >> 7, c = i & 127;
    yt[c * 36 + r] = y1[((base + r) << 7) + c];
  }
  __syncthreads();
  const int o2 = tid & 63;
  const int rq = tid >> 6;
  float acc[2][8];
#pragma unroll
  for (int i = 0; i < 8; ++i) { acc[0][i] = 0.f; acc[1][i] = 0.f; }
  const float* w0 = wl + o2 * 129;
  const float* w1 = wl + (o2 + 64) * 129;
  for (int c = 0; c < 128; ++c) {
    float wv0 = w0[c], wv1 = w1[c];
    const float4* yp = (const float4*)(yt + c * 36 + rq * 8);
    float4 a = yp[0], b = yp[1];
    acc[0][0] += wv0 * a.x; acc[0][1] += wv0 * a.y; acc[0][2] += wv0 * a.z; acc[0][3] += wv0 * a.w;
    acc[0][4] += wv0 * b.x; acc[0][5] += wv0 * b.y; acc[0][6] += wv0 * b.z; acc[0][7] += wv0 * b.w;
    acc[1][0] += wv1 * a.x; acc[1][1] += wv1 * a.y; acc[1][2] += wv1 * a.z; acc[1][3] += wv1 * a.w;
    acc[1][4] += wv1 * b.x; acc[1][5] += wv1 * b.y; acc[1][6] += wv1 * b.z; acc[1][7] += wv1 * b.w;
  }
#pragma unroll
  for (int oi = 0; oi < 2; ++oi) {
    int o = o2 + 64 * oi;
    float scale = g_ff[o] * rsqrtf(v_ff[o] + EPSF);
    float sh = beta_ff[o] - m_ff[o] * scale;
    float bb = b_ff[o];
#pragma unroll
    for (int r = 0; r < 8; ++r) {
      int row = base + rq * 8 + r;
      float a = (acc[oi][r] + bb) * scale + sh;
      float rr = x[(row << 7) + o] + a;
      y2[(row << 7) + o] = rr > 0.f ? rr : 0.1f * rr;
    }
  }
}

// ---------------- K5a: transpose w_t (o,c,kt) -> wt_cr[kt][c][o] ----------------
__global__ __launch_bounds__(256) void k_wt_tr(const float* __restrict__ w_t,
                                               float* __restrict__ wt_cr) {
  int i = blockIdx.x * 256 + threadIdx.x;
  if (i < 128 * 128 * 7) {
    int o = i / 896;
    int rem = i - o * 896;
    int c = rem / 7, kt = rem - c * 7;
    wt_cr[(kt * 128 + c) * 128 + o] = w_t[i];
  }
}

// ---------------- K5: temporal conv 7x1 + BN + leaky + relu residual ----------------
// grid 512 (16 n x 32 row-chunks of 225), block 512.
// Per thread: o = 4*o4..4*o4+3 (o4=tid&31), rows rgrp*15+j (rgrp=tid>>5, j<15; rows>=225 discarded).
// Weights [c][o] in LDS (64KB -> 2 blocks/CU); activations read direct from global (L1/L2-resident).
__global__ __launch_bounds__(512, 4) void k_tconv(
    const float* __restrict__ y2, const float* __restrict__ x,
    const float* __restrict__ wt_cr, const float* __restrict__ b_t,
    const float* __restrict__ g_t, const float* __restrict__ beta_t,
    const float* __restrict__ m_t, const float* __restrict__ v_t,
    float* __restrict__ out) {
  __shared__ float wl[128 * 128];  // [c][o]
  const int blk = blockIdx.x;
  const int n = blk >> 5;
  const int r0 = (blk & 31) * 225;
  const int tid = threadIdx.x;
  const int o4 = tid & 31;
  const int rgrp = tid >> 5;
  const int rowbase = rgrp * 15;
  const float4* y2n4 = (const float4*)(y2 + (size_t)n * 7200 * 128);
  const bool edge = (r0 == 0) || (r0 == 7200 - 225);
  float4 acc[15];
#pragma unroll
  for (int j = 0; j < 15; ++j) acc[j] = make_float4(0.f, 0.f, 0.f, 0.f);
  for (int kt = 0; kt < 7; ++kt) {
    __syncthreads();
    {
      const float4* wsrc = (const float4*)(wt_cr + kt * 16384);
      float4* wd = (float4*)wl;
      for (int i = tid; i < 4096; i += 512) wd[i] = wsrc[i];
    }
    __syncthreads();
    const int shift = (kt - 3) * 25;
    const float4* wl4 = (const float4*)wl;
    if (!edge) {
      for (int c4 = 0; c4 < 32; ++c4) {
        float4 w0 = wl4[(4 * c4 + 0) * 32 + o4];
        float4 w1 = wl4[(4 * c4 + 1) * 32 + o4];
        float4 w2 = wl4[(4 * c4 + 2) * 32 + o4];
        float4 w3 = wl4[(4 * c4 + 3) * 32 + o4];
#pragma unroll
        for (int j = 0; j < 15; ++j) {
          int src = r0 + rowbase + j + shift;  // in-bounds for rows<225; rows>=225 read
          float4 a = y2n4[src * 32 + c4];      // stale-but-finite ws data, discarded
          fma4(acc[j], a.x, w0); fma4(acc[j], a.y, w1);
          fma4(acc[j], a.z, w2); fma4(acc[j], a.w, w3);
        }
      }
    } else {
      for (int c4 = 0; c4 < 32; ++c4) {
        float4 w0 = wl4[(4 * c4 + 0) * 32 + o4];
        float4 w1 = wl4[(4 * c4 + 1) * 32 + o4];
        float4 w2 = wl4[(4 * c4 + 2) * 32 + o4];
        float4 w3 = wl4[(4 * c4 + 3) * 32 + o4];
#pragma unroll
        for (int j = 0; j < 15; ++j) {
          int src = r0 + rowbase + j + shift;
          bool valid = (src >= 0) && (src < 7200);
          int sc = valid ? src : 0;
          float4 a = y2n4[sc * 32 + c4];
          if (!valid) a = make_float4(0.f, 0.f, 0.f, 0.f);
          fma4(acc[j], a.x, w0); fma4(acc[j], a.y, w1);
          fma4(acc[j], a.z, w2); fma4(acc[j], a.w, w3);
        }
      }
    }
  }
  // epilogue: BN + leaky(y2+z) + relu(+x)
  float4 gg = ((const float4*)g_t)[o4];
  float4 vv = ((const float4*)v_t)[o4];
  float4 mm = ((const float4*)m_t)[o4];
  float4 be = ((const float4*)beta_t)[o4];
  float4 bb = ((const float4*)b_t)[o4];
  float4 sc4, sh4;
  sc4.x = gg.x * rsqrtf(vv.x + EPSF); sc4.y = gg.y * rsqrtf(vv.y + EPSF);
  sc4.z = gg.z * rsqrtf(vv.z + EPSF); sc4.w = gg.w * rsqrtf(vv.w + EPSF);
  sh4.x = be.x - mm.x * sc4.x; sh4.y = be.y - mm.y * sc4.y;
  sh4.z = be.z - mm.z * sc4.z; sh4.w = be.w - mm.w * sc4.w;
  const float4* y24 = (const float4*)y2;
  const float4* x4 = (const float4*)x;
  float4* out4 = (float4*)out;
#pragma unroll
  for (int j = 0; j < 15; ++j) {
    int row = rowbase + j;
    if (row < 225) {
      int idx = (n * 7200 + r0 + row) * 32 + o4;
      float4 yv = y24[idx];
      float4 xv = x4[idx];
      float4 r;
      float z;
      z = (acc[j].x + bb.x) * sc4.x + sh4.x; z += yv.x; z = z > 0.f ? z : 0.1f * z; z += xv.x; r.x = z > 0.f ? z : 0.f;
      z = (acc[j].y + bb.y) * sc4.y + sh4.y; z += yv.y; z = z > 0.f ? z : 0.1f * z; z += xv.y; r.y = z > 0.f ? z : 0.f;
      z = (acc[j].z + bb.z) * sc4.z + sh4.z; z += yv.z; z = z > 0.f ? z : 0.1f * z; z += xv.z; r.z = z > 0.f ? z : 0.f;
      z = (acc[j].w + bb.w) * sc4.w + sh4.w; z += yv.w; z = z > 0.f ? z : 0.1f * z; z += xv.w; r.w = z > 0.f ? z : 0.f;
      out4[idx] = r;
    }
  }
}

extern "C" void kernel_launch(void* const* d_in, const int* in_sizes, int n_in,
                              void* d_out, int out_size, void* d_ws, size_t ws_size,
                              hipStream_t stream) {
  const float* x      = (const float*)d_in[0];
  const float* w_k    = (const float*)d_in[1];
  const float* b_k    = (const float*)d_in[2];
  const float* w_q    = (const float*)d_in[3];
  const float* b_q    = (const float*)d_in[4];
  const float* alphas = (const float*)d_in[5];
  const float* att0   = (const float*)d_in[6];
  const float* w_out  = (const float*)d_in[7];
  const float* b_out  = (const float*)d_in[8];
  const float* g_out  = (const float*)d_in[9];
  const float* be_out = (const float*)d_in[10];
  const float* m_out  = (const float*)d_in[11];
  const float* v_out  = (const float*)d_in[12];
  const float* w_ff   = (const float*)d_in[13];
  const float* b_ff   = (const float*)d_in[14];
  const float* g_ff   = (const float*)d_in[15];
  const float* be_ff  = (const float*)d_in[16];
  const float* m_ff   = (const float*)d_in[17];
  const float* v_ff   = (const float*)d_in[18];
  const float* w_t    = (const float*)d_in[19];
  const float* b_t    = (const float*)d_in[20];
  const float* g_t    = (const float*)d_in[21];
  const float* be_t   = (const float*)d_in[22];
  const float* m_t    = (const float*)d_in[23];
  const float* v_t    = (const float*)d_in[24];

  float* ws = (float*)d_ws;
  float* qfull = ws;                   // 16*290*25*128 = 14,848,000 (reused as y2)
  float* kfull = qfull + 14848000;     // 16*288*25*128 = 14,745,600 (reused as y1)
  float* part  = kfull + 14745600;     // 128*9*1875    =  2,160,000
  float* att   = part + 2160000;       // 128*1875      =    240,000
  float* wt_cr = att + 240000;         // 7*128*128     =    114,688
  float* y1 = kfull;
  float* y2 = qfull;
  float* outp = (float*)d_out;

  k_qk<<<3625, 256, 0, stream>>>(x, w_k, b_k, w_q, b_q, kfull, qfull);
  k_scores<<<dim3(9, 8, 16), 128, 0, stream>>>(kfull, qfull, part);
  k_softmax<<<128, 128, 0, stream>>>(part, alphas, att0, att);
  k_attn_out<<<dim3(288, 16), 256, 0, stream>>>(x, att, w_out, b_out, g_out,
                                                be_out, m_out, v_out, y1);
  k_ff<<<3600, 256, 0, stream>>>(y1, x, w_ff, b_ff, g_ff, be_ff, m_ff, v_ff, y2);
  k_wt_tr<<<448, 256, 0, stream>>>(w_t, wt_cr);
  k_tconv<<<512, 512, 0, stream>>>(y2, x, wt_cr, b_t, g_t, be_t, m_t, v_t, outp);
}

// Round 3
// 3961.055 us; speedup vs baseline: 1.2988x; 1.0052x over previous
//
#include <hip/hip_runtime.h>

// SSHA block. Round 3: k_attn_out replaced by H-reassociation:
//   H[n,t',vp,(s,o)] = sum_c x[n,t',vp,c]*W[o,s,c]      (bf16 MFMA GEMM, M=115200,K=128,N=1024)
//   O[n,t,v,o] = sum_{w,s,vp} A[n,s,(w,vp),v]*H[n,t+w-1,vp,(s,o)] + b_out  (fp32, A in LDS)
// Fallback to round-2 fused k_attn_out if ws_size < ~394 MB.
// Shapes: N=16, T=288, V=25, C=128, S=8, IC=16, W=3, U=75, TP=290.

#define NN 16
#define TT 288
#define VV 25
#define CC 128
#define SS 8
#define UU 75
#define TP 290
#define EPSF 1e-5f

typedef __attribute__((ext_vector_type(8))) short bf16x8;
typedef __attribute__((ext_vector_type(4))) float f32x4;

static __device__ __forceinline__ void fma4(float4& a, float s, const float4 b) {
  a.x += s * b.x; a.y += s * b.y; a.z += s * b.z; a.w += s * b.w;
}
static __device__ __forceinline__ ushort f2bf(float f) {
  uint u = __float_as_uint(f);
  u = (u + 0x7FFFu + ((u >> 16) & 1u)) >> 16;
  return (ushort)u;
}

// ---------------- K1: k/q 1x1 convs ----------------
__global__ __launch_bounds__(256) void k_qk(
    const float* __restrict__ x,
    const float* __restrict__ w_k, const float* __restrict__ b_k,
    const float* __restrict__ w_q, const float* __restrict__ b_q,
    float* __restrict__ kfull, float* __restrict__ qfull) {
  __shared__ float wk[128 * 129];
  __shared__ float wq[128 * 129];
  __shared__ float xt[128 * 36];
  const int tid = threadIdx.x;
  for (int i = tid; i < 128 * 128; i += 256) {
    int o = i >> 7, c = i & 127;
    wk[o * 129 + c] = w_k[i];
    wq[o * 129 + c] = w_q[i];
  }
  const int base = blockIdx.x * 32;
  for (int i = tid; i < 32 * 128; i += 256) {
    int r = i >> 7, c = i & 127;
    int row = base + r;
    int n = row / (TP * VV);
    int rem = row - n * (TP * VV);
    int tp = rem / VV, v = rem - tp * VV;
    float val = 0.f;
    if (tp >= 1 && tp <= TT) val = x[(((n * TT + (tp - 1)) * VV + v) << 7) + c];
    xt[c * 36 + r] = val;
  }
  __syncthreads();
  const int o = tid & 127;
  const int rh = tid >> 7;
  float acck[16], accq[16];
#pragma unroll
  for (int r = 0; r < 16; ++r) { acck[r] = 0.f; accq[r] = 0.f; }
  const float* wkp = wk + o * 129;
  const float* wqp = wq + o * 129;
  for (int c = 0; c < 128; ++c) {
    float wv0 = wkp[c];
    float wv1 = wqp[c];
    const float4* xp = (const float4*)(xt + c * 36 + rh * 16);
#pragma unroll
    for (int r4 = 0; r4 < 4; ++r4) {
      float4 xv = xp[r4];
      acck[r4 * 4 + 0] += wv0 * xv.x; acck[r4 * 4 + 1] += wv0 * xv.y;
      acck[r4 * 4 + 2] += wv0 * xv.z; acck[r4 * 4 + 3] += wv0 * xv.w;
      accq[r4 * 4 + 0] += wv1 * xv.x; accq[r4 * 4 + 1] += wv1 * xv.y;
      accq[r4 * 4 + 2] += wv1 * xv.z; accq[r4 * 4 + 3] += wv1 * xv.w;
    }
  }
  const float bk = b_k[o], bq = b_q[o];
  for (int r = 0; r < 16; ++r) {
    int row = base + rh * 16 + r;
    int n = row / (TP * VV);
    int rem = row - n * (TP * VV);
    int tp = rem / VV, v = rem - tp * VV;
    qfull[(((n * TP + tp) * VV + v) << 7) + o] = accq[r] + bq;
    if (tp >= 1 && tp <= TT)
      kfull[(((n * TT + (tp - 1)) * VV + v) << 7) + o] = acck[r] + bk;
  }
}

// ---------------- K2a: partial scores ----------------
__global__ __launch_bounds__(128) void k_scores(
    const float* __restrict__ kfull, const float* __restrict__ qfull,
    float* __restrict__ partial) {
  __shared__ float kl[32 * 16 * 28];
  __shared__ float ql[34 * 25 * 17];
  const int tc = blockIdx.x, s = blockIdx.y, n = blockIdx.z;
  const int t0 = tc * 32;
  const int tid = threadIdx.x;
  for (int i = tid; i < 32 * 16 * 28; i += 128) {
    int tt = i / 448;
    int rem = i - tt * 448;
    int ic = rem / 28, v = rem - ic * 28;
    float val = 0.f;
    if (v < 25) val = kfull[(((n * TT + t0 + tt) * VV + v) << 7) + s * 16 + ic];
    kl[i] = val;
  }
  for (int i = tid; i < 34 * 25 * 16; i += 128) {
    int tt = i / 400;
    int rem = i - tt * 400;
    int vp = rem >> 4, ic = rem & 15;
    ql[(tt * 25 + vp) * 17 + ic] =
        qfull[(((n * TP + t0 + tt) * VV + vp) << 7) + s * 16 + ic];
  }
  __syncthreads();
  if (tid < 75) {
    const int w = tid / 25, vp = tid - w * 25;
    float4 acc[7];
#pragma unroll
    for (int j = 0; j < 7; ++j) acc[j] = make_float4(0.f, 0.f, 0.f, 0.f);
    for (int tt = 0; tt < 32; ++tt) {
      const float* qp = ql + ((tt + w) * 25 + vp) * 17;
      const float* kb = kl + tt * 448;
#pragma unroll
      for (int ic = 0; ic < 16; ++ic) {
        float qv = qp[ic];
        const float4* kq = (const float4*)(kb + ic * 28);
#pragma unroll
        for (int j = 0; j < 7; ++j) fma4(acc[j], qv, kq[j]);
      }
    }
    float av[28];
#pragma unroll
    for (int j = 0; j < 7; ++j) *(float4*)(av + 4 * j) = acc[j];
    float* op = partial + ((((n * SS + s) * 9 + tc) * UU) + tid) * VV;
#pragma unroll
    for (int v = 0; v < 25; ++v) op[v] = av[v];
  }
}

// ---------------- K2b: reduce + softmax + att ----------------
__global__ __launch_bounds__(128) void k_softmax(
    const float* __restrict__ partial, const float* __restrict__ alphas,
    const float* __restrict__ att0, float* __restrict__ att) {
  __shared__ float sc[1875];
  __shared__ float mx[25];
  __shared__ float den[25];
  const int ns = blockIdx.x;
  const int s = ns & 7;
  const int tid = threadIdx.x;
  const float inv = 1.0f / 4608.0f;
  for (int i = tid; i < 1875; i += 128) {
    float a = 0.f;
    const float* p = partial + ns * 9 * 1875 + i;
#pragma unroll
    for (int j = 0; j < 9; ++j) a += p[j * 1875];
    sc[i] = a * inv;
  }
  __syncthreads();
  if (tid < 25) {
    float m = -1e30f;
    for (int u = 0; u < 75; ++u) m = fmaxf(m, sc[u * 25 + tid]);
    float d = 0.f;
    for (int u = 0; u < 75; ++u) d += expf(sc[u * 25 + tid] - m);
    mx[tid] = m;
    den[tid] = d;
  }
  __syncthreads();
  const float alpha = alphas[s];
  for (int i = tid; i < 1875; i += 128) {
    int v = i % 25;
    att[ns * 1875 + i] = expf(sc[i] - mx[v]) / den[v] * alpha + att0[s * 1875 + i];
  }
}

// ---------------- K3 prep: fp32 -> bf16 converts ----------------
__global__ __launch_bounds__(256) void k_xcvt(const float* __restrict__ x,
                                              ushort* __restrict__ xb) {
  int i = blockIdx.x * 256 + threadIdx.x;  // 3,686,400 threads, 4 elems each
  float4 a = ((const float4*)x)[i];
  ushort4 o;
  o.x = f2bf(a.x); o.y = f2bf(a.y); o.z = f2bf(a.z); o.w = f2bf(a.w);
  ((ushort4*)xb)[i] = o;
}

// Wb[j=(s*128+o)][c] = bf16(w_out[o*1024 + s*128 + c])
__global__ __launch_bounds__(256) void k_wcvt(const float* __restrict__ w_out,
                                              ushort* __restrict__ wb) {
  int i = blockIdx.x * 256 + threadIdx.x;  // 131072
  int j = i >> 7, c = i & 127;
  int s = j >> 7, o = j & 127;
  wb[i] = f2bf(w_out[(o << 10) + (s << 7) + c]);
}

// ---------------- K3a: H-GEMM (bf16 MFMA) ----------------
// H[r][j] = sum_c xb[r][c]*wb[j][c]; r=(n*288+t)*25+v (115200), j=s*128+o (1024).
// Grid 7200: bm = bx>>3 (900 M-tiles of 128), bn = bx&7 (8 N-tiles of 128).
// 256 thr = 4 waves (2x2), each wave 64x64; K staged in two 64-halves.
__global__ __launch_bounds__(256) void k_hgemm(const ushort* __restrict__ xb,
                                               const ushort* __restrict__ wb,
                                               ushort* __restrict__ H) {
  __shared__ ushort As[8][128][8];  // [k-group of 8][row][8k] 16KB
  __shared__ ushort Bs[8][128][8];
  const int bx = blockIdx.x;
  const int bm = bx >> 3, bn = bx & 7;
  const int gm0 = bm << 7, gn0 = bn << 7;
  const int tid = threadIdx.x;
  const int lane = tid & 63, wid = tid >> 6;
  const int wm = wid >> 1, wn = wid & 1;
  const int srow = tid & 127;
  const int skg0 = tid >> 7;
  f32x4 acc[4][4] = {};
  for (int kh = 0; kh < 2; ++kh) {
    __syncthreads();
#pragma unroll
    for (int j = 0; j < 4; ++j) {
      int kg = skg0 + 2 * j;
      *(uint4*)&As[kg][srow][0] =
          *(const uint4*)&xb[((size_t)(gm0 + srow) << 7) + kh * 64 + kg * 8];
      *(uint4*)&Bs[kg][srow][0] =
          *(const uint4*)&wb[((size_t)(gn0 + srow) << 7) + kh * 64 + kg * 8];
    }
    __syncthreads();
#pragma unroll
    for (int ks = 0; ks < 2; ++ks) {
      int g = ks * 4 + (lane >> 4);
      bf16x8 af[4], bfr[4];
#pragma unroll
      for (int mi = 0; mi < 4; ++mi)
        af[mi] = *(const bf16x8*)&As[g][wm * 64 + mi * 16 + (lane & 15)][0];
#pragma unroll
      for (int ni = 0; ni < 4; ++ni)
        bfr[ni] = *(const bf16x8*)&Bs[g][wn * 64 + ni * 16 + (lane & 15)][0];
#pragma unroll
      for (int mi = 0; mi < 4; ++mi)
#pragma unroll
        for (int ni = 0; ni < 4; ++ni)
          acc[mi][ni] = __builtin_amdgcn_mfma_f32_16x16x32_bf16(
              af[mi], bfr[ni], acc[mi][ni], 0, 0, 0);
    }
  }
  const int r0 = gm0 + wm * 64;
  const int c0 = gn0 + wn * 64;
#pragma unroll
  for (int mi = 0; mi < 4; ++mi)
#pragma unroll
    for (int ni = 0; ni < 4; ++ni) {
      int col = c0 + ni * 16 + (lane & 15);
#pragma unroll
      for (int reg = 0; reg < 4; ++reg) {
        int row = r0 + mi * 16 + ((lane >> 4) << 2) + reg;
        H[((size_t)row << 10) + col] = f2bf(acc[mi][ni][reg]);
      }
    }
}

// ---------------- K3b: O = A.H contraction + b_out + BN + leaky residual ----------------
// Grid (36, 16): 8 t per block. 256 thr: og=tid&15 (o=og*8..+7), vg=tid>>4 (v=vg, vg+16).
__global__ __launch_bounds__(256) void k_attn2(
    const ushort* __restrict__ H, const float* __restrict__ att,
    const float* __restrict__ x, const float* __restrict__ b_out,
    const float* __restrict__ g_out, const float* __restrict__ beta_out,
    const float* __restrict__ m_out, const float* __restrict__ v_out,
    float* __restrict__ y1) {
  __shared__ float Al[3][200][32];  // [w][k=vp*8+s][v pad32]
  const int n = blockIdx.y;
  const int t0 = blockIdx.x * 8;
  const int tid = threadIdx.x;
  for (int i = tid; i < 19200; i += 256) {
    int w = i / 6400;
    int rem = i - w * 6400;
    int k = rem >> 5, v = rem & 31;
    int vp = k >> 3, s = k & 7;
    float val = 0.f;
    if (v < 25) val = att[((size_t)(n * 8 + s) * 75 + (w * 25 + vp)) * 25 + v];
    Al[w][k][v] = val;
  }
  __syncthreads();
  const int og = tid & 15;
  const int vg = tid >> 4;
  float sc[8], sh[8], bb[8];
#pragma unroll
  for (int j = 0; j < 8; ++j) {
    int o = og * 8 + j;
    float s1 = g_out[o] * rsqrtf(v_out[o] + EPSF);
    sc[j] = s1;
    sh[j] = beta_out[o] - m_out[o] * s1;
    bb[j] = b_out[o];
  }
  const float* Af = &Al[0][0][0];
  for (int tt = 0; tt < 8; ++tt) {
    int t = t0 + tt;
    float acc0[8], acc1[8];
#pragma unroll
    for (int j = 0; j < 8; ++j) { acc0[j] = 0.f; acc1[j] = 0.f; }
    for (int w = 0; w < 3; ++w) {
      int tp = t + w - 1;
      if (tp < 0 || tp >= TT) continue;
      const ushort* hp = H + (size_t)(n * TT + tp) * 25600 + og * 8;
      const float* ap = Af + w * 6400;
      for (int k = 0; k < 200; ++k) {
        uint4 h4 = *(const uint4*)(hp + (k << 7));
        float a0 = ap[(k << 5) + vg];
        float a1 = ap[(k << 5) + vg + 16];
        float f0 = __uint_as_float(h4.x << 16);
        float f1 = __uint_as_float(h4.x & 0xffff0000u);
        float f2 = __uint_as_float(h4.y << 16);
        float f3 = __uint_as_float(h4.y & 0xffff0000u);
        float f4 = __uint_as_float(h4.z << 16);
        float f5 = __uint_as_float(h4.z & 0xffff0000u);
        float f6 = __uint_as_float(h4.w << 16);
        float f7 = __uint_as_float(h4.w & 0xffff0000u);
        acc0[0] += a0 * f0; acc0[1] += a0 * f1; acc0[2] += a0 * f2; acc0[3] += a0 * f3;
        acc0[4] += a0 * f4; acc0[5] += a0 * f5; acc0[6] += a0 * f6; acc0[7] += a0 * f7;
        acc1[0] += a1 * f0; acc1[1] += a1 * f1; acc1[2] += a1 * f2; acc1[3] += a1 * f3;
        acc1[4] += a1 * f4; acc1[5] += a1 * f5; acc1[6] += a1 * f6; acc1[7] += a1 * f7;
      }
    }
    {
      size_t idx = ((size_t)((n * TT + t) * VV + vg) << 7) + og * 8;
      const float* xr = x + idx;
      float* yr = y1 + idx;
#pragma unroll
      for (int j = 0; j < 8; ++j) {
        float a = (acc0[j] + bb[j]) * sc[j] + sh[j];
        float r = xr[j] + a;
        yr[j] = r > 0.f ? r : 0.1f * r;
      }
    }
    if (vg < 9) {
      size_t idx = ((size_t)((n * TT + t) * VV + vg + 16) << 7) + og * 8;
      const float* xr = x + idx;
      float* yr = y1 + idx;
#pragma unroll
      for (int j = 0; j < 8; ++j) {
        float a = (acc1[j] + bb[j]) * sc[j] + sh[j];
        float r = xr[j] + a;
        yr[j] = r > 0.f ? r : 0.1f * r;
      }
    }
  }
}

// ---------------- K3 (fallback): fused attention-apply + out conv ----------------
__global__ __launch_bounds__(256) void k_attn_out(
    const float* __restrict__ x, const float* __restrict__ att,
    const float* __restrict__ w_out, const float* __restrict__ b_out,
    const float* __restrict__ g_out, const float* __restrict__ beta_out,
    const float* __restrict__ m_out, const float* __restrict__ v_out,
    float* __restrict__ y1) {
  __shared__ float xs[75 * 128];
  __shared__ float al[75 * 32];
  __shared__ float yl[128 * 36];
  __shared__ float wl[128 * 129];
  const int t = blockIdx.x, n = blockIdx.y;
  const int tid = threadIdx.x;
  for (int i = tid; i < 75 * 128; i += 256) {
    int u = i >> 7, c = i & 127;
    int w = u / 25, vp = u - w * 25;
    int tr = t + w - 1;
    float val = 0.f;
    if (tr >= 0 && tr < TT) val = x[(((n * TT + tr) * VV + vp) << 7) + c];
    xs[i] = val;
  }
  const int l2 = tid & 63;
  const int h = tid >> 6;
  float4 oacc[2][2];
  oacc[0][0] = make_float4(0, 0, 0, 0); oacc[0][1] = make_float4(0, 0, 0, 0);
  oacc[1][0] = make_float4(0, 0, 0, 0); oacc[1][1] = make_float4(0, 0, 0, 0);
  for (int s = 0; s < SS; ++s) {
    __syncthreads();
    for (int i = tid; i < 75 * 32; i += 256) {
      int u = i >> 5, v = i & 31;
      al[i] = (v < 25) ? att[(((n * SS + s) * UU) + u) * VV + v] : 0.f;
    }
    for (int i = tid; i < 128 * 128; i += 256) {
      int o = i >> 7, c = i & 127;
      wl[o * 129 + c] = w_out[(o << 10) + (s << 7) + c];
    }
    __syncthreads();
    {
      float4 ya00 = make_float4(0, 0, 0, 0), ya01 = make_float4(0, 0, 0, 0);
      float4 ya10 = make_float4(0, 0, 0, 0), ya11 = make_float4(0, 0, 0, 0);
      for (int u = 0; u < 75; ++u) {
        float xv0 = xs[(u << 7) + l2];
        float xv1 = xs[(u << 7) + l2 + 64];
        const float4* ap = (const float4*)(al + (u << 5)) + 2 * h;
        float4 a0 = ap[0], a1 = ap[1];
        fma4(ya00, xv0, a0); fma4(ya01, xv0, a1);
        fma4(ya10, xv1, a0); fma4(ya11, xv1, a1);
      }
      *(float4*)(yl + l2 * 36 + h * 8) = ya00;
      *(float4*)(yl + l2 * 36 + h * 8 + 4) = ya01;
      *(float4*)(yl + (l2 + 64) * 36 + h * 8) = ya10;
      *(float4*)(yl + (l2 + 64) * 36 + h * 8 + 4) = ya11;
    }
    __syncthreads();
    const float* w0 = wl + l2 * 129;
    const float* w1 = wl + (l2 + 64) * 129;
    for (int c = 0; c < 128; ++c) {
      float wv0 = w0[c], wv1 = w1[c];
      const float4* yp = (const float4*)(yl + c * 36) + 2 * h;
      float4 yq0 = yp[0], yq1 = yp[1];
      fma4(oacc[0][0], wv0, yq0); fma4(oacc[0][1], wv0, yq1);
      fma4(oacc[1][0], wv1, yq0); fma4(oacc[1][1], wv1, yq1);
    }
  }
#pragma unroll
  for (int oi = 0; oi < 2; ++oi) {
    int o = l2 + 64 * oi;
    float scale = g_out[o] * rsqrtf(v_out[o] + EPSF);
    float sh = beta_out[o] - m_out[o] * scale;
    float bb = b_out[o];
    float av[8];
    *(float4*)(av) = oacc[oi][0];
    *(float4*)(av + 4) = oacc[oi][1];
#pragma unroll
    for (int j = 0; j < 8; ++j) {
      int v = 8 * h + j;
      if (v < 25) {
        float a = (av[j] + bb) * scale + sh;
        int idx = (((n * TT + t) * VV + v) << 7) + o;
        float r = x[idx] + a;
        y1[idx] = r > 0.f ? r : 0.1f * r;
      }
    }
  }
}

// ---------------- K4: ff conv + BN + leaky residual ----------------
__global__ __launch_bounds__(256) void k_ff(
    const float* __restrict__ y1, const float* __restrict__ x,
    const float* __restrict__ w_ff, const float* __restrict__ b_ff,
    const float* __restrict__ g_ff, const float* __restrict__ beta_ff,
    const float* __restrict__ m_ff, const float* __restrict__ v_ff,
    float* __restrict__ y2) {
  __shared__ float wl[128 * 129];
  __shared__ float yt[128 * 36];
  const int tid = threadIdx.x;
  for (int i = tid; i < 128 * 128; i += 256)
    wl[(i >> 7) * 129 + (i & 127)] = w_ff[i];
  const int base = blockIdx.x * 32;
  for (int i = tid; i < 32 * 128; i += 256) {
    int r = i >> 7, c = i & 127;
    yt[c * 36 + r] = y1[((base + r) << 7) + c];
  }
  __syncthreads();
  const int o2 = tid & 63;
  const int rq = tid >> 6;
  float acc[2][8];
#pragma unroll
  for (int i = 0; i < 8; ++i) { acc[0][i] = 0.f; acc[1][i] = 0.f; }
  const float* w0 = wl + o2 * 129;
  const float* w1 = wl + (o2 + 64) * 129;
  for (int c = 0; c < 128; ++c) {
    float wv0 = w0[c], wv1 = w1[c];
    const float4* yp = (const float4*)(yt + c * 36 + rq * 8);
    float4 a = yp[0], b = yp[1];
    acc[0][0] += wv0 * a.x; acc[0][1] += wv0 * a.y; acc[0][2] += wv0 * a.z; acc[0][3] += wv0 * a.w;
    acc[0][4] += wv0 * b.x; acc[0][5] += wv0 * b.y; acc[0][6] += wv0 * b.z; acc[0][7] += wv0 * b.w;
    acc[1][0] += wv1 * a.x; acc[1][1] += wv1 * a.y; acc[1][2] += wv1 * a.z; acc[1][3] += wv1 * a.w;
    acc[1][4] += wv1 * b.x; acc[1][5] += wv1 * b.y; acc[1][6] += wv1 * b.z; acc[1][7] += wv1 * b.w;
  }
#pragma unroll
  for (int oi = 0; oi < 2; ++oi) {
    int o = o2 + 64 * oi;
    float scale = g_ff[o] * rsqrtf(v_ff[o] + EPSF);
    float sh = beta_ff[o] - m_ff[o] * scale;
    float bb = b_ff[o];
#pragma unroll
    for (int r = 0; r < 8; ++r) {
      int row = base + rq * 8 + r;
      float a = (acc[oi][r] + bb) * scale + sh;
      float rr = x[(row << 7) + o] + a;
      y2[(row << 7) + o] = rr > 0.f ? rr : 0.1f * rr;
    }
  }
}

// ---------------- K5a: transpose w_t (o,c,kt) -> wt_cr[kt][c][o] ----------------
__global__ __launch_bounds__(256) void k_wt_tr(const float* __restrict__ w_t,
                                               float* __restrict__ wt_cr) {
  int i = blockIdx.x * 256 + threadIdx.x;
  if (i < 128 * 128 * 7) {
    int o = i / 896;
    int rem = i - o * 896;
    int c = rem / 7, kt = rem - c * 7;
    wt_cr[(kt * 128 + c) * 128 + o] = w_t[i];
  }
}

// ---------------- K5: temporal conv 7x1 + BN + leaky + relu residual ----------------
__global__ __launch_bounds__(512, 4) void k_tconv(
    const float* __restrict__ y2, const float* __restrict__ x,
    const float* __restrict__ wt_cr, const float* __restrict__ b_t,
    const float* __restrict__ g_t, const float* __restrict__ beta_t,
    const float* __restrict__ m_t, const float* __restrict__ v_t,
    float* __restrict__ out) {
  __shared__ float wl[128 * 128];
  const int blk = blockIdx.x;
  const int n = blk >> 5;
  const int r0 = (blk & 31) * 225;
  const int tid = threadIdx.x;
  const int o4 = tid & 31;
  const int rgrp = tid >> 5;
  const int rowbase = rgrp * 15;
  const float4* y2n4 = (const float4*)(y2 + (size_t)n * 7200 * 128);
  const bool edge = (r0 == 0) || (r0 == 7200 - 225);
  float4 acc[15];
#pragma unroll
  for (int j = 0; j < 15; ++j) acc[j] = make_float4(0.f, 0.f, 0.f, 0.f);
  for (int kt = 0; kt < 7; ++kt) {
    __syncthreads();
    {
      const float4* wsrc = (const float4*)(wt_cr + kt * 16384);
      float4* wd = (float4*)wl;
      for (int i = tid; i < 4096; i += 512) wd[i] = wsrc[i];
    }
    __syncthreads();
    const int shift = (kt - 3) * 25;
    const float4* wl4 = (const float4*)wl;
    if (!edge) {
      for (int c4 = 0; c4 < 32; ++c4) {
        float4 w0 = wl4[(4 * c4 + 0) * 32 + o4];
        float4 w1 = wl4[(4 * c4 + 1) * 32 + o4];
        float4 w2 = wl4[(4 * c4 + 2) * 32 + o4];
        float4 w3 = wl4[(4 * c4 + 3) * 32 + o4];
#pragma unroll
        for (int j = 0; j < 15; ++j) {
          int src = r0 + rowbase + j + shift;
          float4 a = y2n4[src * 32 + c4];
          fma4(acc[j], a.x, w0); fma4(acc[j], a.y, w1);
          fma4(acc[j], a.z, w2); fma4(acc[j], a.w, w3);
        }
      }
    } else {
      for (int c4 = 0; c4 < 32; ++c4) {
        float4 w0 = wl4[(4 * c4 + 0) * 32 + o4];
        float4 w1 = wl4[(4 * c4 + 1) * 32 + o4];
        float4 w2 = wl4[(4 * c4 + 2) * 32 + o4];
        float4 w3 = wl4[(4 * c4 + 3) * 32 + o4];
#pragma unroll
        for (int j = 0; j < 15; ++j) {
          int src = r0 + rowbase + j + shift;
          bool valid = (src >= 0) && (src < 7200);
          int scc = valid ? src : 0;
          float4 a = y2n4[scc * 32 + c4];
          if (!valid) a = make_float4(0.f, 0.f, 0.f, 0.f);
          fma4(acc[j], a.x, w0); fma4(acc[j], a.y, w1);
          fma4(acc[j], a.z, w2); fma4(acc[j], a.w, w3);
        }
      }
    }
  }
  float4 gg = ((const float4*)g_t)[o4];
  float4 vv = ((const float4*)v_t)[o4];
  float4 mm = ((const float4*)m_t)[o4];
  float4 be = ((const float4*)beta_t)[o4];
  float4 bb = ((const float4*)b_t)[o4];
  float4 sc4, sh4;
  sc4.x = gg.x * rsqrtf(vv.x + EPSF); sc4.y = gg.y * rsqrtf(vv.y + EPSF);
  sc4.z = gg.z * rsqrtf(vv.z + EPSF); sc4.w = gg.w * rsqrtf(vv.w + EPSF);
  sh4.x = be.x - mm.x * sc4.x; sh4.y = be.y - mm.y * sc4.y;
  sh4.z = be.z - mm.z * sc4.z; sh4.w = be.w - mm.w * sc4.w;
  const float4* y24 = (const float4*)y2;
  const float4* x4 = (const float4*)x;
  float4* out4 = (float4*)out;
#pragma unroll
  for (int j = 0; j < 15; ++j) {
    int row = rowbase + j;
    if (row < 225) {
      int idx = (n * 7200 + r0 + row) * 32 + o4;
      float4 yv = y24[idx];
      float4 xv = x4[idx];
      float4 r;
      float z;
      z = (acc[j].x + bb.x) * sc4.x + sh4.x; z += yv.x; z = z > 0.f ? z : 0.1f * z; z += xv.x; r.x = z > 0.f ? z : 0.f;
      z = (acc[j].y + bb.y) * sc4.y + sh4.y; z += yv.y; z = z > 0.f ? z : 0.1f * z; z += xv.y; r.y = z > 0.f ? z : 0.f;
      z = (acc[j].z + bb.z) * sc4.z + sh4.z; z += yv.z; z = z > 0.f ? z : 0.1f * z; z += xv.z; r.z = z > 0.f ? z : 0.f;
      z = (acc[j].w + bb.w) * sc4.w + sh4.w; z += yv.w; z = z > 0.f ? z : 0.1f * z; z += xv.w; r.w = z > 0.f ? z : 0.f;
      out4[idx] = r;
    }
  }
}

extern "C" void kernel_launch(void* const* d_in, const int* in_sizes, int n_in,
                              void* d_out, int out_size, void* d_ws, size_t ws_size,
                              hipStream_t stream) {
  const float* x      = (const float*)d_in[0];
  const float* w_k    = (const float*)d_in[1];
  const float* b_k    = (const float*)d_in[2];
  const float* w_q    = (const float*)d_in[3];
  const float* b_q    = (const float*)d_in[4];
  const float* alphas = (const float*)d_in[5];
  const float* att0   = (const float*)d_in[6];
  const float* w_out  = (const float*)d_in[7];
  const float* b_out  = (const float*)d_in[8];
  const float* g_out  = (const float*)d_in[9];
  const float* be_out = (const float*)d_in[10];
  const float* m_out  = (const float*)d_in[11];
  const float* v_out  = (const float*)d_in[12];
  const float* w_ff   = (const float*)d_in[13];
  const float* b_ff   = (const float*)d_in[14];
  const float* g_ff   = (const float*)d_in[15];
  const float* be_ff  = (const float*)d_in[16];
  const float* m_ff   = (const float*)d_in[17];
  const float* v_ff   = (const float*)d_in[18];
  const float* w_t    = (const float*)d_in[19];
  const float* b_t    = (const float*)d_in[20];
  const float* g_t    = (const float*)d_in[21];
  const float* be_t   = (const float*)d_in[22];
  const float* m_t    = (const float*)d_in[23];
  const float* v_t    = (const float*)d_in[24];

  float* ws = (float*)d_ws;
  // floats:
  float* qfull = ws;                     //  0          14,848,000  (later y2)
  float* kfull = ws + 14848000;          //             14,745,600  (later y1)
  float* part  = ws + 29593600;          //              2,160,000
  float* att   = ws + 31753600;          //                240,000
  float* wt_cr = ws + 31993600;          //                114,688   (end 32,108,288)
  ushort* xb   = (ushort*)(ws + 32108288);   // 14,745,600 shorts (7,372,800 fl)
  ushort* wb   = (ushort*)(ws + 39481088);   //    131,072 shorts (65,536 fl)
  ushort* H    = (ushort*)(ws + 39546624);   // 117,964,800 shorts (58,982,400 fl)
  const size_t NEED = 98529024ull * 4ull;    // ~394 MB
  float* y1 = kfull;
  float* y2 = qfull;
  float* outp = (float*)d_out;

  k_qk<<<3625, 256, 0, stream>>>(x, w_k, b_k, w_q, b_q, kfull, qfull);
  k_scores<<<dim3(9, 8, 16), 128, 0, stream>>>(kfull, qfull, part);
  k_softmax<<<128, 128, 0, stream>>>(part, alphas, att0, att);
  if (ws_size >= NEED) {
    k_xcvt<<<14400, 256, 0, stream>>>(x, xb);
    k_wcvt<<<512, 256, 0, stream>>>(w_out, wb);
    k_hgemm<<<7200, 256, 0, stream>>>(xb, wb, H);
    k_attn2<<<dim3(36, 16), 256, 0, stream>>>(H, att, x, b_out, g_out, be_out,
                                              m_out, v_out, y1);
  } else {
    k_attn_out<<<dim3(288, 16), 256, 0, stream>>>(x, att, w_out, b_out, g_out,
                                                  be_out, m_out, v_out, y1);
  }
  k_ff<<<3600, 256, 0, stream>>>(y1, x, w_ff, b_ff, g_ff, be_ff, m_ff, v_ff, y2);
  k_wt_tr<<<448, 256, 0, stream>>>(w_t, wt_cr);
  k_tconv<<<512, 512, 0, stream>>>(y2, x, wt_cr, b_t, g_t, be_t, m_t, v_t, outp);
}

// Round 4
// 3165.112 us; speedup vs baseline: 1.6254x; 1.2515x over previous
//
#include <hip/hip_runtime.h>

// SSHA block. Round 4: chunked H-reassociation fitting in round-1's proven
// 128.4 MB workspace (no fallback):
//   wb = bf16(w_out) reindexed [j=(s,o)][c]            (part region, dead space)
//   per 4-n chunk: Hc[rl][j] = sum_c x[row][c]*wb[j][c]  (bf16 MFMA, fp32 x
//     converted in LDS staging; Hc in qfull region, 28.1 MB)
//   k_attn2: O = sum_{w,s,vp} A.Hc + b_out, BN, leaky residual -> y1 (kfull)
// Shapes: N=16, T=288, V=25, C=128, S=8, IC=16, W=3, U=75, TP=290.

#define NN 16
#define TT 288
#define VV 25
#define CC 128
#define SS 8
#define UU 75
#define TP 290
#define EPSF 1e-5f

typedef __attribute__((ext_vector_type(8))) short bf16x8;
typedef __attribute__((ext_vector_type(4))) float f32x4;

static __device__ __forceinline__ void fma4(float4& a, float s, const float4 b) {
  a.x += s * b.x; a.y += s * b.y; a.z += s * b.z; a.w += s * b.w;
}
static __device__ __forceinline__ ushort f2bf(float f) {
  uint u = __float_as_uint(f);
  u = (u + 0x7FFFu + ((u >> 16) & 1u)) >> 16;
  return (ushort)u;
}

// ---------------- K1: k/q 1x1 convs ----------------
__global__ __launch_bounds__(256) void k_qk(
    const float* __restrict__ x,
    const float* __restrict__ w_k, const float* __restrict__ b_k,
    const float* __restrict__ w_q, const float* __restrict__ b_q,
    float* __restrict__ kfull, float* __restrict__ qfull) {
  __shared__ float wk[128 * 129];
  __shared__ float wq[128 * 129];
  __shared__ float xt[128 * 36];
  const int tid = threadIdx.x;
  for (int i = tid; i < 128 * 128; i += 256) {
    int o = i >> 7, c = i & 127;
    wk[o * 129 + c] = w_k[i];
    wq[o * 129 + c] = w_q[i];
  }
  const int base = blockIdx.x * 32;
  for (int i = tid; i < 32 * 128; i += 256) {
    int r = i >> 7, c = i & 127;
    int row = base + r;
    int n = row / (TP * VV);
    int rem = row - n * (TP * VV);
    int tp = rem / VV, v = rem - tp * VV;
    float val = 0.f;
    if (tp >= 1 && tp <= TT) val = x[(((n * TT + (tp - 1)) * VV + v) << 7) + c];
    xt[c * 36 + r] = val;
  }
  __syncthreads();
  const int o = tid & 127;
  const int rh = tid >> 7;
  float acck[16], accq[16];
#pragma unroll
  for (int r = 0; r < 16; ++r) { acck[r] = 0.f; accq[r] = 0.f; }
  const float* wkp = wk + o * 129;
  const float* wqp = wq + o * 129;
  for (int c = 0; c < 128; ++c) {
    float wv0 = wkp[c];
    float wv1 = wqp[c];
    const float4* xp = (const float4*)(xt + c * 36 + rh * 16);
#pragma unroll
    for (int r4 = 0; r4 < 4; ++r4) {
      float4 xv = xp[r4];
      acck[r4 * 4 + 0] += wv0 * xv.x; acck[r4 * 4 + 1] += wv0 * xv.y;
      acck[r4 * 4 + 2] += wv0 * xv.z; acck[r4 * 4 + 3] += wv0 * xv.w;
      accq[r4 * 4 + 0] += wv1 * xv.x; accq[r4 * 4 + 1] += wv1 * xv.y;
      accq[r4 * 4 + 2] += wv1 * xv.z; accq[r4 * 4 + 3] += wv1 * xv.w;
    }
  }
  const float bk = b_k[o], bq = b_q[o];
  for (int r = 0; r < 16; ++r) {
    int row = base + rh * 16 + r;
    int n = row / (TP * VV);
    int rem = row - n * (TP * VV);
    int tp = rem / VV, v = rem - tp * VV;
    qfull[(((n * TP + tp) * VV + v) << 7) + o] = accq[r] + bq;
    if (tp >= 1 && tp <= TT)
      kfull[(((n * TT + (tp - 1)) * VV + v) << 7) + o] = acck[r] + bk;
  }
}

// ---------------- K2a: partial scores ----------------
__global__ __launch_bounds__(128) void k_scores(
    const float* __restrict__ kfull, const float* __restrict__ qfull,
    float* __restrict__ partial) {
  __shared__ float kl[32 * 16 * 28];
  __shared__ float ql[34 * 25 * 17];
  const int tc = blockIdx.x, s = blockIdx.y, n = blockIdx.z;
  const int t0 = tc * 32;
  const int tid = threadIdx.x;
  for (int i = tid; i < 32 * 16 * 28; i += 128) {
    int tt = i / 448;
    int rem = i - tt * 448;
    int ic = rem / 28, v = rem - ic * 28;
    float val = 0.f;
    if (v < 25) val = kfull[(((n * TT + t0 + tt) * VV + v) << 7) + s * 16 + ic];
    kl[i] = val;
  }
  for (int i = tid; i < 34 * 25 * 16; i += 128) {
    int tt = i / 400;
    int rem = i - tt * 400;
    int vp = rem >> 4, ic = rem & 15;
    ql[(tt * 25 + vp) * 17 + ic] =
        qfull[(((n * TP + t0 + tt) * VV + vp) << 7) + s * 16 + ic];
  }
  __syncthreads();
  if (tid < 75) {
    const int w = tid / 25, vp = tid - w * 25;
    float4 acc[7];
#pragma unroll
    for (int j = 0; j < 7; ++j) acc[j] = make_float4(0.f, 0.f, 0.f, 0.f);
    for (int tt = 0; tt < 32; ++tt) {
      const float* qp = ql + ((tt + w) * 25 + vp) * 17;
      const float* kb = kl + tt * 448;
#pragma unroll
      for (int ic = 0; ic < 16; ++ic) {
        float qv = qp[ic];
        const float4* kq = (const float4*)(kb + ic * 28);
#pragma unroll
        for (int j = 0; j < 7; ++j) fma4(acc[j], qv, kq[j]);
      }
    }
    float av[28];
#pragma unroll
    for (int j = 0; j < 7; ++j) *(float4*)(av + 4 * j) = acc[j];
    float* op = partial + ((((n * SS + s) * 9 + tc) * UU) + tid) * VV;
#pragma unroll
    for (int v = 0; v < 25; ++v) op[v] = av[v];
  }
}

// ---------------- K2b: reduce + softmax + att ----------------
__global__ __launch_bounds__(128) void k_softmax(
    const float* __restrict__ partial, const float* __restrict__ alphas,
    const float* __restrict__ att0, float* __restrict__ att) {
  __shared__ float sc[1875];
  __shared__ float mx[25];
  __shared__ float den[25];
  const int ns = blockIdx.x;
  const int s = ns & 7;
  const int tid = threadIdx.x;
  const float inv = 1.0f / 4608.0f;
  for (int i = tid; i < 1875; i += 128) {
    float a = 0.f;
    const float* p = partial + ns * 9 * 1875 + i;
#pragma unroll
    for (int j = 0; j < 9; ++j) a += p[j * 1875];
    sc[i] = a * inv;
  }
  __syncthreads();
  if (tid < 25) {
    float m = -1e30f;
    for (int u = 0; u < 75; ++u) m = fmaxf(m, sc[u * 25 + tid]);
    float d = 0.f;
    for (int u = 0; u < 75; ++u) d += expf(sc[u * 25 + tid] - m);
    mx[tid] = m;
    den[tid] = d;
  }
  __syncthreads();
  const float alpha = alphas[s];
  for (int i = tid; i < 1875; i += 128) {
    int v = i % 25;
    att[ns * 1875 + i] = expf(sc[i] - mx[v]) / den[v] * alpha + att0[s * 1875 + i];
  }
}

// Wb[j=(s*128+o)][c] = bf16(w_out[o*1024 + s*128 + c])
__global__ __launch_bounds__(256) void k_wcvt(const float* __restrict__ w_out,
                                              ushort* __restrict__ wb) {
  int i = blockIdx.x * 256 + threadIdx.x;  // 131072
  int j = i >> 7, c = i & 127;
  int s = j >> 7, o = j & 127;
  wb[i] = f2bf(w_out[(o << 10) + (s << 7) + c]);
}

// ---------------- K3a: H-GEMM chunk (bf16 MFMA, fp32 A converted in staging) ----------------
// Hc[rl][j] = sum_c x[n0*7200+rl][c]*wb[j][c]; rl in [0,28800), j in [0,1024).
// Grid 1800: bm = bx>>3 (225 M-tiles of 128), bn = bx&7. 4 waves (2x2), 64x64 each.
__global__ __launch_bounds__(256) void k_hgemm(const float* __restrict__ x,
                                               const ushort* __restrict__ wb,
                                               ushort* __restrict__ Hc, int n0) {
  __shared__ ushort As[8][128][8];  // [k-group of 8][row][8k] 16KB
  __shared__ ushort Bs[8][128][8];
  const int bx = blockIdx.x;
  const int bm = bx >> 3, bn = bx & 7;
  const int gm0 = bm << 7, gn0 = bn << 7;
  const int tid = threadIdx.x;
  const int lane = tid & 63, wid = tid >> 6;
  const int wm = wid >> 1, wn = wid & 1;
  const int srow = tid & 127;
  const int skg0 = tid >> 7;
  const size_t xbase = ((size_t)n0 * 7200 + gm0) << 7;
  f32x4 acc[4][4] = {};
  for (int kh = 0; kh < 2; ++kh) {
    __syncthreads();
#pragma unroll
    for (int j = 0; j < 4; ++j) {
      int kg = skg0 + 2 * j;
      const float* xp = x + xbase + ((size_t)srow << 7) + kh * 64 + kg * 8;
      float4 a0 = *(const float4*)xp;
      float4 a1 = *(const float4*)(xp + 4);
      uint4 pk;
      pk.x = (uint)f2bf(a0.x) | ((uint)f2bf(a0.y) << 16);
      pk.y = (uint)f2bf(a0.z) | ((uint)f2bf(a0.w) << 16);
      pk.z = (uint)f2bf(a1.x) | ((uint)f2bf(a1.y) << 16);
      pk.w = (uint)f2bf(a1.z) | ((uint)f2bf(a1.w) << 16);
      *(uint4*)&As[kg][srow][0] = pk;
      *(uint4*)&Bs[kg][srow][0] =
          *(const uint4*)&wb[((size_t)(gn0 + srow) << 7) + kh * 64 + kg * 8];
    }
    __syncthreads();
#pragma unroll
    for (int ks = 0; ks < 2; ++ks) {
      int g = ks * 4 + (lane >> 4);
      bf16x8 af[4], bfr[4];
#pragma unroll
      for (int mi = 0; mi < 4; ++mi)
        af[mi] = *(const bf16x8*)&As[g][wm * 64 + mi * 16 + (lane & 15)][0];
#pragma unroll
      for (int ni = 0; ni < 4; ++ni)
        bfr[ni] = *(const bf16x8*)&Bs[g][wn * 64 + ni * 16 + (lane & 15)][0];
#pragma unroll
      for (int mi = 0; mi < 4; ++mi)
#pragma unroll
        for (int ni = 0; ni < 4; ++ni)
          acc[mi][ni] = __builtin_amdgcn_mfma_f32_16x16x32_bf16(
              af[mi], bfr[ni], acc[mi][ni], 0, 0, 0);
    }
  }
  const int r0 = gm0 + wm * 64;
  const int c0 = gn0 + wn * 64;
#pragma unroll
  for (int mi = 0; mi < 4; ++mi)
#pragma unroll
    for (int ni = 0; ni < 4; ++ni) {
      int col = c0 + ni * 16 + (lane & 15);
#pragma unroll
      for (int reg = 0; reg < 4; ++reg) {
        int row = r0 + mi * 16 + ((lane >> 4) << 2) + reg;
        Hc[((size_t)row << 10) + col] = f2bf(acc[mi][ni][reg]);
      }
    }
}

// ---------------- K3b: O = A.Hc + b_out + BN + leaky residual ----------------
// Grid (72, 4): 4 t per block, blockIdx.y = local n. 256 thr:
// og=tid&15 (o=og*8..+7), vg=tid>>4 (v=vg, vg+16).
__global__ __launch_bounds__(256) void k_attn2(
    const ushort* __restrict__ Hc, const float* __restrict__ att,
    const float* __restrict__ x, const float* __restrict__ b_out,
    const float* __restrict__ g_out, const float* __restrict__ beta_out,
    const float* __restrict__ m_out, const float* __restrict__ v_out,
    float* __restrict__ y1, int n0) {
  __shared__ float Al[3][200][32];  // [w][k=vp*8+s][v pad32]
  const int nl = blockIdx.y;
  const int n = n0 + nl;
  const int t0 = blockIdx.x * 4;
  const int tid = threadIdx.x;
  for (int i = tid; i < 19200; i += 256) {
    int w = i / 6400;
    int rem = i - w * 6400;
    int k = rem >> 5, v = rem & 31;
    int vp = k >> 3, s = k & 7;
    float val = 0.f;
    if (v < 25) val = att[((size_t)(n * 8 + s) * 75 + (w * 25 + vp)) * 25 + v];
    Al[w][k][v] = val;
  }
  __syncthreads();
  const int og = tid & 15;
  const int vg = tid >> 4;
  float sc[8], sh[8], bb[8];
#pragma unroll
  for (int j = 0; j < 8; ++j) {
    int o = og * 8 + j;
    float s1 = g_out[o] * rsqrtf(v_out[o] + EPSF);
    sc[j] = s1;
    sh[j] = beta_out[o] - m_out[o] * s1;
    bb[j] = b_out[o];
  }
  const float* Af = &Al[0][0][0];
  for (int tt = 0; tt < 4; ++tt) {
    int t = t0 + tt;
    float acc0[8], acc1[8];
#pragma unroll
    for (int j = 0; j < 8; ++j) { acc0[j] = 0.f; acc1[j] = 0.f; }
    for (int w = 0; w < 3; ++w) {
      int tp = t + w - 1;
      if (tp < 0 || tp >= TT) continue;
      const ushort* hp = Hc + (size_t)(nl * TT + tp) * 25600 + og * 8;
      const float* ap = Af + w * 6400;
      for (int k = 0; k < 200; ++k) {
        uint4 h4 = *(const uint4*)(hp + (k << 7));
        float a0 = ap[(k << 5) + vg];
        float a1 = ap[(k << 5) + vg + 16];
        float f0 = __uint_as_float(h4.x << 16);
        float f1 = __uint_as_float(h4.x & 0xffff0000u);
        float f2 = __uint_as_float(h4.y << 16);
        float f3 = __uint_as_float(h4.y & 0xffff0000u);
        float f4 = __uint_as_float(h4.z << 16);
        float f5 = __uint_as_float(h4.z & 0xffff0000u);
        float f6 = __uint_as_float(h4.w << 16);
        float f7 = __uint_as_float(h4.w & 0xffff0000u);
        acc0[0] += a0 * f0; acc0[1] += a0 * f1; acc0[2] += a0 * f2; acc0[3] += a0 * f3;
        acc0[4] += a0 * f4; acc0[5] += a0 * f5; acc0[6] += a0 * f6; acc0[7] += a0 * f7;
        acc1[0] += a1 * f0; acc1[1] += a1 * f1; acc1[2] += a1 * f2; acc1[3] += a1 * f3;
        acc1[4] += a1 * f4; acc1[5] += a1 * f5; acc1[6] += a1 * f6; acc1[7] += a1 * f7;
      }
    }
    {
      size_t idx = ((size_t)((n * TT + t) * VV + vg) << 7) + og * 8;
      const float* xr = x + idx;
      float* yr = y1 + idx;
#pragma unroll
      for (int j = 0; j < 8; ++j) {
        float a = (acc0[j] + bb[j]) * sc[j] + sh[j];
        float r = xr[j] + a;
        yr[j] = r > 0.f ? r : 0.1f * r;
      }
    }
    if (vg < 9) {
      size_t idx = ((size_t)((n * TT + t) * VV + vg + 16) << 7) + og * 8;
      const float* xr = x + idx;
      float* yr = y1 + idx;
#pragma unroll
      for (int j = 0; j < 8; ++j) {
        float a = (acc1[j] + bb[j]) * sc[j] + sh[j];
        float r = xr[j] + a;
        yr[j] = r > 0.f ? r : 0.1f * r;
      }
    }
  }
}

// ---------------- K4: ff conv + BN + leaky residual ----------------
__global__ __launch_bounds__(256) void k_ff(
    const float* __restrict__ y1, const float* __restrict__ x,
    const float* __restrict__ w_ff, const float* __restrict__ b_ff,
    const float* __restrict__ g_ff, const float* __restrict__ beta_ff,
    const float* __restrict__ m_ff, const float* __restrict__ v_ff,
    float* __restrict__ y2) {
  __shared__ float wl[128 * 129];
  __shared__ float yt[128 * 36];
  const int tid = threadIdx.x;
  for (int i = tid; i < 128 * 128; i += 256)
    wl[(i >> 7) * 129 + (i & 127)] = w_ff[i];
  const int base = blockIdx.x * 32;
  for (int i = tid; i < 32 * 128; i += 256) {
    int r = i >> 7, c = i & 127;
    yt[c * 36 + r] = y1[((base + r) << 7) + c];
  }
  __syncthreads();
  const int o2 = tid & 63;
  const int rq = tid >> 6;
  float acc[2][8];
#pragma unroll
  for (int i = 0; i < 8; ++i) { acc[0][i] = 0.f; acc[1][i] = 0.f; }
  const float* w0 = wl + o2 * 129;
  const float* w1 = wl + (o2 + 64) * 129;
  for (int c = 0; c < 128; ++c) {
    float wv0 = w0[c], wv1 = w1[c];
    const float4* yp = (const float4*)(yt + c * 36 + rq * 8);
    float4 a = yp[0], b = yp[1];
    acc[0][0] += wv0 * a.x; acc[0][1] += wv0 * a.y; acc[0][2] += wv0 * a.z; acc[0][3] += wv0 * a.w;
    acc[0][4] += wv0 * b.x; acc[0][5] += wv0 * b.y; acc[0][6] += wv0 * b.z; acc[0][7] += wv0 * b.w;
    acc[1][0] += wv1 * a.x; acc[1][1] += wv1 * a.y; acc[1][2] += wv1 * a.z; acc[1][3] += wv1 * a.w;
    acc[1][4] += wv1 * b.x; acc[1][5] += wv1 * b.y; acc[1][6] += wv1 * b.z; acc[1][7] += wv1 * b.w;
  }
#pragma unroll
  for (int oi = 0; oi < 2; ++oi) {
    int o = o2 + 64 * oi;
    float scale = g_ff[o] * rsqrtf(v_ff[o] + EPSF);
    float sh = beta_ff[o] - m_ff[o] * scale;
    float bb = b_ff[o];
#pragma unroll
    for (int r = 0; r < 8; ++r) {
      int row = base + rq * 8 + r;
      float a = (acc[oi][r] + bb) * scale + sh;
      float rr = x[(row << 7) + o] + a;
      y2[(row << 7) + o] = rr > 0.f ? rr : 0.1f * rr;
    }
  }
}

// ---------------- K5a: transpose w_t (o,c,kt) -> wt_cr[kt][c][o] ----------------
__global__ __launch_bounds__(256) void k_wt_tr(const float* __restrict__ w_t,
                                               float* __restrict__ wt_cr) {
  int i = blockIdx.x * 256 + threadIdx.x;
  if (i < 128 * 128 * 7) {
    int o = i / 896;
    int rem = i - o * 896;
    int c = rem / 7, kt = rem - c * 7;
    wt_cr[(kt * 128 + c) * 128 + o] = w_t[i];
  }
}

// ---------------- K5: temporal conv 7x1 + BN + leaky + relu residual ----------------
__global__ __launch_bounds__(512, 4) void k_tconv(
    const float* __restrict__ y2, const float* __restrict__ x,
    const float* __restrict__ wt_cr, const float* __restrict__ b_t,
    const float* __restrict__ g_t, const float* __restrict__ beta_t,
    const float* __restrict__ m_t, const float* __restrict__ v_t,
    float* __restrict__ out) {
  __shared__ float wl[128 * 128];
  const int blk = blockIdx.x;
  const int n = blk >> 5;
  const int r0 = (blk & 31) * 225;
  const int tid = threadIdx.x;
  const int o4 = tid & 31;
  const int rgrp = tid >> 5;
  const int rowbase = rgrp * 15;
  const float4* y2n4 = (const float4*)(y2 + (size_t)n * 7200 * 128);
  const bool edge = (r0 == 0) || (r0 == 7200 - 225);
  float4 acc[15];
#pragma unroll
  for (int j = 0; j < 15; ++j) acc[j] = make_float4(0.f, 0.f, 0.f, 0.f);
  for (int kt = 0; kt < 7; ++kt) {
    __syncthreads();
    {
      const float4* wsrc = (const float4*)(wt_cr + kt * 16384);
      float4* wd = (float4*)wl;
      for (int i = tid; i < 4096; i += 512) wd[i] = wsrc[i];
    }
    __syncthreads();
    const int shift = (kt - 3) * 25;
    const float4* wl4 = (const float4*)wl;
    if (!edge) {
      for (int c4 = 0; c4 < 32; ++c4) {
        float4 w0 = wl4[(4 * c4 + 0) * 32 + o4];
        float4 w1 = wl4[(4 * c4 + 1) * 32 + o4];
        float4 w2 = wl4[(4 * c4 + 2) * 32 + o4];
        float4 w3 = wl4[(4 * c4 + 3) * 32 + o4];
#pragma unroll
        for (int j = 0; j < 15; ++j) {
          int src = r0 + rowbase + j + shift;
          float4 a = y2n4[src * 32 + c4];
          fma4(acc[j], a.x, w0); fma4(acc[j], a.y, w1);
          fma4(acc[j], a.z, w2); fma4(acc[j], a.w, w3);
        }
      }
    } else {
      for (int c4 = 0; c4 < 32; ++c4) {
        float4 w0 = wl4[(4 * c4 + 0) * 32 + o4];
        float4 w1 = wl4[(4 * c4 + 1) * 32 + o4];
        float4 w2 = wl4[(4 * c4 + 2) * 32 + o4];
        float4 w3 = wl4[(4 * c4 + 3) * 32 + o4];
#pragma unroll
        for (int j = 0; j < 15; ++j) {
          int src = r0 + rowbase + j + shift;
          bool valid = (src >= 0) && (src < 7200);
          int scc = valid ? src : 0;
          float4 a = y2n4[scc * 32 + c4];
          if (!valid) a = make_float4(0.f, 0.f, 0.f, 0.f);
          fma4(acc[j], a.x, w0); fma4(acc[j], a.y, w1);
          fma4(acc[j], a.z, w2); fma4(acc[j], a.w, w3);
        }
      }
    }
  }
  float4 gg = ((const float4*)g_t)[o4];
  float4 vv = ((const float4*)v_t)[o4];
  float4 mm = ((const float4*)m_t)[o4];
  float4 be = ((const float4*)beta_t)[o4];
  float4 bb = ((const float4*)b_t)[o4];
  float4 sc4, sh4;
  sc4.x = gg.x * rsqrtf(vv.x + EPSF); sc4.y = gg.y * rsqrtf(vv.y + EPSF);
  sc4.z = gg.z * rsqrtf(vv.z + EPSF); sc4.w = gg.w * rsqrtf(vv.w + EPSF);
  sh4.x = be.x - mm.x * sc4.x; sh4.y = be.y - mm.y * sc4.y;
  sh4.z = be.z - mm.z * sc4.z; sh4.w = be.w - mm.w * sc4.w;
  const float4* y24 = (const float4*)y2;
  const float4* x4 = (const float4*)x;
  float4* out4 = (float4*)out;
#pragma unroll
  for (int j = 0; j < 15; ++j) {
    int row = rowbase + j;
    if (row < 225) {
      int idx = (n * 7200 + r0 + row) * 32 + o4;
      float4 yv = y24[idx];
      float4 xv = x4[idx];
      float4 r;
      float z;
      z = (acc[j].x + bb.x) * sc4.x + sh4.x; z += yv.x; z = z > 0.f ? z : 0.1f * z; z += xv.x; r.x = z > 0.f ? z : 0.f;
      z = (acc[j].y + bb.y) * sc4.y + sh4.y; z += yv.y; z = z > 0.f ? z : 0.1f * z; z += xv.y; r.y = z > 0.f ? z : 0.f;
      z = (acc[j].z + bb.z) * sc4.z + sh4.z; z += yv.z; z = z > 0.f ? z : 0.1f * z; z += xv.z; r.z = z > 0.f ? z : 0.f;
      z = (acc[j].w + bb.w) * sc4.w + sh4.w; z += yv.w; z = z > 0.f ? z : 0.1f * z; z += xv.w; r.w = z > 0.f ? z : 0.f;
      out4[idx] = r;
    }
  }
}

extern "C" void kernel_launch(void* const* d_in, const int* in_sizes, int n_in,
                              void* d_out, int out_size, void* d_ws, size_t ws_size,
                              hipStream_t stream) {
  const float* x      = (const float*)d_in[0];
  const float* w_k    = (const float*)d_in[1];
  const float* b_k    = (const float*)d_in[2];
  const float* w_q    = (const float*)d_in[3];
  const float* b_q    = (const float*)d_in[4];
  const float* alphas = (const float*)d_in[5];
  const float* att0   = (const float*)d_in[6];
  const float* w_out  = (const float*)d_in[7];
  const float* b_out  = (const float*)d_in[8];
  const float* g_out  = (const float*)d_in[9];
  const float* be_out = (const float*)d_in[10];
  const float* m_out  = (const float*)d_in[11];
  const float* v_out  = (const float*)d_in[12];
  const float* w_ff   = (const float*)d_in[13];
  const float* b_ff   = (const float*)d_in[14];
  const float* g_ff   = (const float*)d_in[15];
  const float* be_ff  = (const float*)d_in[16];
  const float* m_ff   = (const float*)d_in[17];
  const float* v_ff   = (const float*)d_in[18];
  const float* w_t    = (const float*)d_in[19];
  const float* b_t    = (const float*)d_in[20];
  const float* g_t    = (const float*)d_in[21];
  const float* be_t   = (const float*)d_in[22];
  const float* m_t    = (const float*)d_in[23];
  const float* v_t    = (const float*)d_in[24];

  float* ws = (float*)d_ws;
  // Region plan (floats), total 32,108,288 = round-1 proven footprint:
  float* qfull = ws;               // [0, 14848000)  later: Hc (bf16) then y2
  float* kfull = ws + 14848000;    // [.., +14745600) later: y1
  float* part  = ws + 29593600;    // [.., +2160000)  later: wb (bf16, 65536 fl)
  float* att   = ws + 31753600;    // [.., +240000)
  float* wt_cr = ws + 31993600;    // [.., +114688)
  ushort* Hc = (ushort*)qfull;     // 4n chunk: 29,491,200 shorts = 14,745,600 fl
  ushort* wb = (ushort*)part;
  float* y1 = kfull;
  float* y2 = qfull;
  float* outp = (float*)d_out;

  k_qk<<<3625, 256, 0, stream>>>(x, w_k, b_k, w_q, b_q, kfull, qfull);
  k_scores<<<dim3(9, 8, 16), 128, 0, stream>>>(kfull, qfull, part);
  k_softmax<<<128, 128, 0, stream>>>(part, alphas, att0, att);
  k_wcvt<<<512, 256, 0, stream>>>(w_out, wb);
  for (int n0 = 0; n0 < 16; n0 += 4) {
    k_hgemm<<<1800, 256, 0, stream>>>(x, wb, Hc, n0);
    k_attn2<<<dim3(72, 4), 256, 0, stream>>>(Hc, att, x, b_out, g_out, be_out,
                                             m_out, v_out, y1, n0);
  }
  k_ff<<<3600, 256, 0, stream>>>(y1, x, w_ff, b_ff, g_ff, be_ff, m_ff, v_ff, y2);
  k_wt_tr<<<448, 256, 0, stream>>>(w_t, wt_cr);
  k_tconv<<<512, 512, 0, stream>>>(y2, x, wt_cr, b_t, g_t, be_t, m_t, v_t, outp);
}

// Round 5
// 2102.579 us; speedup vs baseline: 2.4467x; 1.5053x over previous
//
#include <hip/hip_runtime.h>

// SSHA block. Round 5: k_tconv rewritten as bf16 MFMA GEMM.
//   tconv: out[r,o] = sum_{kt,c} y2[r+25*(kt-3), c] * w_t[o,c,kt]
//   => K=896 GEMM where the 7 K-chunks are row-shifted views of y2.
//   Per block: 278-row x 128-col bf16 A-ext slab in LDS (XOR-swizzled),
//   B = wbt[o][kt*128+c] bf16 streamed from L2 into fragments, 64x64/wave.
// Attn stage unchanged from round 4 (chunked H-reassociation, bf16 MFMA).
// Shapes: N=16, T=288, V=25, C=128, S=8, IC=16, W=3, U=75, TP=290.

#define NN 16
#define TT 288
#define VV 25
#define CC 128
#define SS 8
#define UU 75
#define TP 290
#define EPSF 1e-5f

typedef __attribute__((ext_vector_type(8))) short bf16x8;
typedef __attribute__((ext_vector_type(4))) float f32x4;

static __device__ __forceinline__ void fma4(float4& a, float s, const float4 b) {
  a.x += s * b.x; a.y += s * b.y; a.z += s * b.z; a.w += s * b.w;
}
static __device__ __forceinline__ ushort f2bf(float f) {
  uint u = __float_as_uint(f);
  u = (u + 0x7FFFu + ((u >> 16) & 1u)) >> 16;
  return (ushort)u;
}

// ---------------- K1: k/q 1x1 convs ----------------
__global__ __launch_bounds__(256) void k_qk(
    const float* __restrict__ x,
    const float* __restrict__ w_k, const float* __restrict__ b_k,
    const float* __restrict__ w_q, const float* __restrict__ b_q,
    float* __restrict__ kfull, float* __restrict__ qfull) {
  __shared__ float wk[128 * 129];
  __shared__ float wq[128 * 129];
  __shared__ float xt[128 * 36];
  const int tid = threadIdx.x;
  for (int i = tid; i < 128 * 128; i += 256) {
    int o = i >> 7, c = i & 127;
    wk[o * 129 + c] = w_k[i];
    wq[o * 129 + c] = w_q[i];
  }
  const int base = blockIdx.x * 32;
  for (int i = tid; i < 32 * 128; i += 256) {
    int r = i >> 7, c = i & 127;
    int row = base + r;
    int n = row / (TP * VV);
    int rem = row - n * (TP * VV);
    int tp = rem / VV, v = rem - tp * VV;
    float val = 0.f;
    if (tp >= 1 && tp <= TT) val = x[(((n * TT + (tp - 1)) * VV + v) << 7) + c];
    xt[c * 36 + r] = val;
  }
  __syncthreads();
  const int o = tid & 127;
  const int rh = tid >> 7;
  float acck[16], accq[16];
#pragma unroll
  for (int r = 0; r < 16; ++r) { acck[r] = 0.f; accq[r] = 0.f; }
  const float* wkp = wk + o * 129;
  const float* wqp = wq + o * 129;
  for (int c = 0; c < 128; ++c) {
    float wv0 = wkp[c];
    float wv1 = wqp[c];
    const float4* xp = (const float4*)(xt + c * 36 + rh * 16);
#pragma unroll
    for (int r4 = 0; r4 < 4; ++r4) {
      float4 xv = xp[r4];
      acck[r4 * 4 + 0] += wv0 * xv.x; acck[r4 * 4 + 1] += wv0 * xv.y;
      acck[r4 * 4 + 2] += wv0 * xv.z; acck[r4 * 4 + 3] += wv0 * xv.w;
      accq[r4 * 4 + 0] += wv1 * xv.x; accq[r4 * 4 + 1] += wv1 * xv.y;
      accq[r4 * 4 + 2] += wv1 * xv.z; accq[r4 * 4 + 3] += wv1 * xv.w;
    }
  }
  const float bk = b_k[o], bq = b_q[o];
  for (int r = 0; r < 16; ++r) {
    int row = base + rh * 16 + r;
    int n = row / (TP * VV);
    int rem = row - n * (TP * VV);
    int tp = rem / VV, v = rem - tp * VV;
    qfull[(((n * TP + tp) * VV + v) << 7) + o] = accq[r] + bq;
    if (tp >= 1 && tp <= TT)
      kfull[(((n * TT + (tp - 1)) * VV + v) << 7) + o] = acck[r] + bk;
  }
}

// ---------------- K2a: partial scores ----------------
__global__ __launch_bounds__(128) void k_scores(
    const float* __restrict__ kfull, const float* __restrict__ qfull,
    float* __restrict__ partial) {
  __shared__ float kl[32 * 16 * 28];
  __shared__ float ql[34 * 25 * 17];
  const int tc = blockIdx.x, s = blockIdx.y, n = blockIdx.z;
  const int t0 = tc * 32;
  const int tid = threadIdx.x;
  for (int i = tid; i < 32 * 16 * 28; i += 128) {
    int tt = i / 448;
    int rem = i - tt * 448;
    int ic = rem / 28, v = rem - ic * 28;
    float val = 0.f;
    if (v < 25) val = kfull[(((n * TT + t0 + tt) * VV + v) << 7) + s * 16 + ic];
    kl[i] = val;
  }
  for (int i = tid; i < 34 * 25 * 16; i += 128) {
    int tt = i / 400;
    int rem = i - tt * 400;
    int vp = rem >> 4, ic = rem & 15;
    ql[(tt * 25 + vp) * 17 + ic] =
        qfull[(((n * TP + t0 + tt) * VV + vp) << 7) + s * 16 + ic];
  }
  __syncthreads();
  if (tid < 75) {
    const int w = tid / 25, vp = tid - w * 25;
    float4 acc[7];
#pragma unroll
    for (int j = 0; j < 7; ++j) acc[j] = make_float4(0.f, 0.f, 0.f, 0.f);
    for (int tt = 0; tt < 32; ++tt) {
      const float* qp = ql + ((tt + w) * 25 + vp) * 17;
      const float* kb = kl + tt * 448;
#pragma unroll
      for (int ic = 0; ic < 16; ++ic) {
        float qv = qp[ic];
        const float4* kq = (const float4*)(kb + ic * 28);
#pragma unroll
        for (int j = 0; j < 7; ++j) fma4(acc[j], qv, kq[j]);
      }
    }
    float av[28];
#pragma unroll
    for (int j = 0; j < 7; ++j) *(float4*)(av + 4 * j) = acc[j];
    float* op = partial + ((((n * SS + s) * 9 + tc) * UU) + tid) * VV;
#pragma unroll
    for (int v = 0; v < 25; ++v) op[v] = av[v];
  }
}

// ---------------- K2b: reduce + softmax + att ----------------
__global__ __launch_bounds__(128) void k_softmax(
    const float* __restrict__ partial, const float* __restrict__ alphas,
    const float* __restrict__ att0, float* __restrict__ att) {
  __shared__ float sc[1875];
  __shared__ float mx[25];
  __shared__ float den[25];
  const int ns = blockIdx.x;
  const int s = ns & 7;
  const int tid = threadIdx.x;
  const float inv = 1.0f / 4608.0f;
  for (int i = tid; i < 1875; i += 128) {
    float a = 0.f;
    const float* p = partial + ns * 9 * 1875 + i;
#pragma unroll
    for (int j = 0; j < 9; ++j) a += p[j * 1875];
    sc[i] = a * inv;
  }
  __syncthreads();
  if (tid < 25) {
    float m = -1e30f;
    for (int u = 0; u < 75; ++u) m = fmaxf(m, sc[u * 25 + tid]);
    float d = 0.f;
    for (int u = 0; u < 75; ++u) d += expf(sc[u * 25 + tid] - m);
    mx[tid] = m;
    den[tid] = d;
  }
  __syncthreads();
  const float alpha = alphas[s];
  for (int i = tid; i < 1875; i += 128) {
    int v = i % 25;
    att[ns * 1875 + i] = expf(sc[i] - mx[v]) / den[v] * alpha + att0[s * 1875 + i];
  }
}

// Wb[j=(s*128+o)][c] = bf16(w_out[o*1024 + s*128 + c])
__global__ __launch_bounds__(256) void k_wcvt(const float* __restrict__ w_out,
                                              ushort* __restrict__ wb) {
  int i = blockIdx.x * 256 + threadIdx.x;  // 131072
  int j = i >> 7, c = i & 127;
  int s = j >> 7, o = j & 127;
  wb[i] = f2bf(w_out[(o << 10) + (s << 7) + c]);
}

// ---------------- K3a: H-GEMM chunk (bf16 MFMA) ----------------
__global__ __launch_bounds__(256) void k_hgemm(const float* __restrict__ x,
                                               const ushort* __restrict__ wb,
                                               ushort* __restrict__ Hc, int n0) {
  __shared__ ushort As[8][128][8];
  __shared__ ushort Bs[8][128][8];
  const int bx = blockIdx.x;
  const int bm = bx >> 3, bn = bx & 7;
  const int gm0 = bm << 7, gn0 = bn << 7;
  const int tid = threadIdx.x;
  const int lane = tid & 63, wid = tid >> 6;
  const int wm = wid >> 1, wn = wid & 1;
  const int srow = tid & 127;
  const int skg0 = tid >> 7;
  const size_t xbase = ((size_t)n0 * 7200 + gm0) << 7;
  f32x4 acc[4][4] = {};
  for (int kh = 0; kh < 2; ++kh) {
    __syncthreads();
#pragma unroll
    for (int j = 0; j < 4; ++j) {
      int kg = skg0 + 2 * j;
      const float* xp = x + xbase + ((size_t)srow << 7) + kh * 64 + kg * 8;
      float4 a0 = *(const float4*)xp;
      float4 a1 = *(const float4*)(xp + 4);
      uint4 pk;
      pk.x = (uint)f2bf(a0.x) | ((uint)f2bf(a0.y) << 16);
      pk.y = (uint)f2bf(a0.z) | ((uint)f2bf(a0.w) << 16);
      pk.z = (uint)f2bf(a1.x) | ((uint)f2bf(a1.y) << 16);
      pk.w = (uint)f2bf(a1.z) | ((uint)f2bf(a1.w) << 16);
      *(uint4*)&As[kg][srow][0] = pk;
      *(uint4*)&Bs[kg][srow][0] =
          *(const uint4*)&wb[((size_t)(gn0 + srow) << 7) + kh * 64 + kg * 8];
    }
    __syncthreads();
#pragma unroll
    for (int ks = 0; ks < 2; ++ks) {
      int g = ks * 4 + (lane >> 4);
      bf16x8 af[4], bfr[4];
#pragma unroll
      for (int mi = 0; mi < 4; ++mi)
        af[mi] = *(const bf16x8*)&As[g][wm * 64 + mi * 16 + (lane & 15)][0];
#pragma unroll
      for (int ni = 0; ni < 4; ++ni)
        bfr[ni] = *(const bf16x8*)&Bs[g][wn * 64 + ni * 16 + (lane & 15)][0];
#pragma unroll
      for (int mi = 0; mi < 4; ++mi)
#pragma unroll
        for (int ni = 0; ni < 4; ++ni)
          acc[mi][ni] = __builtin_amdgcn_mfma_f32_16x16x32_bf16(
              af[mi], bfr[ni], acc[mi][ni], 0, 0, 0);
    }
  }
  const int r0 = gm0 + wm * 64;
  const int c0 = gn0 + wn * 64;
#pragma unroll
  for (int mi = 0; mi < 4; ++mi)
#pragma unroll
    for (int ni = 0; ni < 4; ++ni) {
      int col = c0 + ni * 16 + (lane & 15);
#pragma unroll
      for (int reg = 0; reg < 4; ++reg) {
        int row = r0 + mi * 16 + ((lane >> 4) << 2) + reg;
        Hc[((size_t)row << 10) + col] = f2bf(acc[mi][ni][reg]);
      }
    }
}

// ---------------- K3b: O = A.Hc + b_out + BN + leaky residual ----------------
__global__ __launch_bounds__(256) void k_attn2(
    const ushort* __restrict__ Hc, const float* __restrict__ att,
    const float* __restrict__ x, const float* __restrict__ b_out,
    const float* __restrict__ g_out, const float* __restrict__ beta_out,
    const float* __restrict__ m_out, const float* __restrict__ v_out,
    float* __restrict__ y1, int n0) {
  __shared__ float Al[3][200][32];
  const int nl = blockIdx.y;
  const int n = n0 + nl;
  const int t0 = blockIdx.x * 4;
  const int tid = threadIdx.x;
  for (int i = tid; i < 19200; i += 256) {
    int w = i / 6400;
    int rem = i - w * 6400;
    int k = rem >> 5, v = rem & 31;
    int vp = k >> 3, s = k & 7;
    float val = 0.f;
    if (v < 25) val = att[((size_t)(n * 8 + s) * 75 + (w * 25 + vp)) * 25 + v];
    Al[w][k][v] = val;
  }
  __syncthreads();
  const int og = tid & 15;
  const int vg = tid >> 4;
  float sc[8], sh[8], bb[8];
#pragma unroll
  for (int j = 0; j < 8; ++j) {
    int o = og * 8 + j;
    float s1 = g_out[o] * rsqrtf(v_out[o] + EPSF);
    sc[j] = s1;
    sh[j] = beta_out[o] - m_out[o] * s1;
    bb[j] = b_out[o];
  }
  const float* Af = &Al[0][0][0];
  for (int tt = 0; tt < 4; ++tt) {
    int t = t0 + tt;
    float acc0[8], acc1[8];
#pragma unroll
    for (int j = 0; j < 8; ++j) { acc0[j] = 0.f; acc1[j] = 0.f; }
    for (int w = 0; w < 3; ++w) {
      int tp = t + w - 1;
      if (tp < 0 || tp >= TT) continue;
      const ushort* hp = Hc + (size_t)(nl * TT + tp) * 25600 + og * 8;
      const float* ap = Af + w * 6400;
      for (int k = 0; k < 200; ++k) {
        uint4 h4 = *(const uint4*)(hp + (k << 7));
        float a0 = ap[(k << 5) + vg];
        float a1 = ap[(k << 5) + vg + 16];
        float f0 = __uint_as_float(h4.x << 16);
        float f1 = __uint_as_float(h4.x & 0xffff0000u);
        float f2 = __uint_as_float(h4.y << 16);
        float f3 = __uint_as_float(h4.y & 0xffff0000u);
        float f4 = __uint_as_float(h4.z << 16);
        float f5 = __uint_as_float(h4.z & 0xffff0000u);
        float f6 = __uint_as_float(h4.w << 16);
        float f7 = __uint_as_float(h4.w & 0xffff0000u);
        acc0[0] += a0 * f0; acc0[1] += a0 * f1; acc0[2] += a0 * f2; acc0[3] += a0 * f3;
        acc0[4] += a0 * f4; acc0[5] += a0 * f5; acc0[6] += a0 * f6; acc0[7] += a0 * f7;
        acc1[0] += a1 * f0; acc1[1] += a1 * f1; acc1[2] += a1 * f2; acc1[3] += a1 * f3;
        acc1[4] += a1 * f4; acc1[5] += a1 * f5; acc1[6] += a1 * f6; acc1[7] += a1 * f7;
      }
    }
    {
      size_t idx = ((size_t)((n * TT + t) * VV + vg) << 7) + og * 8;
      const float* xr = x + idx;
      float* yr = y1 + idx;
#pragma unroll
      for (int j = 0; j < 8; ++j) {
        float a = (acc0[j] + bb[j]) * sc[j] + sh[j];
        float r = xr[j] + a;
        yr[j] = r > 0.f ? r : 0.1f * r;
      }
    }
    if (vg < 9) {
      size_t idx = ((size_t)((n * TT + t) * VV + vg + 16) << 7) + og * 8;
      const float* xr = x + idx;
      float* yr = y1 + idx;
#pragma unroll
      for (int j = 0; j < 8; ++j) {
        float a = (acc1[j] + bb[j]) * sc[j] + sh[j];
        float r = xr[j] + a;
        yr[j] = r > 0.f ? r : 0.1f * r;
      }
    }
  }
}

// ---------------- K4: ff conv + BN + leaky residual ----------------
__global__ __launch_bounds__(256) void k_ff(
    const float* __restrict__ y1, const float* __restrict__ x,
    const float* __restrict__ w_ff, const float* __restrict__ b_ff,
    const float* __restrict__ g_ff, const float* __restrict__ beta_ff,
    const float* __restrict__ m_ff, const float* __restrict__ v_ff,
    float* __restrict__ y2) {
  __shared__ float wl[128 * 129];
  __shared__ float yt[128 * 36];
  const int tid = threadIdx.x;
  for (int i = tid; i < 128 * 128; i += 256)
    wl[(i >> 7) * 129 + (i & 127)] = w_ff[i];
  const int base = blockIdx.x * 32;
  for (int i = tid; i < 32 * 128; i += 256) {
    int r = i >> 7, c = i & 127;
    yt[c * 36 + r] = y1[((base + r) << 7) + c];
  }
  __syncthreads();
  const int o2 = tid & 63;
  const int rq = tid >> 6;
  float acc[2][8];
#pragma unroll
  for (int i = 0; i < 8; ++i) { acc[0][i] = 0.f; acc[1][i] = 0.f; }
  const float* w0 = wl + o2 * 129;
  const float* w1 = wl + (o2 + 64) * 129;
  for (int c = 0; c < 128; ++c) {
    float wv0 = w0[c], wv1 = w1[c];
    const float4* yp = (const float4*)(yt + c * 36 + rq * 8);
    float4 a = yp[0], b = yp[1];
    acc[0][0] += wv0 * a.x; acc[0][1] += wv0 * a.y; acc[0][2] += wv0 * a.z; acc[0][3] += wv0 * a.w;
    acc[0][4] += wv0 * b.x; acc[0][5] += wv0 * b.y; acc[0][6] += wv0 * b.z; acc[0][7] += wv0 * b.w;
    acc[1][0] += wv1 * a.x; acc[1][1] += wv1 * a.y; acc[1][2] += wv1 * a.z; acc[1][3] += wv1 * a.w;
    acc[1][4] += wv1 * b.x; acc[1][5] += wv1 * b.y; acc[1][6] += wv1 * b.z; acc[1][7] += wv1 * b.w;
  }
#pragma unroll
  for (int oi = 0; oi < 2; ++oi) {
    int o = o2 + 64 * oi;
    float scale = g_ff[o] * rsqrtf(v_ff[o] + EPSF);
    float sh = beta_ff[o] - m_ff[o] * scale;
    float bb = b_ff[o];
#pragma unroll
    for (int r = 0; r < 8; ++r) {
      int row = base + rq * 8 + r;
      float a = (acc[oi][r] + bb) * scale + sh;
      float rr = x[(row << 7) + o] + a;
      y2[(row << 7) + o] = rr > 0.f ? rr : 0.1f * rr;
    }
  }
}

// ---------------- K5a: w_t (o,c,kt) -> bf16 wbt[o][kt*128+c] ----------------
__global__ __launch_bounds__(256) void k_wtb(const float* __restrict__ w_t,
                                             ushort* __restrict__ wbt) {
  int i = blockIdx.x * 256 + threadIdx.x;
  if (i < 128 * 128 * 7) {
    int o = i / 896;
    int rem = i - o * 896;
    int c = rem / 7, kt = rem - c * 7;
    wbt[o * 896 + kt * 128 + c] = f2bf(w_t[i]);
  }
}

// ---------------- K5: temporal conv as bf16 MFMA GEMM ----------------
// out[r, o] = sum_{kt, c} y2[r + 25*(kt-3), c] * wbt[o][kt*128+c]
// Grid (57, 16): 128-row M-tile per block within one n. 256 thr = 4 waves (2x2),
// each wave 64x64. A-ext: rows r0-75 .. r0+202 (278) in LDS bf16, XOR-swizzled.
__global__ __launch_bounds__(256, 2) void k_tconv(
    const float* __restrict__ y2, const float* __restrict__ x,
    const ushort* __restrict__ wbt, const float* __restrict__ b_t,
    const float* __restrict__ g_t, const float* __restrict__ beta_t,
    const float* __restrict__ m_t, const float* __restrict__ v_t,
    float* __restrict__ out) {
  __shared__ uint4 As[280 * 16];  // [row][16B-chunk], chunk idx ^= (row&7)
  const int n = blockIdx.y;
  const int r0 = blockIdx.x << 7;
  const int tid = threadIdx.x;
  const float* y2n = y2 + ((size_t)n * 7200 << 7);
  // stage A-ext: rows r0-75 .. r0+202, fp32 -> bf16, swizzled
  for (int i = tid; i < 278 * 16; i += 256) {
    int rl = i >> 4, cc = i & 15;
    int g = r0 - 75 + rl;
    uint4 pk = make_uint4(0u, 0u, 0u, 0u);
    if (g >= 0 && g < 7200) {
      const float* xp = y2n + ((size_t)g << 7) + (cc << 3);
      float4 a0 = *(const float4*)xp;
      float4 a1 = *(const float4*)(xp + 4);
      pk.x = (uint)f2bf(a0.x) | ((uint)f2bf(a0.y) << 16);
      pk.y = (uint)f2bf(a0.z) | ((uint)f2bf(a0.w) << 16);
      pk.z = (uint)f2bf(a1.x) | ((uint)f2bf(a1.y) << 16);
      pk.w = (uint)f2bf(a1.z) | ((uint)f2bf(a1.w) << 16);
    }
    As[(rl << 4) + (cc ^ (rl & 7))] = pk;
  }
  __syncthreads();
  const int lane = tid & 63, wid = tid >> 6;
  const int wm = wid >> 1, wn = wid & 1;
  const int l15 = lane & 15, l4 = lane >> 4;
  f32x4 acc[4][4] = {};
  for (int kt = 0; kt < 7; ++kt) {
    // B frags for this kt: bfr[ni][cc0], o = wn*64+ni*16+l15, k = kt*128+cc0*32+l4*8
    bf16x8 bfr[4][4];
#pragma unroll
    for (int ni = 0; ni < 4; ++ni) {
      const ushort* bp =
          wbt + (size_t)(wn * 64 + ni * 16 + l15) * 896 + kt * 128 + l4 * 8;
#pragma unroll
      for (int cc0 = 0; cc0 < 4; ++cc0)
        bfr[ni][cc0] = *(const bf16x8*)(bp + cc0 * 32);
    }
#pragma unroll
    for (int cc0 = 0; cc0 < 4; ++cc0) {
      bf16x8 af[4];
#pragma unroll
      for (int mi = 0; mi < 4; ++mi) {
        int rl = wm * 64 + mi * 16 + l15 + 25 * kt;
        af[mi] = *(const bf16x8*)&As[(rl << 4) + ((cc0 * 4 + l4) ^ (rl & 7))];
      }
#pragma unroll
      for (int mi = 0; mi < 4; ++mi)
#pragma unroll
        for (int ni = 0; ni < 4; ++ni)
          acc[mi][ni] = __builtin_amdgcn_mfma_f32_16x16x32_bf16(
              af[mi], bfr[ni][cc0], acc[mi][ni], 0, 0, 0);
    }
  }
  // epilogue: per ni BN params, then BN + leaky(y2+z) + relu(+x)
#pragma unroll
  for (int ni = 0; ni < 4; ++ni) {
    int o = wn * 64 + ni * 16 + l15;
    float s1 = g_t[o] * rsqrtf(v_t[o] + EPSF);
    float sh = beta_t[o] - m_t[o] * s1;
    float bb = b_t[o];
#pragma unroll
    for (int mi = 0; mi < 4; ++mi) {
#pragma unroll
      for (int reg = 0; reg < 4; ++reg) {
        int grow = r0 + wm * 64 + mi * 16 + (l4 << 2) + reg;
        if (grow < 7200) {
          size_t idx = (((size_t)n * 7200 + grow) << 7) + o;
          float z = (acc[mi][ni][reg] + bb) * s1 + sh;
          z += y2[idx];
          z = z > 0.f ? z : 0.1f * z;
          z += x[idx];
          out[idx] = z > 0.f ? z : 0.f;
        }
      }
    }
  }
}

extern "C" void kernel_launch(void* const* d_in, const int* in_sizes, int n_in,
                              void* d_out, int out_size, void* d_ws, size_t ws_size,
                              hipStream_t stream) {
  const float* x      = (const float*)d_in[0];
  const float* w_k    = (const float*)d_in[1];
  const float* b_k    = (const float*)d_in[2];
  const float* w_q    = (const float*)d_in[3];
  const float* b_q    = (const float*)d_in[4];
  const float* alphas = (const float*)d_in[5];
  const float* att0   = (const float*)d_in[6];
  const float* w_out  = (const float*)d_in[7];
  const float* b_out  = (const float*)d_in[8];
  const float* g_out  = (const float*)d_in[9];
  const float* be_out = (const float*)d_in[10];
  const float* m_out  = (const float*)d_in[11];
  const float* v_out  = (const float*)d_in[12];
  const float* w_ff   = (const float*)d_in[13];
  const float* b_ff   = (const float*)d_in[14];
  const float* g_ff   = (const float*)d_in[15];
  const float* be_ff  = (const float*)d_in[16];
  const float* m_ff   = (const float*)d_in[17];
  const float* v_ff   = (const float*)d_in[18];
  const float* w_t    = (const float*)d_in[19];
  const float* b_t    = (const float*)d_in[20];
  const float* g_t    = (const float*)d_in[21];
  const float* be_t   = (const float*)d_in[22];
  const float* m_t    = (const float*)d_in[23];
  const float* v_t    = (const float*)d_in[24];

  float* ws = (float*)d_ws;
  // Region plan (floats), total 32,108,288 = round-1 proven footprint:
  float* qfull = ws;               // [0, 14848000)  later: Hc (bf16) then y2
  float* kfull = ws + 14848000;    // [.., +14745600) later: y1
  float* part  = ws + 29593600;    // [.., +2160000)  later: wb (bf16)
  float* att   = ws + 31753600;    // [.., +240000)
  float* wtr   = ws + 31993600;    // [.., +114688)   wbt bf16 (114688 shorts)
  ushort* Hc  = (ushort*)qfull;
  ushort* wb  = (ushort*)part;
  ushort* wbt = (ushort*)wtr;
  float* y1 = kfull;
  float* y2 = qfull;
  float* outp = (float*)d_out;

  k_qk<<<3625, 256, 0, stream>>>(x, w_k, b_k, w_q, b_q, kfull, qfull);
  k_scores<<<dim3(9, 8, 16), 128, 0, stream>>>(kfull, qfull, part);
  k_softmax<<<128, 128, 0, stream>>>(part, alphas, att0, att);
  k_wcvt<<<512, 256, 0, stream>>>(w_out, wb);
  for (int n0 = 0; n0 < 16; n0 += 4) {
    k_hgemm<<<1800, 256, 0, stream>>>(x, wb, Hc, n0);
    k_attn2<<<dim3(72, 4), 256, 0, stream>>>(Hc, att, x, b_out, g_out, be_out,
                                             m_out, v_out, y1, n0);
  }
  k_ff<<<3600, 256, 0, stream>>>(y1, x, w_ff, b_ff, g_ff, be_ff, m_ff, v_ff, y2);
  k_wtb<<<448, 256, 0, stream>>>(w_t, wbt);
  k_tconv<<<dim3(57, 16), 256, 0, stream>>>(y2, x, wbt, b_t, g_t, be_t, m_t,
                                            v_t, outp);
}

// Round 6
// 1751.878 us; speedup vs baseline: 2.9365x; 1.2002x over previous
//
#include <hip/hip_runtime.h>

// SSHA block. Round 6: k_scores rewritten as per-(n,s) bf16 MFMA kernel with
// fused softmax (kills k_softmax + partial buffer); k_qk now emits bf16 qb/kb.
//   scores[u,v] = sum_{t,ic} q[ic,t,u]*k[ic,t,v]  -> 5x2 16x16 tiles, K=4608
//   att = softmax_u(scores/4608)*alpha + att0, computed in-block.
// Attn stage (H-reassociation) and MFMA tconv unchanged from round 5.
// Shapes: N=16, T=288, V=25, C=128, S=8, IC=16, W=3, U=75, TP=290.

#define NN 16
#define TT 288
#define VV 25
#define CC 128
#define SS 8
#define UU 75
#define TP 290
#define EPSF 1e-5f

typedef __attribute__((ext_vector_type(8))) short bf16x8;
typedef __attribute__((ext_vector_type(4))) float f32x4;

static __device__ __forceinline__ void fma4(float4& a, float s, const float4 b) {
  a.x += s * b.x; a.y += s * b.y; a.z += s * b.z; a.w += s * b.w;
}
static __device__ __forceinline__ ushort f2bf(float f) {
  uint u = __float_as_uint(f);
  u = (u + 0x7FFFu + ((u >> 16) & 1u)) >> 16;
  return (ushort)u;
}

// ---------------- K1: k/q 1x1 convs -> bf16 kb/qb ----------------
__global__ __launch_bounds__(256) void k_qk(
    const float* __restrict__ x,
    const float* __restrict__ w_k, const float* __restrict__ b_k,
    const float* __restrict__ w_q, const float* __restrict__ b_q,
    ushort* __restrict__ kb, ushort* __restrict__ qb) {
  __shared__ float wk[128 * 129];
  __shared__ float wq[128 * 129];
  __shared__ float xt[128 * 36];
  const int tid = threadIdx.x;
  for (int i = tid; i < 128 * 128; i += 256) {
    int o = i >> 7, c = i & 127;
    wk[o * 129 + c] = w_k[i];
    wq[o * 129 + c] = w_q[i];
  }
  const int base = blockIdx.x * 32;
  for (int i = tid; i < 32 * 128; i += 256) {
    int r = i >> 7, c = i & 127;
    int row = base + r;
    int n = row / (TP * VV);
    int rem = row - n * (TP * VV);
    int tp = rem / VV, v = rem - tp * VV;
    float val = 0.f;
    if (tp >= 1 && tp <= TT) val = x[(((n * TT + (tp - 1)) * VV + v) << 7) + c];
    xt[c * 36 + r] = val;
  }
  __syncthreads();
  const int o = tid & 127;
  const int rh = tid >> 7;
  float acck[16], accq[16];
#pragma unroll
  for (int r = 0; r < 16; ++r) { acck[r] = 0.f; accq[r] = 0.f; }
  const float* wkp = wk + o * 129;
  const float* wqp = wq + o * 129;
  for (int c = 0; c < 128; ++c) {
    float wv0 = wkp[c];
    float wv1 = wqp[c];
    const float4* xp = (const float4*)(xt + c * 36 + rh * 16);
#pragma unroll
    for (int r4 = 0; r4 < 4; ++r4) {
      float4 xv = xp[r4];
      acck[r4 * 4 + 0] += wv0 * xv.x; acck[r4 * 4 + 1] += wv0 * xv.y;
      acck[r4 * 4 + 2] += wv0 * xv.z; acck[r4 * 4 + 3] += wv0 * xv.w;
      accq[r4 * 4 + 0] += wv1 * xv.x; accq[r4 * 4 + 1] += wv1 * xv.y;
      accq[r4 * 4 + 2] += wv1 * xv.z; accq[r4 * 4 + 3] += wv1 * xv.w;
    }
  }
  const float bk = b_k[o], bq = b_q[o];
  for (int r = 0; r < 16; ++r) {
    int row = base + rh * 16 + r;
    int n = row / (TP * VV);
    int rem = row - n * (TP * VV);
    int tp = rem / VV, v = rem - tp * VV;
    qb[((size_t)(n * TP + tp) * VV + v) * 128 + o] = f2bf(accq[r] + bq);
    if (tp >= 1 && tp <= TT)
      kb[((size_t)(n * TT + (tp - 1)) * VV + v) * 128 + o] = f2bf(acck[r] + bk);
  }
}

// ---------------- K2: scores (bf16 MFMA) + fused softmax -> att ----------------
// Grid 128 = (n,s). 512 thr = 8 waves; wave w handles k-steps kk = w, w+8, ... (<144).
// Per k-step (t0=2*kk): 10 MFMAs (5 u-tiles x 2 v-tiles), K=32 = 2t x 16ic.
__global__ __launch_bounds__(512) void k_scores(
    const ushort* __restrict__ kb, const ushort* __restrict__ qb,
    const float* __restrict__ alphas, const float* __restrict__ att0,
    float* __restrict__ att) {
  __shared__ float red[8][2640];  // [wave][u(80) * 33 + v(32)]
  __shared__ float scl[1875];
  __shared__ float mx[25];
  __shared__ float den[25];
  const int bx = blockIdx.x;
  const int n = bx >> 3, s = bx & 7;
  const int tid = threadIdx.x;
  const int lane = tid & 63, wid = tid >> 6;
  const int l15 = lane & 15, l4 = lane >> 4;
  const int dt = l4 >> 1;
  const int sic = s * 16 + (l4 & 1) * 8;
  // per-lane constant offsets (elements)
  int qoff[5];
#pragma unroll
  for (int tu = 0; tu < 5; ++tu) {
    int u = tu * 16 + l15;
    int w = u / 25, vp = u - w * 25;  // garbage ok for u>=75 (zeroed below)
    qoff[tu] = (w * 25 + vp) * 128 + sic;
  }
  const bool qv4 = (64 + l15) < 75;
  const bool kv1 = (16 + l15) < 25;
  int koff0 = l15 * 128 + sic;
  int koff1 = (16 + l15) * 128 + sic;
  const ushort* qbase = qb + (size_t)n * 928000 + (size_t)dt * 3200;
  const ushort* kbase = kb + (size_t)n * 921600 + (size_t)dt * 3200;
  f32x4 acc[5][2] = {};
  const bf16x8 zf = {};
  for (int kk = wid; kk < 144; kk += 8) {
    const ushort* qp = qbase + kk * 6400;
    const ushort* kp = kbase + kk * 6400;
    bf16x8 a[5], b[2];
#pragma unroll
    for (int tu = 0; tu < 4; ++tu) a[tu] = *(const bf16x8*)(qp + qoff[tu]);
    a[4] = qv4 ? *(const bf16x8*)(qp + qoff[4]) : zf;
    b[0] = *(const bf16x8*)(kp + koff0);
    b[1] = kv1 ? *(const bf16x8*)(kp + koff1) : zf;
#pragma unroll
    for (int tu = 0; tu < 5; ++tu)
#pragma unroll
      for (int tv = 0; tv < 2; ++tv)
        acc[tu][tv] = __builtin_amdgcn_mfma_f32_16x16x32_bf16(
            a[tu], b[tv], acc[tu][tv], 0, 0, 0);
  }
  // dump per-wave tiles to LDS: C/D layout col=lane&15, row=l4*4+reg
#pragma unroll
  for (int tu = 0; tu < 5; ++tu)
#pragma unroll
    for (int tv = 0; tv < 2; ++tv) {
#pragma unroll
      for (int reg = 0; reg < 4; ++reg)
        red[wid][(tu * 16 + l4 * 4 + reg) * 33 + tv * 16 + l15] =
            acc[tu][tv][reg];
    }
  __syncthreads();
  const float inv = 1.0f / 4608.0f;
  for (int i = tid; i < 1875; i += 512) {
    int u = i / 25, v = i - u * 25;
    float a = 0.f;
#pragma unroll
    for (int w = 0; w < 8; ++w) a += red[w][u * 33 + v];
    scl[i] = a * inv;
  }
  __syncthreads();
  if (tid < 25) {
    float m = -1e30f;
    for (int u = 0; u < 75; ++u) m = fmaxf(m, scl[u * 25 + tid]);
    float d = 0.f;
    for (int u = 0; u < 75; ++u) d += expf(scl[u * 25 + tid] - m);
    mx[tid] = m;
    den[tid] = d;
  }
  __syncthreads();
  const float alpha = alphas[s];
  for (int i = tid; i < 1875; i += 512) {
    int v = i % 25;
    att[(size_t)bx * 1875 + i] =
        expf(scl[i] - mx[v]) / den[v] * alpha + att0[s * 1875 + i];
  }
}

// Wb[j=(s*128+o)][c] = bf16(w_out[o*1024 + s*128 + c])
__global__ __launch_bounds__(256) void k_wcvt(const float* __restrict__ w_out,
                                              ushort* __restrict__ wb) {
  int i = blockIdx.x * 256 + threadIdx.x;  // 131072
  int j = i >> 7, c = i & 127;
  int s = j >> 7, o = j & 127;
  wb[i] = f2bf(w_out[(o << 10) + (s << 7) + c]);
}

// ---------------- K3a: H-GEMM chunk (bf16 MFMA) ----------------
__global__ __launch_bounds__(256) void k_hgemm(const float* __restrict__ x,
                                               const ushort* __restrict__ wb,
                                               ushort* __restrict__ Hc, int n0) {
  __shared__ ushort As[8][128][8];
  __shared__ ushort Bs[8][128][8];
  const int bx = blockIdx.x;
  const int bm = bx >> 3, bn = bx & 7;
  const int gm0 = bm << 7, gn0 = bn << 7;
  const int tid = threadIdx.x;
  const int lane = tid & 63, wid = tid >> 6;
  const int wm = wid >> 1, wn = wid & 1;
  const int srow = tid & 127;
  const int skg0 = tid >> 7;
  const size_t xbase = ((size_t)n0 * 7200 + gm0) << 7;
  f32x4 acc[4][4] = {};
  for (int kh = 0; kh < 2; ++kh) {
    __syncthreads();
#pragma unroll
    for (int j = 0; j < 4; ++j) {
      int kg = skg0 + 2 * j;
      const float* xp = x + xbase + ((size_t)srow << 7) + kh * 64 + kg * 8;
      float4 a0 = *(const float4*)xp;
      float4 a1 = *(const float4*)(xp + 4);
      uint4 pk;
      pk.x = (uint)f2bf(a0.x) | ((uint)f2bf(a0.y) << 16);
      pk.y = (uint)f2bf(a0.z) | ((uint)f2bf(a0.w) << 16);
      pk.z = (uint)f2bf(a1.x) | ((uint)f2bf(a1.y) << 16);
      pk.w = (uint)f2bf(a1.z) | ((uint)f2bf(a1.w) << 16);
      *(uint4*)&As[kg][srow][0] = pk;
      *(uint4*)&Bs[kg][srow][0] =
          *(const uint4*)&wb[((size_t)(gn0 + srow) << 7) + kh * 64 + kg * 8];
    }
    __syncthreads();
#pragma unroll
    for (int ks = 0; ks < 2; ++ks) {
      int g = ks * 4 + (lane >> 4);
      bf16x8 af[4], bfr[4];
#pragma unroll
      for (int mi = 0; mi < 4; ++mi)
        af[mi] = *(const bf16x8*)&As[g][wm * 64 + mi * 16 + (lane & 15)][0];
#pragma unroll
      for (int ni = 0; ni < 4; ++ni)
        bfr[ni] = *(const bf16x8*)&Bs[g][wn * 64 + ni * 16 + (lane & 15)][0];
#pragma unroll
      for (int mi = 0; mi < 4; ++mi)
#pragma unroll
        for (int ni = 0; ni < 4; ++ni)
          acc[mi][ni] = __builtin_amdgcn_mfma_f32_16x16x32_bf16(
              af[mi], bfr[ni], acc[mi][ni], 0, 0, 0);
    }
  }
  const int r0 = gm0 + wm * 64;
  const int c0 = gn0 + wn * 64;
#pragma unroll
  for (int mi = 0; mi < 4; ++mi)
#pragma unroll
    for (int ni = 0; ni < 4; ++ni) {
      int col = c0 + ni * 16 + (lane & 15);
#pragma unroll
      for (int reg = 0; reg < 4; ++reg) {
        int row = r0 + mi * 16 + ((lane >> 4) << 2) + reg;
        Hc[((size_t)row << 10) + col] = f2bf(acc[mi][ni][reg]);
      }
    }
}

// ---------------- K3b: O = A.Hc + b_out + BN + leaky residual ----------------
__global__ __launch_bounds__(256) void k_attn2(
    const ushort* __restrict__ Hc, const float* __restrict__ att,
    const float* __restrict__ x, const float* __restrict__ b_out,
    const float* __restrict__ g_out, const float* __restrict__ beta_out,
    const float* __restrict__ m_out, const float* __restrict__ v_out,
    float* __restrict__ y1, int n0) {
  __shared__ float Al[3][200][32];
  const int nl = blockIdx.y;
  const int n = n0 + nl;
  const int t0 = blockIdx.x * 4;
  const int tid = threadIdx.x;
  for (int i = tid; i < 19200; i += 256) {
    int w = i / 6400;
    int rem = i - w * 6400;
    int k = rem >> 5, v = rem & 31;
    int vp = k >> 3, s = k & 7;
    float val = 0.f;
    if (v < 25) val = att[((size_t)(n * 8 + s) * 75 + (w * 25 + vp)) * 25 + v];
    Al[w][k][v] = val;
  }
  __syncthreads();
  const int og = tid & 15;
  const int vg = tid >> 4;
  float sc[8], sh[8], bb[8];
#pragma unroll
  for (int j = 0; j < 8; ++j) {
    int o = og * 8 + j;
    float s1 = g_out[o] * rsqrtf(v_out[o] + EPSF);
    sc[j] = s1;
    sh[j] = beta_out[o] - m_out[o] * s1;
    bb[j] = b_out[o];
  }
  const float* Af = &Al[0][0][0];
  for (int tt = 0; tt < 4; ++tt) {
    int t = t0 + tt;
    float acc0[8], acc1[8];
#pragma unroll
    for (int j = 0; j < 8; ++j) { acc0[j] = 0.f; acc1[j] = 0.f; }
    for (int w = 0; w < 3; ++w) {
      int tp = t + w - 1;
      if (tp < 0 || tp >= TT) continue;
      const ushort* hp = Hc + (size_t)(nl * TT + tp) * 25600 + og * 8;
      const float* ap = Af + w * 6400;
      for (int k = 0; k < 200; ++k) {
        uint4 h4 = *(const uint4*)(hp + (k << 7));
        float a0 = ap[(k << 5) + vg];
        float a1 = ap[(k << 5) + vg + 16];
        float f0 = __uint_as_float(h4.x << 16);
        float f1 = __uint_as_float(h4.x & 0xffff0000u);
        float f2 = __uint_as_float(h4.y << 16);
        float f3 = __uint_as_float(h4.y & 0xffff0000u);
        float f4 = __uint_as_float(h4.z << 16);
        float f5 = __uint_as_float(h4.z & 0xffff0000u);
        float f6 = __uint_as_float(h4.w << 16);
        float f7 = __uint_as_float(h4.w & 0xffff0000u);
        acc0[0] += a0 * f0; acc0[1] += a0 * f1; acc0[2] += a0 * f2; acc0[3] += a0 * f3;
        acc0[4] += a0 * f4; acc0[5] += a0 * f5; acc0[6] += a0 * f6; acc0[7] += a0 * f7;
        acc1[0] += a1 * f0; acc1[1] += a1 * f1; acc1[2] += a1 * f2; acc1[3] += a1 * f3;
        acc1[4] += a1 * f4; acc1[5] += a1 * f5; acc1[6] += a1 * f6; acc1[7] += a1 * f7;
      }
    }
    {
      size_t idx = ((size_t)((n * TT + t) * VV + vg) << 7) + og * 8;
      const float* xr = x + idx;
      float* yr = y1 + idx;
#pragma unroll
      for (int j = 0; j < 8; ++j) {
        float a = (acc0[j] + bb[j]) * sc[j] + sh[j];
        float r = xr[j] + a;
        yr[j] = r > 0.f ? r : 0.1f * r;
      }
    }
    if (vg < 9) {
      size_t idx = ((size_t)((n * TT + t) * VV + vg + 16) << 7) + og * 8;
      const float* xr = x + idx;
      float* yr = y1 + idx;
#pragma unroll
      for (int j = 0; j < 8; ++j) {
        float a = (acc1[j] + bb[j]) * sc[j] + sh[j];
        float r = xr[j] + a;
        yr[j] = r > 0.f ? r : 0.1f * r;
      }
    }
  }
}

// ---------------- K4: ff conv + BN + leaky residual ----------------
__global__ __launch_bounds__(256) void k_ff(
    const float* __restrict__ y1, const float* __restrict__ x,
    const float* __restrict__ w_ff, const float* __restrict__ b_ff,
    const float* __restrict__ g_ff, const float* __restrict__ beta_ff,
    const float* __restrict__ m_ff, const float* __restrict__ v_ff,
    float* __restrict__ y2) {
  __shared__ float wl[128 * 129];
  __shared__ float yt[128 * 36];
  const int tid = threadIdx.x;
  for (int i = tid; i < 128 * 128; i += 256)
    wl[(i >> 7) * 129 + (i & 127)] = w_ff[i];
  const int base = blockIdx.x * 32;
  for (int i = tid; i < 32 * 128; i += 256) {
    int r = i >> 7, c = i & 127;
    yt[c * 36 + r] = y1[((base + r) << 7) + c];
  }
  __syncthreads();
  const int o2 = tid & 63;
  const int rq = tid >> 6;
  float acc[2][8];
#pragma unroll
  for (int i = 0; i < 8; ++i) { acc[0][i] = 0.f; acc[1][i] = 0.f; }
  const float* w0 = wl + o2 * 129;
  const float* w1 = wl + (o2 + 64) * 129;
  for (int c = 0; c < 128; ++c) {
    float wv0 = w0[c], wv1 = w1[c];
    const float4* yp = (const float4*)(yt + c * 36 + rq * 8);
    float4 a = yp[0], b = yp[1];
    acc[0][0] += wv0 * a.x; acc[0][1] += wv0 * a.y; acc[0][2] += wv0 * a.z; acc[0][3] += wv0 * a.w;
    acc[0][4] += wv0 * b.x; acc[0][5] += wv0 * b.y; acc[0][6] += wv0 * b.z; acc[0][7] += wv0 * b.w;
    acc[1][0] += wv1 * a.x; acc[1][1] += wv1 * a.y; acc[1][2] += wv1 * a.z; acc[1][3] += wv1 * a.w;
    acc[1][4] += wv1 * b.x; acc[1][5] += wv1 * b.y; acc[1][6] += wv1 * b.z; acc[1][7] += wv1 * b.w;
  }
#pragma unroll
  for (int oi = 0; oi < 2; ++oi) {
    int o = o2 + 64 * oi;
    float scale = g_ff[o] * rsqrtf(v_ff[o] + EPSF);
    float sh = beta_ff[o] - m_ff[o] * scale;
    float bb = b_ff[o];
#pragma unroll
    for (int r = 0; r < 8; ++r) {
      int row = base + rq * 8 + r;
      float a = (acc[oi][r] + bb) * scale + sh;
      float rr = x[(row << 7) + o] + a;
      y2[(row << 7) + o] = rr > 0.f ? rr : 0.1f * rr;
    }
  }
}

// ---------------- K5a: w_t (o,c,kt) -> bf16 wbt[o][kt*128+c] ----------------
__global__ __launch_bounds__(256) void k_wtb(const float* __restrict__ w_t,
                                             ushort* __restrict__ wbt) {
  int i = blockIdx.x * 256 + threadIdx.x;
  if (i < 128 * 128 * 7) {
    int o = i / 896;
    int rem = i - o * 896;
    int c = rem / 7, kt = rem - c * 7;
    wbt[o * 896 + kt * 128 + c] = f2bf(w_t[i]);
  }
}

// ---------------- K5: temporal conv as bf16 MFMA GEMM ----------------
__global__ __launch_bounds__(256, 2) void k_tconv(
    const float* __restrict__ y2, const float* __restrict__ x,
    const ushort* __restrict__ wbt, const float* __restrict__ b_t,
    const float* __restrict__ g_t, const float* __restrict__ beta_t,
    const float* __restrict__ m_t, const float* __restrict__ v_t,
    float* __restrict__ out) {
  __shared__ uint4 As[280 * 16];  // [row][16B-chunk], chunk idx ^= (row&7)
  const int n = blockIdx.y;
  const int r0 = blockIdx.x << 7;
  const int tid = threadIdx.x;
  const float* y2n = y2 + ((size_t)n * 7200 << 7);
  for (int i = tid; i < 278 * 16; i += 256) {
    int rl = i >> 4, cc = i & 15;
    int g = r0 - 75 + rl;
    uint4 pk = make_uint4(0u, 0u, 0u, 0u);
    if (g >= 0 && g < 7200) {
      const float* xp = y2n + ((size_t)g << 7) + (cc << 3);
      float4 a0 = *(const float4*)xp;
      float4 a1 = *(const float4*)(xp + 4);
      pk.x = (uint)f2bf(a0.x) | ((uint)f2bf(a0.y) << 16);
      pk.y = (uint)f2bf(a0.z) | ((uint)f2bf(a0.w) << 16);
      pk.z = (uint)f2bf(a1.x) | ((uint)f2bf(a1.y) << 16);
      pk.w = (uint)f2bf(a1.z) | ((uint)f2bf(a1.w) << 16);
    }
    As[(rl << 4) + (cc ^ (rl & 7))] = pk;
  }
  __syncthreads();
  const int lane = tid & 63, wid = tid >> 6;
  const int wm = wid >> 1, wn = wid & 1;
  const int l15 = lane & 15, l4 = lane >> 4;
  f32x4 acc[4][4] = {};
  for (int kt = 0; kt < 7; ++kt) {
    bf16x8 bfr[4][4];
#pragma unroll
    for (int ni = 0; ni < 4; ++ni) {
      const ushort* bp =
          wbt + (size_t)(wn * 64 + ni * 16 + l15) * 896 + kt * 128 + l4 * 8;
#pragma unroll
      for (int cc0 = 0; cc0 < 4; ++cc0)
        bfr[ni][cc0] = *(const bf16x8*)(bp + cc0 * 32);
    }
#pragma unroll
    for (int cc0 = 0; cc0 < 4; ++cc0) {
      bf16x8 af[4];
#pragma unroll
      for (int mi = 0; mi < 4; ++mi) {
        int rl = wm * 64 + mi * 16 + l15 + 25 * kt;
        af[mi] = *(const bf16x8*)&As[(rl << 4) + ((cc0 * 4 + l4) ^ (rl & 7))];
      }
#pragma unroll
      for (int mi = 0; mi < 4; ++mi)
#pragma unroll
        for (int ni = 0; ni < 4; ++ni)
          acc[mi][ni] = __builtin_amdgcn_mfma_f32_16x16x32_bf16(
              af[mi], bfr[ni][cc0], acc[mi][ni], 0, 0, 0);
    }
  }
#pragma unroll
  for (int ni = 0; ni < 4; ++ni) {
    int o = wn * 64 + ni * 16 + l15;
    float s1 = g_t[o] * rsqrtf(v_t[o] + EPSF);
    float sh = beta_t[o] - m_t[o] * s1;
    float bb = b_t[o];
#pragma unroll
    for (int mi = 0; mi < 4; ++mi) {
#pragma unroll
      for (int reg = 0; reg < 4; ++reg) {
        int grow = r0 + wm * 64 + mi * 16 + (l4 << 2) + reg;
        if (grow < 7200) {
          size_t idx = (((size_t)n * 7200 + grow) << 7) + o;
          float z = (acc[mi][ni][reg] + bb) * s1 + sh;
          z += y2[idx];
          z = z > 0.f ? z : 0.1f * z;
          z += x[idx];
          out[idx] = z > 0.f ? z : 0.f;
        }
      }
    }
  }
}

extern "C" void kernel_launch(void* const* d_in, const int* in_sizes, int n_in,
                              void* d_out, int out_size, void* d_ws, size_t ws_size,
                              hipStream_t stream) {
  const float* x      = (const float*)d_in[0];
  const float* w_k    = (const float*)d_in[1];
  const float* b_k    = (const float*)d_in[2];
  const float* w_q    = (const float*)d_in[3];
  const float* b_q    = (const float*)d_in[4];
  const float* alphas = (const float*)d_in[5];
  const float* att0   = (const float*)d_in[6];
  const float* w_out  = (const float*)d_in[7];
  const float* b_out  = (const float*)d_in[8];
  const float* g_out  = (const float*)d_in[9];
  const float* be_out = (const float*)d_in[10];
  const float* m_out  = (const float*)d_in[11];
  const float* v_out  = (const float*)d_in[12];
  const float* w_ff   = (const float*)d_in[13];
  const float* b_ff   = (const float*)d_in[14];
  const float* g_ff   = (const float*)d_in[15];
  const float* be_ff  = (const float*)d_in[16];
  const float* m_ff   = (const float*)d_in[17];
  const float* v_ff   = (const float*)d_in[18];
  const float* w_t    = (const float*)d_in[19];
  const float* b_t    = (const float*)d_in[20];
  const float* g_t    = (const float*)d_in[21];
  const float* be_t   = (const float*)d_in[22];
  const float* m_t    = (const float*)d_in[23];
  const float* v_t    = (const float*)d_in[24];

  float* ws = (float*)d_ws;
  // Region plan (floats), total 32,108,288 = round-1 proven footprint:
  float* qfull = ws;               // [0, 14848000)   qb bf16 -> Hc bf16 -> y2
  float* kfull = ws + 14848000;    // [.., +14745600) kb bf16 -> y1
  float* part  = ws + 29593600;    // [.., +2160000)  wb bf16
  float* att   = ws + 31753600;    // [.., +240000)
  float* wtr   = ws + 31993600;    // [.., +114688)   wbt bf16
  ushort* qbb = (ushort*)qfull;    // 16*290*25*128 = 14,848,000 shorts
  ushort* kbb = (ushort*)kfull;    // 16*288*25*128 = 14,745,600 shorts
  ushort* Hc  = (ushort*)qfull;    // after k_scores consumes qb
  ushort* wb  = (ushort*)part;
  ushort* wbt = (ushort*)wtr;
  float* y1 = kfull;
  float* y2 = qfull;
  float* outp = (float*)d_out;

  k_qk<<<3625, 256, 0, stream>>>(x, w_k, b_k, w_q, b_q, kbb, qbb);
  k_scores<<<128, 512, 0, stream>>>(kbb, qbb, alphas, att0, att);
  k_wcvt<<<512, 256, 0, stream>>>(w_out, wb);
  for (int n0 = 0; n0 < 16; n0 += 4) {
    k_hgemm<<<1800, 256, 0, stream>>>(x, wb, Hc, n0);
    k_attn2<<<dim3(72, 4), 256, 0, stream>>>(Hc, att, x, b_out, g_out, be_out,
                                             m_out, v_out, y1, n0);
  }
  k_ff<<<3600, 256, 0, stream>>>(y1, x, w_ff, b_ff, g_ff, be_ff, m_ff, v_ff, y2);
  k_wtb<<<448, 256, 0, stream>>>(w_t, wbt);
  k_tconv<<<dim3(57, 16), 256, 0, stream>>>(y2, x, wbt, b_t, g_t, be_t, m_t,
                                            v_t, outp);
}

// Round 7
// 1422.607 us; speedup vs baseline: 3.6162x; 1.2315x over previous
//
#include <hip/hip_runtime.h>

// SSHA block. Round 7: k_qk and k_ff rewritten as bf16 MFMA GEMMs
// (k_hgemm 128x128-tile structure). k_qkpad fills qb bias-only pad rows.
// Everything else unchanged from round 6.
// Shapes: N=16, T=288, V=25, C=128, S=8, IC=16, W=3, U=75, TP=290.

#define NN 16
#define TT 288
#define VV 25
#define CC 128
#define SS 8
#define UU 75
#define TP 290
#define EPSF 1e-5f

typedef __attribute__((ext_vector_type(8))) short bf16x8;
typedef __attribute__((ext_vector_type(4))) float f32x4;

static __device__ __forceinline__ ushort f2bf(float f) {
  uint u = __float_as_uint(f);
  u = (u + 0x7FFFu + ((u >> 16) & 1u)) >> 16;
  return (ushort)u;
}

// ---------------- K0: weight converts ----------------
// wb[j=(s*128+o)][c] = bf16(w_out); wkqb[0:16384]=w_k, [16384:32768]=w_q; wffb=w_ff.
__global__ __launch_bounds__(256) void k_wcvt(
    const float* __restrict__ w_out, const float* __restrict__ w_k,
    const float* __restrict__ w_q, const float* __restrict__ w_ff,
    ushort* __restrict__ wb, ushort* __restrict__ wkqb,
    ushort* __restrict__ wffb) {
  int i = blockIdx.x * 256 + threadIdx.x;  // 180224 total
  if (i < 131072) {
    int j = i >> 7, c = i & 127;
    int s = j >> 7, o = j & 127;
    wb[i] = f2bf(w_out[(o << 10) + (s << 7) + c]);
  } else {
    int j = i - 131072;
    if (j < 16384) wkqb[j] = f2bf(w_k[j]);
    else if (j < 32768) wkqb[j] = f2bf(w_q[j - 16384]);
    else wffb[j - 32768] = f2bf(w_ff[j - 32768]);
  }
}

// ---------------- K1: k/q 1x1 convs as bf16 MFMA GEMM ----------------
// Grid (900, 2): 128-row M-tile; by=0 -> kb (w_k), by=1 -> qb (w_q, row-shifted).
__global__ __launch_bounds__(256) void k_qkg(
    const float* __restrict__ x, const ushort* __restrict__ wkqb,
    const float* __restrict__ b_k, const float* __restrict__ b_q,
    ushort* __restrict__ kb, ushort* __restrict__ qb) {
  __shared__ ushort As[8][128][8];
  __shared__ ushort Bs[8][128][8];
  const int bm = blockIdx.x, by = blockIdx.y;
  const int gm0 = bm << 7;
  const int tid = threadIdx.x;
  const int lane = tid & 63, wid = tid >> 6;
  const int wm = wid >> 1, wn = wid & 1;
  const int srow = tid & 127;
  const int skg0 = tid >> 7;
  const ushort* wsrc = wkqb + by * 16384;
  f32x4 acc[4][4] = {};
  for (int kh = 0; kh < 2; ++kh) {
    __syncthreads();
#pragma unroll
    for (int j = 0; j < 4; ++j) {
      int kg = skg0 + 2 * j;
      const float* xp = x + (((size_t)(gm0 + srow)) << 7) + kh * 64 + kg * 8;
      float4 a0 = *(const float4*)xp;
      float4 a1 = *(const float4*)(xp + 4);
      uint4 pk;
      pk.x = (uint)f2bf(a0.x) | ((uint)f2bf(a0.y) << 16);
      pk.y = (uint)f2bf(a0.z) | ((uint)f2bf(a0.w) << 16);
      pk.z = (uint)f2bf(a1.x) | ((uint)f2bf(a1.y) << 16);
      pk.w = (uint)f2bf(a1.z) | ((uint)f2bf(a1.w) << 16);
      *(uint4*)&As[kg][srow][0] = pk;
      *(uint4*)&Bs[kg][srow][0] =
          *(const uint4*)&wsrc[(srow << 7) + kh * 64 + kg * 8];
    }
    __syncthreads();
#pragma unroll
    for (int ks = 0; ks < 2; ++ks) {
      int g = ks * 4 + (lane >> 4);
      bf16x8 af[4], bfr[4];
#pragma unroll
      for (int mi = 0; mi < 4; ++mi)
        af[mi] = *(const bf16x8*)&As[g][wm * 64 + mi * 16 + (lane & 15)][0];
#pragma unroll
      for (int ni = 0; ni < 4; ++ni)
        bfr[ni] = *(const bf16x8*)&Bs[g][wn * 64 + ni * 16 + (lane & 15)][0];
#pragma unroll
      for (int mi = 0; mi < 4; ++mi)
#pragma unroll
        for (int ni = 0; ni < 4; ++ni)
          acc[mi][ni] = __builtin_amdgcn_mfma_f32_16x16x32_bf16(
              af[mi], bfr[ni], acc[mi][ni], 0, 0, 0);
    }
  }
  const int l15 = lane & 15, l4 = lane >> 4;
  const float* bias = by ? b_q : b_k;
#pragma unroll
  for (int ni = 0; ni < 4; ++ni) {
    int col = wn * 64 + ni * 16 + l15;
    float bb = bias[col];
#pragma unroll
    for (int mi = 0; mi < 4; ++mi) {
#pragma unroll
      for (int reg = 0; reg < 4; ++reg) {
        int row = gm0 + wm * 64 + mi * 16 + (l4 << 2) + reg;
        ushort val = f2bf(acc[mi][ni][reg] + bb);
        if (by == 0) {
          kb[((size_t)row << 7) + col] = val;
        } else {
          int n = row / 7200;
          qb[((size_t)(row + n * 50 + 25) << 7) + col] = val;
        }
      }
    }
  }
}

// qb pad rows (tp=0, tp=289): bias-only. 102400 elems.
__global__ __launch_bounds__(256) void k_qkpad(const float* __restrict__ b_q,
                                               ushort* __restrict__ qb) {
  int i = blockIdx.x * 256 + threadIdx.x;  // 16*2*25*128
  int o = i & 127;
  int r = i >> 7;  // (n, e, v)
  int v = r % 25;
  int e = (r / 25) & 1;
  int n = r / 50;
  int tp = e ? 289 : 0;
  qb[((size_t)((n * TP + tp) * VV + v) << 7) + o] = f2bf(b_q[o]);
}

// ---------------- K2: scores (bf16 MFMA) + fused softmax -> att ----------------
__global__ __launch_bounds__(512) void k_scores(
    const ushort* __restrict__ kb, const ushort* __restrict__ qb,
    const float* __restrict__ alphas, const float* __restrict__ att0,
    float* __restrict__ att) {
  __shared__ float red[8][2640];  // [wave][u(80) * 33 + v(32)]
  __shared__ float scl[1875];
  __shared__ float mx[25];
  __shared__ float den[25];
  const int bx = blockIdx.x;
  const int n = bx >> 3, s = bx & 7;
  const int tid = threadIdx.x;
  const int lane = tid & 63, wid = tid >> 6;
  const int l15 = lane & 15, l4 = lane >> 4;
  const int dt = l4 >> 1;
  const int sic = s * 16 + (l4 & 1) * 8;
  int qoff[5];
#pragma unroll
  for (int tu = 0; tu < 5; ++tu) {
    int u = tu * 16 + l15;
    int w = u / 25, vp = u - w * 25;
    qoff[tu] = (w * 25 + vp) * 128 + sic;
  }
  const bool qv4 = (64 + l15) < 75;
  const bool kv1 = (16 + l15) < 25;
  int koff0 = l15 * 128 + sic;
  int koff1 = (16 + l15) * 128 + sic;
  const ushort* qbase = qb + (size_t)n * 928000 + (size_t)dt * 3200;
  const ushort* kbase = kb + (size_t)n * 921600 + (size_t)dt * 3200;
  f32x4 acc[5][2] = {};
  const bf16x8 zf = {};
  for (int kk = wid; kk < 144; kk += 8) {
    const ushort* qp = qbase + kk * 6400;
    const ushort* kp = kbase + kk * 6400;
    bf16x8 a[5], b[2];
#pragma unroll
    for (int tu = 0; tu < 4; ++tu) a[tu] = *(const bf16x8*)(qp + qoff[tu]);
    a[4] = qv4 ? *(const bf16x8*)(qp + qoff[4]) : zf;
    b[0] = *(const bf16x8*)(kp + koff0);
    b[1] = kv1 ? *(const bf16x8*)(kp + koff1) : zf;
#pragma unroll
    for (int tu = 0; tu < 5; ++tu)
#pragma unroll
      for (int tv = 0; tv < 2; ++tv)
        acc[tu][tv] = __builtin_amdgcn_mfma_f32_16x16x32_bf16(
            a[tu], b[tv], acc[tu][tv], 0, 0, 0);
  }
#pragma unroll
  for (int tu = 0; tu < 5; ++tu)
#pragma unroll
    for (int tv = 0; tv < 2; ++tv) {
#pragma unroll
      for (int reg = 0; reg < 4; ++reg)
        red[wid][(tu * 16 + l4 * 4 + reg) * 33 + tv * 16 + l15] =
            acc[tu][tv][reg];
    }
  __syncthreads();
  const float inv = 1.0f / 4608.0f;
  for (int i = tid; i < 1875; i += 512) {
    int u = i / 25, v = i - u * 25;
    float a = 0.f;
#pragma unroll
    for (int w = 0; w < 8; ++w) a += red[w][u * 33 + v];
    scl[i] = a * inv;
  }
  __syncthreads();
  if (tid < 25) {
    float m = -1e30f;
    for (int u = 0; u < 75; ++u) m = fmaxf(m, scl[u * 25 + tid]);
    float d = 0.f;
    for (int u = 0; u < 75; ++u) d += expf(scl[u * 25 + tid] - m);
    mx[tid] = m;
    den[tid] = d;
  }
  __syncthreads();
  const float alpha = alphas[s];
  for (int i = tid; i < 1875; i += 512) {
    int v = i % 25;
    att[(size_t)bx * 1875 + i] =
        expf(scl[i] - mx[v]) / den[v] * alpha + att0[s * 1875 + i];
  }
}

// ---------------- K3a: H-GEMM chunk (bf16 MFMA) ----------------
__global__ __launch_bounds__(256) void k_hgemm(const float* __restrict__ x,
                                               const ushort* __restrict__ wb,
                                               ushort* __restrict__ Hc, int n0) {
  __shared__ ushort As[8][128][8];
  __shared__ ushort Bs[8][128][8];
  const int bx = blockIdx.x;
  const int bm = bx >> 3, bn = bx & 7;
  const int gm0 = bm << 7, gn0 = bn << 7;
  const int tid = threadIdx.x;
  const int lane = tid & 63, wid = tid >> 6;
  const int wm = wid >> 1, wn = wid & 1;
  const int srow = tid & 127;
  const int skg0 = tid >> 7;
  const size_t xbase = ((size_t)n0 * 7200 + gm0) << 7;
  f32x4 acc[4][4] = {};
  for (int kh = 0; kh < 2; ++kh) {
    __syncthreads();
#pragma unroll
    for (int j = 0; j < 4; ++j) {
      int kg = skg0 + 2 * j;
      const float* xp = x + xbase + ((size_t)srow << 7) + kh * 64 + kg * 8;
      float4 a0 = *(const float4*)xp;
      float4 a1 = *(const float4*)(xp + 4);
      uint4 pk;
      pk.x = (uint)f2bf(a0.x) | ((uint)f2bf(a0.y) << 16);
      pk.y = (uint)f2bf(a0.z) | ((uint)f2bf(a0.w) << 16);
      pk.z = (uint)f2bf(a1.x) | ((uint)f2bf(a1.y) << 16);
      pk.w = (uint)f2bf(a1.z) | ((uint)f2bf(a1.w) << 16);
      *(uint4*)&As[kg][srow][0] = pk;
      *(uint4*)&Bs[kg][srow][0] =
          *(const uint4*)&wb[((size_t)(gn0 + srow) << 7) + kh * 64 + kg * 8];
    }
    __syncthreads();
#pragma unroll
    for (int ks = 0; ks < 2; ++ks) {
      int g = ks * 4 + (lane >> 4);
      bf16x8 af[4], bfr[4];
#pragma unroll
      for (int mi = 0; mi < 4; ++mi)
        af[mi] = *(const bf16x8*)&As[g][wm * 64 + mi * 16 + (lane & 15)][0];
#pragma unroll
      for (int ni = 0; ni < 4; ++ni)
        bfr[ni] = *(const bf16x8*)&Bs[g][wn * 64 + ni * 16 + (lane & 15)][0];
#pragma unroll
      for (int mi = 0; mi < 4; ++mi)
#pragma unroll
        for (int ni = 0; ni < 4; ++ni)
          acc[mi][ni] = __builtin_amdgcn_mfma_f32_16x16x32_bf16(
              af[mi], bfr[ni], acc[mi][ni], 0, 0, 0);
    }
  }
  const int r0 = gm0 + wm * 64;
  const int c0 = gn0 + wn * 64;
#pragma unroll
  for (int mi = 0; mi < 4; ++mi)
#pragma unroll
    for (int ni = 0; ni < 4; ++ni) {
      int col = c0 + ni * 16 + (lane & 15);
#pragma unroll
      for (int reg = 0; reg < 4; ++reg) {
        int row = r0 + mi * 16 + ((lane >> 4) << 2) + reg;
        Hc[((size_t)row << 10) + col] = f2bf(acc[mi][ni][reg]);
      }
    }
}

// ---------------- K3b: O = A.Hc + b_out + BN + leaky residual ----------------
__global__ __launch_bounds__(256) void k_attn2(
    const ushort* __restrict__ Hc, const float* __restrict__ att,
    const float* __restrict__ x, const float* __restrict__ b_out,
    const float* __restrict__ g_out, const float* __restrict__ beta_out,
    const float* __restrict__ m_out, const float* __restrict__ v_out,
    float* __restrict__ y1, int n0) {
  __shared__ float Al[3][200][32];
  const int nl = blockIdx.y;
  const int n = n0 + nl;
  const int t0 = blockIdx.x * 4;
  const int tid = threadIdx.x;
  for (int i = tid; i < 19200; i += 256) {
    int w = i / 6400;
    int rem = i - w * 6400;
    int k = rem >> 5, v = rem & 31;
    int vp = k >> 3, s = k & 7;
    float val = 0.f;
    if (v < 25) val = att[((size_t)(n * 8 + s) * 75 + (w * 25 + vp)) * 25 + v];
    Al[w][k][v] = val;
  }
  __syncthreads();
  const int og = tid & 15;
  const int vg = tid >> 4;
  float sc[8], sh[8], bb[8];
#pragma unroll
  for (int j = 0; j < 8; ++j) {
    int o = og * 8 + j;
    float s1 = g_out[o] * rsqrtf(v_out[o] + EPSF);
    sc[j] = s1;
    sh[j] = beta_out[o] - m_out[o] * s1;
    bb[j] = b_out[o];
  }
  const float* Af = &Al[0][0][0];
  for (int tt = 0; tt < 4; ++tt) {
    int t = t0 + tt;
    float acc0[8], acc1[8];
#pragma unroll
    for (int j = 0; j < 8; ++j) { acc0[j] = 0.f; acc1[j] = 0.f; }
    for (int w = 0; w < 3; ++w) {
      int tp = t + w - 1;
      if (tp < 0 || tp >= TT) continue;
      const ushort* hp = Hc + (size_t)(nl * TT + tp) * 25600 + og * 8;
      const float* ap = Af + w * 6400;
      for (int k = 0; k < 200; ++k) {
        uint4 h4 = *(const uint4*)(hp + (k << 7));
        float a0 = ap[(k << 5) + vg];
        float a1 = ap[(k << 5) + vg + 16];
        float f0 = __uint_as_float(h4.x << 16);
        float f1 = __uint_as_float(h4.x & 0xffff0000u);
        float f2 = __uint_as_float(h4.y << 16);
        float f3 = __uint_as_float(h4.y & 0xffff0000u);
        float f4 = __uint_as_float(h4.z << 16);
        float f5 = __uint_as_float(h4.z & 0xffff0000u);
        float f6 = __uint_as_float(h4.w << 16);
        float f7 = __uint_as_float(h4.w & 0xffff0000u);
        acc0[0] += a0 * f0; acc0[1] += a0 * f1; acc0[2] += a0 * f2; acc0[3] += a0 * f3;
        acc0[4] += a0 * f4; acc0[5] += a0 * f5; acc0[6] += a0 * f6; acc0[7] += a0 * f7;
        acc1[0] += a1 * f0; acc1[1] += a1 * f1; acc1[2] += a1 * f2; acc1[3] += a1 * f3;
        acc1[4] += a1 * f4; acc1[5] += a1 * f5; acc1[6] += a1 * f6; acc1[7] += a1 * f7;
      }
    }
    {
      size_t idx = ((size_t)((n * TT + t) * VV + vg) << 7) + og * 8;
      const float* xr = x + idx;
      float* yr = y1 + idx;
#pragma unroll
      for (int j = 0; j < 8; ++j) {
        float a = (acc0[j] + bb[j]) * sc[j] + sh[j];
        float r = xr[j] + a;
        yr[j] = r > 0.f ? r : 0.1f * r;
      }
    }
    if (vg < 9) {
      size_t idx = ((size_t)((n * TT + t) * VV + vg + 16) << 7) + og * 8;
      const float* xr = x + idx;
      float* yr = y1 + idx;
#pragma unroll
      for (int j = 0; j < 8; ++j) {
        float a = (acc1[j] + bb[j]) * sc[j] + sh[j];
        float r = xr[j] + a;
        yr[j] = r > 0.f ? r : 0.1f * r;
      }
    }
  }
}

// ---------------- K4: ff conv as bf16 MFMA GEMM + BN + leaky residual ----------------
// Grid 900: 128-row M-tile, N=128.
__global__ __launch_bounds__(256) void k_ffg(
    const float* __restrict__ y1, const float* __restrict__ x,
    const ushort* __restrict__ wffb, const float* __restrict__ b_ff,
    const float* __restrict__ g_ff, const float* __restrict__ beta_ff,
    const float* __restrict__ m_ff, const float* __restrict__ v_ff,
    float* __restrict__ y2) {
  __shared__ ushort As[8][128][8];
  __shared__ ushort Bs[8][128][8];
  const int gm0 = blockIdx.x << 7;
  const int tid = threadIdx.x;
  const int lane = tid & 63, wid = tid >> 6;
  const int wm = wid >> 1, wn = wid & 1;
  const int srow = tid & 127;
  const int skg0 = tid >> 7;
  f32x4 acc[4][4] = {};
  for (int kh = 0; kh < 2; ++kh) {
    __syncthreads();
#pragma unroll
    for (int j = 0; j < 4; ++j) {
      int kg = skg0 + 2 * j;
      const float* yp = y1 + (((size_t)(gm0 + srow)) << 7) + kh * 64 + kg * 8;
      float4 a0 = *(const float4*)yp;
      float4 a1 = *(const float4*)(yp + 4);
      uint4 pk;
      pk.x = (uint)f2bf(a0.x) | ((uint)f2bf(a0.y) << 16);
      pk.y = (uint)f2bf(a0.z) | ((uint)f2bf(a0.w) << 16);
      pk.z = (uint)f2bf(a1.x) | ((uint)f2bf(a1.y) << 16);
      pk.w = (uint)f2bf(a1.z) | ((uint)f2bf(a1.w) << 16);
      *(uint4*)&As[kg][srow][0] = pk;
      *(uint4*)&Bs[kg][srow][0] =
          *(const uint4*)&wffb[(srow << 7) + kh * 64 + kg * 8];
    }
    __syncthreads();
#pragma unroll
    for (int ks = 0; ks < 2; ++ks) {
      int g = ks * 4 + (lane >> 4);
      bf16x8 af[4], bfr[4];
#pragma unroll
      for (int mi = 0; mi < 4; ++mi)
        af[mi] = *(const bf16x8*)&As[g][wm * 64 + mi * 16 + (lane & 15)][0];
#pragma unroll
      for (int ni = 0; ni < 4; ++ni)
        bfr[ni] = *(const bf16x8*)&Bs[g][wn * 64 + ni * 16 + (lane & 15)][0];
#pragma unroll
      for (int mi = 0; mi < 4; ++mi)
#pragma unroll
        for (int ni = 0; ni < 4; ++ni)
          acc[mi][ni] = __builtin_amdgcn_mfma_f32_16x16x32_bf16(
              af[mi], bfr[ni], acc[mi][ni], 0, 0, 0);
    }
  }
  const int l15 = lane & 15, l4 = lane >> 4;
#pragma unroll
  for (int ni = 0; ni < 4; ++ni) {
    int o = wn * 64 + ni * 16 + l15;
    float s1 = g_ff[o] * rsqrtf(v_ff[o] + EPSF);
    float sh = beta_ff[o] - m_ff[o] * s1;
    float bb = b_ff[o];
#pragma unroll
    for (int mi = 0; mi < 4; ++mi) {
#pragma unroll
      for (int reg = 0; reg < 4; ++reg) {
        int row = gm0 + wm * 64 + mi * 16 + (l4 << 2) + reg;
        size_t idx = ((size_t)row << 7) + o;
        float a = (acc[mi][ni][reg] + bb) * s1 + sh;
        float rr = x[idx] + a;
        y2[idx] = rr > 0.f ? rr : 0.1f * rr;
      }
    }
  }
}

// ---------------- K5a: w_t (o,c,kt) -> bf16 wbt[o][kt*128+c] ----------------
__global__ __launch_bounds__(256) void k_wtb(const float* __restrict__ w_t,
                                             ushort* __restrict__ wbt) {
  int i = blockIdx.x * 256 + threadIdx.x;
  if (i < 128 * 128 * 7) {
    int o = i / 896;
    int rem = i - o * 896;
    int c = rem / 7, kt = rem - c * 7;
    wbt[o * 896 + kt * 128 + c] = f2bf(w_t[i]);
  }
}

// ---------------- K5: temporal conv as bf16 MFMA GEMM ----------------
__global__ __launch_bounds__(256, 2) void k_tconv(
    const float* __restrict__ y2, const float* __restrict__ x,
    const ushort* __restrict__ wbt, const float* __restrict__ b_t,
    const float* __restrict__ g_t, const float* __restrict__ beta_t,
    const float* __restrict__ m_t, const float* __restrict__ v_t,
    float* __restrict__ out) {
  __shared__ uint4 As[280 * 16];  // [row][16B-chunk], chunk idx ^= (row&7)
  const int n = blockIdx.y;
  const int r0 = blockIdx.x << 7;
  const int tid = threadIdx.x;
  const float* y2n = y2 + ((size_t)n * 7200 << 7);
  for (int i = tid; i < 278 * 16; i += 256) {
    int rl = i >> 4, cc = i & 15;
    int g = r0 - 75 + rl;
    uint4 pk = make_uint4(0u, 0u, 0u, 0u);
    if (g >= 0 && g < 7200) {
      const float* xp = y2n + ((size_t)g << 7) + (cc << 3);
      float4 a0 = *(const float4*)xp;
      float4 a1 = *(const float4*)(xp + 4);
      pk.x = (uint)f2bf(a0.x) | ((uint)f2bf(a0.y) << 16);
      pk.y = (uint)f2bf(a0.z) | ((uint)f2bf(a0.w) << 16);
      pk.z = (uint)f2bf(a1.x) | ((uint)f2bf(a1.y) << 16);
      pk.w = (uint)f2bf(a1.z) | ((uint)f2bf(a1.w) << 16);
    }
    As[(rl << 4) + (cc ^ (rl & 7))] = pk;
  }
  __syncthreads();
  const int lane = tid & 63, wid = tid >> 6;
  const int wm = wid >> 1, wn = wid & 1;
  const int l15 = lane & 15, l4 = lane >> 4;
  f32x4 acc[4][4] = {};
  for (int kt = 0; kt < 7; ++kt) {
    bf16x8 bfr[4][4];
#pragma unroll
    for (int ni = 0; ni < 4; ++ni) {
      const ushort* bp =
          wbt + (size_t)(wn * 64 + ni * 16 + l15) * 896 + kt * 128 + l4 * 8;
#pragma unroll
      for (int cc0 = 0; cc0 < 4; ++cc0)
        bfr[ni][cc0] = *(const bf16x8*)(bp + cc0 * 32);
    }
#pragma unroll
    for (int cc0 = 0; cc0 < 4; ++cc0) {
      bf16x8 af[4];
#pragma unroll
      for (int mi = 0; mi < 4; ++mi) {
        int rl = wm * 64 + mi * 16 + l15 + 25 * kt;
        af[mi] = *(const bf16x8*)&As[(rl << 4) + ((cc0 * 4 + l4) ^ (rl & 7))];
      }
#pragma unroll
      for (int mi = 0; mi < 4; ++mi)
#pragma unroll
        for (int ni = 0; ni < 4; ++ni)
          acc[mi][ni] = __builtin_amdgcn_mfma_f32_16x16x32_bf16(
              af[mi], bfr[ni][cc0], acc[mi][ni], 0, 0, 0);
    }
  }
#pragma unroll
  for (int ni = 0; ni < 4; ++ni) {
    int o = wn * 64 + ni * 16 + l15;
    float s1 = g_t[o] * rsqrtf(v_t[o] + EPSF);
    float sh = beta_t[o] - m_t[o] * s1;
    float bb = b_t[o];
#pragma unroll
    for (int mi = 0; mi < 4; ++mi) {
#pragma unroll
      for (int reg = 0; reg < 4; ++reg) {
        int grow = r0 + wm * 64 + mi * 16 + (l4 << 2) + reg;
        if (grow < 7200) {
          size_t idx = (((size_t)n * 7200 + grow) << 7) + o;
          float z = (acc[mi][ni][reg] + bb) * s1 + sh;
          z += y2[idx];
          z = z > 0.f ? z : 0.1f * z;
          z += x[idx];
          out[idx] = z > 0.f ? z : 0.f;
        }
      }
    }
  }
}

extern "C" void kernel_launch(void* const* d_in, const int* in_sizes, int n_in,
                              void* d_out, int out_size, void* d_ws, size_t ws_size,
                              hipStream_t stream) {
  const float* x      = (const float*)d_in[0];
  const float* w_k    = (const float*)d_in[1];
  const float* b_k    = (const float*)d_in[2];
  const float* w_q    = (const float*)d_in[3];
  const float* b_q    = (const float*)d_in[4];
  const float* alphas = (const float*)d_in[5];
  const float* att0   = (const float*)d_in[6];
  const float* w_out  = (const float*)d_in[7];
  const float* b_out  = (const float*)d_in[8];
  const float* g_out  = (const float*)d_in[9];
  const float* be_out = (const float*)d_in[10];
  const float* m_out  = (const float*)d_in[11];
  const float* v_out  = (const float*)d_in[12];
  const float* w_ff   = (const float*)d_in[13];
  const float* b_ff   = (const float*)d_in[14];
  const float* g_ff   = (const float*)d_in[15];
  const float* be_ff  = (const float*)d_in[16];
  const float* m_ff   = (const float*)d_in[17];
  const float* v_ff   = (const float*)d_in[18];
  const float* w_t    = (const float*)d_in[19];
  const float* b_t    = (const float*)d_in[20];
  const float* g_t    = (const float*)d_in[21];
  const float* be_t   = (const float*)d_in[22];
  const float* m_t    = (const float*)d_in[23];
  const float* v_t    = (const float*)d_in[24];

  float* ws = (float*)d_ws;
  // Region plan (floats), total 32,108,288 = round-1 proven footprint:
  float* qfull = ws;               // [0, 14848000)   qb bf16 -> Hc bf16 -> y2
  float* kfull = ws + 14848000;    // [.., +14745600) kb bf16 -> y1
  float* part  = ws + 29593600;    // [.., +2160000)  wb/wkqb/wffb bf16
  float* att   = ws + 31753600;    // [.., +240000)
  float* wtr   = ws + 31993600;    // [.., +114688)   wbt bf16
  ushort* qbb  = (ushort*)qfull;
  ushort* kbb  = (ushort*)kfull;
  ushort* Hc   = (ushort*)qfull;   // after k_scores consumes qb
  ushort* wb   = (ushort*)part;            // 131072 shorts
  ushort* wkqb = (ushort*)part + 131072;   //  32768 shorts
  ushort* wffb = (ushort*)part + 163840;   //  16384 shorts
  ushort* wbt  = (ushort*)wtr;
  float* y1 = kfull;
  float* y2 = qfull;
  float* outp = (float*)d_out;

  k_wcvt<<<704, 256, 0, stream>>>(w_out, w_k, w_q, w_ff, wb, wkqb, wffb);
  k_qkg<<<dim3(900, 2), 256, 0, stream>>>(x, wkqb, b_k, b_q, kbb, qbb);
  k_qkpad<<<400, 256, 0, stream>>>(b_q, qbb);
  k_scores<<<128, 512, 0, stream>>>(kbb, qbb, alphas, att0, att);
  for (int n0 = 0; n0 < 16; n0 += 4) {
    k_hgemm<<<1800, 256, 0, stream>>>(x, wb, Hc, n0);
    k_attn2<<<dim3(72, 4), 256, 0, stream>>>(Hc, att, x, b_out, g_out, be_out,
                                             m_out, v_out, y1, n0);
  }
  k_ffg<<<900, 256, 0, stream>>>(y1, x, wffb, b_ff, g_ff, be_ff, m_ff, v_ff, y2);
  k_wtb<<<448, 256, 0, stream>>>(w_t, wbt);
  k_tconv<<<dim3(57, 16), 256, 0, stream>>>(y2, x, wbt, b_t, g_t, be_t, m_t,
                                            v_t, outp);
}

// Round 9
// 567.624 us; speedup vs baseline: 9.0631x; 2.5062x over previous
//
#include <hip/hip_runtime.h>

// SSHA block. Round 9 = round 8 with the Av staging bug fixed (copy loop
// covered only half the buffer: 1300 -> 2600 uint4s) + explicit 16B alignment
// on uint4-cast LDS arrays.
//   k_attn3 per (n,t):
//     step1 (per s): Y_s[v,c] = sum_u A_s[v,u] * X[c,u]   (MFMA, K=96 pad)
//     step2 (per s): O[o,v] += sum_c W_s[o,c] * Y_s[v,c]  (MFMA, K=128)
//     epilogue: y1 = leaky(x + BN(O + b_out))
// Shapes: N=16, T=288, V=25, C=128, S=8, IC=16, W=3, U=75, TP=290.

#define NN 16
#define TT 288
#define VV 25
#define CC 128
#define SS 8
#define UU 75
#define TP 290
#define EPSF 1e-5f

typedef __attribute__((ext_vector_type(8))) short bf16x8;
typedef __attribute__((ext_vector_type(4))) float f32x4;

static __device__ __forceinline__ ushort f2bf(float f) {
  uint u = __float_as_uint(f);
  u = (u + 0x7FFFu + ((u >> 16) & 1u)) >> 16;
  return (ushort)u;
}

// ---------------- K0: weight converts ----------------
__global__ __launch_bounds__(256) void k_wcvt(
    const float* __restrict__ w_out, const float* __restrict__ w_k,
    const float* __restrict__ w_q, const float* __restrict__ w_ff,
    ushort* __restrict__ wb, ushort* __restrict__ wkqb,
    ushort* __restrict__ wffb) {
  int i = blockIdx.x * 256 + threadIdx.x;  // 180224 total
  if (i < 131072) {
    int j = i >> 7, c = i & 127;
    int s = j >> 7, o = j & 127;
    wb[i] = f2bf(w_out[(o << 10) + (s << 7) + c]);
  } else {
    int j = i - 131072;
    if (j < 16384) wkqb[j] = f2bf(w_k[j]);
    else if (j < 32768) wkqb[j] = f2bf(w_q[j - 16384]);
    else wffb[j - 32768] = f2bf(w_ff[j - 32768]);
  }
}

// ---------------- K1: k/q 1x1 convs as bf16 MFMA GEMM ----------------
__global__ __launch_bounds__(256) void k_qkg(
    const float* __restrict__ x, const ushort* __restrict__ wkqb,
    const float* __restrict__ b_k, const float* __restrict__ b_q,
    ushort* __restrict__ kb, ushort* __restrict__ qb) {
  __shared__ __align__(16) ushort As[8][128][8];
  __shared__ __align__(16) ushort Bs[8][128][8];
  const int bm = blockIdx.x, by = blockIdx.y;
  const int gm0 = bm << 7;
  const int tid = threadIdx.x;
  const int lane = tid & 63, wid = tid >> 6;
  const int wm = wid >> 1, wn = wid & 1;
  const int srow = tid & 127;
  const int skg0 = tid >> 7;
  const ushort* wsrc = wkqb + by * 16384;
  f32x4 acc[4][4] = {};
  for (int kh = 0; kh < 2; ++kh) {
    __syncthreads();
#pragma unroll
    for (int j = 0; j < 4; ++j) {
      int kg = skg0 + 2 * j;
      const float* xp = x + (((size_t)(gm0 + srow)) << 7) + kh * 64 + kg * 8;
      float4 a0 = *(const float4*)xp;
      float4 a1 = *(const float4*)(xp + 4);
      uint4 pk;
      pk.x = (uint)f2bf(a0.x) | ((uint)f2bf(a0.y) << 16);
      pk.y = (uint)f2bf(a0.z) | ((uint)f2bf(a0.w) << 16);
      pk.z = (uint)f2bf(a1.x) | ((uint)f2bf(a1.y) << 16);
      pk.w = (uint)f2bf(a1.z) | ((uint)f2bf(a1.w) << 16);
      *(uint4*)&As[kg][srow][0] = pk;
      *(uint4*)&Bs[kg][srow][0] =
          *(const uint4*)&wsrc[(srow << 7) + kh * 64 + kg * 8];
    }
    __syncthreads();
#pragma unroll
    for (int ks = 0; ks < 2; ++ks) {
      int g = ks * 4 + (lane >> 4);
      bf16x8 af[4], bfr[4];
#pragma unroll
      for (int mi = 0; mi < 4; ++mi)
        af[mi] = *(const bf16x8*)&As[g][wm * 64 + mi * 16 + (lane & 15)][0];
#pragma unroll
      for (int ni = 0; ni < 4; ++ni)
        bfr[ni] = *(const bf16x8*)&Bs[g][wn * 64 + ni * 16 + (lane & 15)][0];
#pragma unroll
      for (int mi = 0; mi < 4; ++mi)
#pragma unroll
        for (int ni = 0; ni < 4; ++ni)
          acc[mi][ni] = __builtin_amdgcn_mfma_f32_16x16x32_bf16(
              af[mi], bfr[ni], acc[mi][ni], 0, 0, 0);
    }
  }
  const int l15 = lane & 15, l4 = lane >> 4;
  const float* bias = by ? b_q : b_k;
#pragma unroll
  for (int ni = 0; ni < 4; ++ni) {
    int col = wn * 64 + ni * 16 + l15;
    float bb = bias[col];
#pragma unroll
    for (int mi = 0; mi < 4; ++mi) {
#pragma unroll
      for (int reg = 0; reg < 4; ++reg) {
        int row = gm0 + wm * 64 + mi * 16 + (l4 << 2) + reg;
        ushort val = f2bf(acc[mi][ni][reg] + bb);
        if (by == 0) {
          kb[((size_t)row << 7) + col] = val;
        } else {
          int n = row / 7200;
          qb[((size_t)(row + n * 50 + 25) << 7) + col] = val;
        }
      }
    }
  }
}

// qb pad rows (tp=0, tp=289): bias-only.
__global__ __launch_bounds__(256) void k_qkpad(const float* __restrict__ b_q,
                                               ushort* __restrict__ qb) {
  int i = blockIdx.x * 256 + threadIdx.x;  // 16*2*25*128
  int o = i & 127;
  int r = i >> 7;
  int v = r % 25;
  int e = (r / 25) & 1;
  int n = r / 50;
  int tp = e ? 289 : 0;
  qb[((size_t)((n * TP + tp) * VV + v) << 7) + o] = f2bf(b_q[o]);
}

// ---------------- K2: scores (bf16 MFMA) + fused softmax -> attTb bf16 ----------------
// attTb[n][s][v(25)][u(104)]: att^T, zero-padded u>=75.
__global__ __launch_bounds__(512) void k_scores(
    const ushort* __restrict__ kb, const ushort* __restrict__ qb,
    const float* __restrict__ alphas, const float* __restrict__ att0,
    ushort* __restrict__ attTb) {
  __shared__ float red[8][2640];  // [wave][u(80) * 33 + v(32)]
  __shared__ float scl[1875];
  __shared__ float mx[25];
  __shared__ float den[25];
  const int bx = blockIdx.x;
  const int n = bx >> 3, s = bx & 7;
  const int tid = threadIdx.x;
  const int lane = tid & 63, wid = tid >> 6;
  const int l15 = lane & 15, l4 = lane >> 4;
  const int dt = l4 >> 1;
  const int sic = s * 16 + (l4 & 1) * 8;
  int qoff[5];
#pragma unroll
  for (int tu = 0; tu < 5; ++tu) {
    int u = tu * 16 + l15;
    int w = u / 25, vp = u - w * 25;
    qoff[tu] = (w * 25 + vp) * 128 + sic;
  }
  const bool qv4 = (64 + l15) < 75;
  const bool kv1 = (16 + l15) < 25;
  int koff0 = l15 * 128 + sic;
  int koff1 = (16 + l15) * 128 + sic;
  const ushort* qbase = qb + (size_t)n * 928000 + (size_t)dt * 3200;
  const ushort* kbase = kb + (size_t)n * 921600 + (size_t)dt * 3200;
  f32x4 acc[5][2] = {};
  const bf16x8 zf = {};
  for (int kk = wid; kk < 144; kk += 8) {
    const ushort* qp = qbase + kk * 6400;
    const ushort* kp = kbase + kk * 6400;
    bf16x8 a[5], b[2];
#pragma unroll
    for (int tu = 0; tu < 4; ++tu) a[tu] = *(const bf16x8*)(qp + qoff[tu]);
    a[4] = qv4 ? *(const bf16x8*)(qp + qoff[4]) : zf;
    b[0] = *(const bf16x8*)(kp + koff0);
    b[1] = kv1 ? *(const bf16x8*)(kp + koff1) : zf;
#pragma unroll
    for (int tu = 0; tu < 5; ++tu)
#pragma unroll
      for (int tv = 0; tv < 2; ++tv)
        acc[tu][tv] = __builtin_amdgcn_mfma_f32_16x16x32_bf16(
            a[tu], b[tv], acc[tu][tv], 0, 0, 0);
  }
#pragma unroll
  for (int tu = 0; tu < 5; ++tu)
#pragma unroll
    for (int tv = 0; tv < 2; ++tv) {
#pragma unroll
      for (int reg = 0; reg < 4; ++reg)
        red[wid][(tu * 16 + l4 * 4 + reg) * 33 + tv * 16 + l15] =
            acc[tu][tv][reg];
    }
  __syncthreads();
  const float inv = 1.0f / 4608.0f;
  for (int i = tid; i < 1875; i += 512) {
    int u = i / 25, v = i - u * 25;
    float a = 0.f;
#pragma unroll
    for (int w = 0; w < 8; ++w) a += red[w][u * 33 + v];
    scl[i] = a * inv;
  }
  __syncthreads();
  if (tid < 25) {
    float m = -1e30f;
    for (int u = 0; u < 75; ++u) m = fmaxf(m, scl[u * 25 + tid]);
    float d = 0.f;
    for (int u = 0; u < 75; ++u) d += expf(scl[u * 25 + tid] - m);
    mx[tid] = m;
    den[tid] = d;
  }
  __syncthreads();
  const float alpha = alphas[s];
  ushort* op = attTb + (size_t)bx * 2600;
  for (int i = tid; i < 2600; i += 512) {
    int v = i / 104, u = i - v * 104;
    float val = 0.f;
    if (u < 75)
      val = expf(scl[u * 25 + v] - mx[v]) / den[v] * alpha +
            att0[(s * 75 + u) * 25 + v];
    op[i] = f2bf(val);
  }
}

// ---------------- K3: attention-apply + out conv (double MFMA) ----------------
// Grid (288, 16), 256 thr = 4 waves. Wave wid owns c-range (step1) and
// o-range (step2) [wid*32, wid*32+32).
__global__ __launch_bounds__(256, 2) void k_attn3(
    const float* __restrict__ x, const ushort* __restrict__ attTb,
    const ushort* __restrict__ wb, const float* __restrict__ b_out,
    const float* __restrict__ g_out, const float* __restrict__ beta_out,
    const float* __restrict__ m_out, const float* __restrict__ v_out,
    float* __restrict__ y1) {
  __shared__ __align__(16) ushort Xt[128 * 104];     // [c][u], zero-pad u>=75
  __shared__ __align__(16) ushort Av[8 * 25 * 104];  // [s][v][u]
  __shared__ __align__(16) ushort Yl[32 * 136];      // [v][c] bf16 roundtrip
  const int t = blockIdx.x, n = blockIdx.y;
  const int tid = threadIdx.x;
  // stage Av: 8*25*104 shorts = 41600 B = 2600 uint4
  {
    const uint4* src = (const uint4*)(attTb + (size_t)n * 20800);
    uint4* dst = (uint4*)Av;
    for (int i = tid; i < 2600; i += 256) dst[i] = src[i];
  }
  // stage Xt[c][u]: u = w*25+vp -> x row (n, t+w-1, vp)
  for (int i = tid; i < 128 * 104; i += 256) {
    int u = i >> 7, c = i & 127;
    float val = 0.f;
    if (u < 75) {
      int w = u / 25, vp = u - w * 25;
      int tr = t + w - 1;
      if (tr >= 0 && tr < TT)
        val = x[(((size_t)(n * TT + tr) * VV + vp)) * 128 + c];
    }
    Xt[c * 104 + u] = f2bf(val);
  }
  __syncthreads();
  const int lane = tid & 63, wid = tid >> 6;
  const int l15 = lane & 15, l4 = lane >> 4;
  const bf16x8 zf = {};
  f32x4 accO[2][2] = {};  // [mi(o)][nj(v)]
  for (int s = 0; s < 8; ++s) {
    // ---- step 1: Y_s[v, c] for this wave's c-range ----
    f32x4 accY[2][2] = {};  // [mi(v)][nj(c)]
    const ushort* AvS = Av + s * 2600;
#pragma unroll
    for (int ks = 0; ks < 3; ++ks) {
      int u0 = ks * 32 + l4 * 8;
      bf16x8 av0 = *(const bf16x8*)&AvS[l15 * 104 + u0];
      int r1 = 16 + l15;
      bf16x8 av1 = *(const bf16x8*)&AvS[(r1 <= 24 ? r1 : 24) * 104 + u0];
      if (l15 > 8) av1 = zf;  // v >= 25 -> zero row
      bf16x8 xb0 = *(const bf16x8*)&Xt[(wid * 32 + l15) * 104 + u0];
      bf16x8 xb1 = *(const bf16x8*)&Xt[(wid * 32 + 16 + l15) * 104 + u0];
      accY[0][0] = __builtin_amdgcn_mfma_f32_16x16x32_bf16(av0, xb0, accY[0][0], 0, 0, 0);
      accY[0][1] = __builtin_amdgcn_mfma_f32_16x16x32_bf16(av0, xb1, accY[0][1], 0, 0, 0);
      accY[1][0] = __builtin_amdgcn_mfma_f32_16x16x32_bf16(av1, xb0, accY[1][0], 0, 0, 0);
      accY[1][1] = __builtin_amdgcn_mfma_f32_16x16x32_bf16(av1, xb1, accY[1][1], 0, 0, 0);
    }
    __syncthreads();  // previous step-2 readers done with Yl
#pragma unroll
    for (int mi = 0; mi < 2; ++mi)
#pragma unroll
      for (int nj = 0; nj < 2; ++nj)
#pragma unroll
        for (int reg = 0; reg < 4; ++reg)
          Yl[(mi * 16 + l4 * 4 + reg) * 136 + wid * 32 + nj * 16 + l15] =
              f2bf(accY[mi][nj][reg]);
    __syncthreads();
    // ---- step 2: O[o, v] += W_s . Y_s for this wave's o-range ----
    const ushort* wS = wb + s * 16384;
#pragma unroll
    for (int kc = 0; kc < 4; ++kc) {
      int c0 = kc * 32 + l4 * 8;
      bf16x8 wf0 = *(const bf16x8*)&wS[(wid * 32 + l15) * 128 + c0];
      bf16x8 wf1 = *(const bf16x8*)&wS[(wid * 32 + 16 + l15) * 128 + c0];
      bf16x8 yb0 = *(const bf16x8*)&Yl[l15 * 136 + c0];
      bf16x8 yb1 = *(const bf16x8*)&Yl[(16 + l15) * 136 + c0];
      accO[0][0] = __builtin_amdgcn_mfma_f32_16x16x32_bf16(wf0, yb0, accO[0][0], 0, 0, 0);
      accO[0][1] = __builtin_amdgcn_mfma_f32_16x16x32_bf16(wf0, yb1, accO[0][1], 0, 0, 0);
      accO[1][0] = __builtin_amdgcn_mfma_f32_16x16x32_bf16(wf1, yb0, accO[1][0], 0, 0, 0);
      accO[1][1] = __builtin_amdgcn_mfma_f32_16x16x32_bf16(wf1, yb1, accO[1][1], 0, 0, 0);
    }
  }
  // ---- epilogue: BN + leaky(x + .) ----
#pragma unroll
  for (int nj = 0; nj < 2; ++nj) {
    int v = nj * 16 + l15;
    if (v < 25) {
      size_t rowbase = (((size_t)(n * TT + t) * VV + v)) * 128 + wid * 32;
#pragma unroll
      for (int mi = 0; mi < 2; ++mi) {
        int ob = mi * 16 + (l4 << 2);  // o offset within wave range
        int og = wid * 32 + ob;
        float4 gg = *(const float4*)&g_out[og];
        float4 vv = *(const float4*)&v_out[og];
        float4 mm = *(const float4*)&m_out[og];
        float4 be = *(const float4*)&beta_out[og];
        float4 bo = *(const float4*)&b_out[og];
        float4 xv = *(const float4*)&x[rowbase + ob];
        float4 r;
        float s1, a;
        s1 = gg.x * rsqrtf(vv.x + EPSF);
        a = (accO[mi][nj][0] + bo.x) * s1 + (be.x - mm.x * s1) + xv.x;
        r.x = a > 0.f ? a : 0.1f * a;
        s1 = gg.y * rsqrtf(vv.y + EPSF);
        a = (accO[mi][nj][1] + bo.y) * s1 + (be.y - mm.y * s1) + xv.y;
        r.y = a > 0.f ? a : 0.1f * a;
        s1 = gg.z * rsqrtf(vv.z + EPSF);
        a = (accO[mi][nj][2] + bo.z) * s1 + (be.z - mm.z * s1) + xv.z;
        r.z = a > 0.f ? a : 0.1f * a;
        s1 = gg.w * rsqrtf(vv.w + EPSF);
        a = (accO[mi][nj][3] + bo.w) * s1 + (be.w - mm.w * s1) + xv.w;
        r.w = a > 0.f ? a : 0.1f * a;
        *(float4*)&y1[rowbase + ob] = r;
      }
    }
  }
}

// ---------------- K4: ff conv as bf16 MFMA GEMM + BN + leaky residual ----------------
__global__ __launch_bounds__(256) void k_ffg(
    const float* __restrict__ y1, const float* __restrict__ x,
    const ushort* __restrict__ wffb, const float* __restrict__ b_ff,
    const float* __restrict__ g_ff, const float* __restrict__ beta_ff,
    const float* __restrict__ m_ff, const float* __restrict__ v_ff,
    float* __restrict__ y2) {
  __shared__ __align__(16) ushort As[8][128][8];
  __shared__ __align__(16) ushort Bs[8][128][8];
  const int gm0 = blockIdx.x << 7;
  const int tid = threadIdx.x;
  const int lane = tid & 63, wid = tid >> 6;
  const int wm = wid >> 1, wn = wid & 1;
  const int srow = tid & 127;
  const int skg0 = tid >> 7;
  f32x4 acc[4][4] = {};
  for (int kh = 0; kh < 2; ++kh) {
    __syncthreads();
#pragma unroll
    for (int j = 0; j < 4; ++j) {
      int kg = skg0 + 2 * j;
      const float* yp = y1 + (((size_t)(gm0 + srow)) << 7) + kh * 64 + kg * 8;
      float4 a0 = *(const float4*)yp;
      float4 a1 = *(const float4*)(yp + 4);
      uint4 pk;
      pk.x = (uint)f2bf(a0.x) | ((uint)f2bf(a0.y) << 16);
      pk.y = (uint)f2bf(a0.z) | ((uint)f2bf(a0.w) << 16);
      pk.z = (uint)f2bf(a1.x) | ((uint)f2bf(a1.y) << 16);
      pk.w = (uint)f2bf(a1.z) | ((uint)f2bf(a1.w) << 16);
      *(uint4*)&As[kg][srow][0] = pk;
      *(uint4*)&Bs[kg][srow][0] =
          *(const uint4*)&wffb[(srow << 7) + kh * 64 + kg * 8];
    }
    __syncthreads();
#pragma unroll
    for (int ks = 0; ks < 2; ++ks) {
      int g = ks * 4 + (lane >> 4);
      bf16x8 af[4], bfr[4];
#pragma unroll
      for (int mi = 0; mi < 4; ++mi)
        af[mi] = *(const bf16x8*)&As[g][wm * 64 + mi * 16 + (lane & 15)][0];
#pragma unroll
      for (int ni = 0; ni < 4; ++ni)
        bfr[ni] = *(const bf16x8*)&Bs[g][wn * 64 + ni * 16 + (lane & 15)][0];
#pragma unroll
      for (int mi = 0; mi < 4; ++mi)
#pragma unroll
        for (int ni = 0; ni < 4; ++ni)
          acc[mi][ni] = __builtin_amdgcn_mfma_f32_16x16x32_bf16(
              af[mi], bfr[ni], acc[mi][ni], 0, 0, 0);
    }
  }
  const int l15 = lane & 15, l4 = lane >> 4;
#pragma unroll
  for (int ni = 0; ni < 4; ++ni) {
    int o = wn * 64 + ni * 16 + l15;
    float s1 = g_ff[o] * rsqrtf(v_ff[o] + EPSF);
    float sh = beta_ff[o] - m_ff[o] * s1;
    float bb = b_ff[o];
#pragma unroll
    for (int mi = 0; mi < 4; ++mi) {
#pragma unroll
      for (int reg = 0; reg < 4; ++reg) {
        int row = gm0 + wm * 64 + mi * 16 + (l4 << 2) + reg;
        size_t idx = ((size_t)row << 7) + o;
        float a = (acc[mi][ni][reg] + bb) * s1 + sh;
        float rr = x[idx] + a;
        y2[idx] = rr > 0.f ? rr : 0.1f * rr;
      }
    }
  }
}

// ---------------- K5a: w_t (o,c,kt) -> bf16 wbt[o][kt*128+c] ----------------
__global__ __launch_bounds__(256) void k_wtb(const float* __restrict__ w_t,
                                             ushort* __restrict__ wbt) {
  int i = blockIdx.x * 256 + threadIdx.x;
  if (i < 128 * 128 * 7) {
    int o = i / 896;
    int rem = i - o * 896;
    int c = rem / 7, kt = rem - c * 7;
    wbt[o * 896 + kt * 128 + c] = f2bf(w_t[i]);
  }
}

// ---------------- K5: temporal conv as bf16 MFMA GEMM ----------------
__global__ __launch_bounds__(256, 2) void k_tconv(
    const float* __restrict__ y2, const float* __restrict__ x,
    const ushort* __restrict__ wbt, const float* __restrict__ b_t,
    const float* __restrict__ g_t, const float* __restrict__ beta_t,
    const float* __restrict__ m_t, const float* __restrict__ v_t,
    float* __restrict__ out) {
  __shared__ __align__(16) uint4 As[280 * 16];  // [row][16B-chunk], ^(row&7)
  const int n = blockIdx.y;
  const int r0 = blockIdx.x << 7;
  const int tid = threadIdx.x;
  const float* y2n = y2 + ((size_t)n * 7200 << 7);
  for (int i = tid; i < 278 * 16; i += 256) {
    int rl = i >> 4, cc = i & 15;
    int g = r0 - 75 + rl;
    uint4 pk = make_uint4(0u, 0u, 0u, 0u);
    if (g >= 0 && g < 7200) {
      const float* xp = y2n + ((size_t)g << 7) + (cc << 3);
      float4 a0 = *(const float4*)xp;
      float4 a1 = *(const float4*)(xp + 4);
      pk.x = (uint)f2bf(a0.x) | ((uint)f2bf(a0.y) << 16);
      pk.y = (uint)f2bf(a0.z) | ((uint)f2bf(a0.w) << 16);
      pk.z = (uint)f2bf(a1.x) | ((uint)f2bf(a1.y) << 16);
      pk.w = (uint)f2bf(a1.z) | ((uint)f2bf(a1.w) << 16);
    }
    As[(rl << 4) + (cc ^ (rl & 7))] = pk;
  }
  __syncthreads();
  const int lane = tid & 63, wid = tid >> 6;
  const int wm = wid >> 1, wn = wid & 1;
  const int l15 = lane & 15, l4 = lane >> 4;
  f32x4 acc[4][4] = {};
  for (int kt = 0; kt < 7; ++kt) {
    bf16x8 bfr[4][4];
#pragma unroll
    for (int ni = 0; ni < 4; ++ni) {
      const ushort* bp =
          wbt + (size_t)(wn * 64 + ni * 16 + l15) * 896 + kt * 128 + l4 * 8;
#pragma unroll
      for (int cc0 = 0; cc0 < 4; ++cc0)
        bfr[ni][cc0] = *(const bf16x8*)(bp + cc0 * 32);
    }
#pragma unroll
    for (int cc0 = 0; cc0 < 4; ++cc0) {
      bf16x8 af[4];
#pragma unroll
      for (int mi = 0; mi < 4; ++mi) {
        int rl = wm * 64 + mi * 16 + l15 + 25 * kt;
        af[mi] = *(const bf16x8*)&As[(rl << 4) + ((cc0 * 4 + l4) ^ (rl & 7))];
      }
#pragma unroll
      for (int mi = 0; mi < 4; ++mi)
#pragma unroll
        for (int ni = 0; ni < 4; ++ni)
          acc[mi][ni] = __builtin_amdgcn_mfma_f32_16x16x32_bf16(
              af[mi], bfr[ni][cc0], acc[mi][ni], 0, 0, 0);
    }
  }
#pragma unroll
  for (int ni = 0; ni < 4; ++ni) {
    int o = wn * 64 + ni * 16 + l15;
    float s1 = g_t[o] * rsqrtf(v_t[o] + EPSF);
    float sh = beta_t[o] - m_t[o] * s1;
    float bb = b_t[o];
#pragma unroll
    for (int mi = 0; mi < 4; ++mi) {
#pragma unroll
      for (int reg = 0; reg < 4; ++reg) {
        int grow = r0 + wm * 64 + mi * 16 + (l4 << 2) + reg;
        if (grow < 7200) {
          size_t idx = (((size_t)n * 7200 + grow) << 7) + o;
          float z = (acc[mi][ni][reg] + bb) * s1 + sh;
          z += y2[idx];
          z = z > 0.f ? z : 0.1f * z;
          z += x[idx];
          out[idx] = z > 0.f ? z : 0.f;
        }
      }
    }
  }
}

extern "C" void kernel_launch(void* const* d_in, const int* in_sizes, int n_in,
                              void* d_out, int out_size, void* d_ws, size_t ws_size,
                              hipStream_t stream) {
  const float* x      = (const float*)d_in[0];
  const float* w_k    = (const float*)d_in[1];
  const float* b_k    = (const float*)d_in[2];
  const float* w_q    = (const float*)d_in[3];
  const float* b_q    = (const float*)d_in[4];
  const float* alphas = (const float*)d_in[5];
  const float* att0   = (const float*)d_in[6];
  const float* w_out  = (const float*)d_in[7];
  const float* b_out  = (const float*)d_in[8];
  const float* g_out  = (const float*)d_in[9];
  const float* be_out = (const float*)d_in[10];
  const float* m_out  = (const float*)d_in[11];
  const float* v_out  = (const float*)d_in[12];
  const float* w_ff   = (const float*)d_in[13];
  const float* b_ff   = (const float*)d_in[14];
  const float* g_ff   = (const float*)d_in[15];
  const float* be_ff  = (const float*)d_in[16];
  const float* m_ff   = (const float*)d_in[17];
  const float* v_ff   = (const float*)d_in[18];
  const float* w_t    = (const float*)d_in[19];
  const float* b_t    = (const float*)d_in[20];
  const float* g_t    = (const float*)d_in[21];
  const float* be_t   = (const float*)d_in[22];
  const float* m_t    = (const float*)d_in[23];
  const float* v_t    = (const float*)d_in[24];

  float* ws = (float*)d_ws;
  // Region plan (floats), total 32,108,288 = round-1 proven footprint:
  float* qfull = ws;               // [0, 14848000)   qb bf16 -> y2
  float* kfull = ws + 14848000;    // [.., +14745600) kb bf16 -> y1
  float* part  = ws + 29593600;    // [.., +2160000)  wb/wkqb/wffb bf16
  float* attr  = ws + 31753600;    // [.., +240000)   attTb bf16 (332800 sh)
  float* wtr   = ws + 31993600;    // [.., +114688)   wbt bf16
  ushort* qbb   = (ushort*)qfull;
  ushort* kbb   = (ushort*)kfull;
  ushort* wb    = (ushort*)part;            // 131072 shorts
  ushort* wkqb  = (ushort*)part + 131072;   //  32768 shorts
  ushort* wffb  = (ushort*)part + 163840;   //  16384 shorts
  ushort* attTb = (ushort*)attr;
  ushort* wbt   = (ushort*)wtr;
  float* y1 = kfull;
  float* y2 = qfull;
  float* outp = (float*)d_out;

  k_wcvt<<<704, 256, 0, stream>>>(w_out, w_k, w_q, w_ff, wb, wkqb, wffb);
  k_qkg<<<dim3(900, 2), 256, 0, stream>>>(x, wkqb, b_k, b_q, kbb, qbb);
  k_qkpad<<<400, 256, 0, stream>>>(b_q, qbb);
  k_scores<<<128, 512, 0, stream>>>(kbb, qbb, alphas, att0, attTb);
  k_attn3<<<dim3(288, 16), 256, 0, stream>>>(x, attTb, wb, b_out, g_out,
                                             be_out, m_out, v_out, y1);
  k_ffg<<<900, 256, 0, stream>>>(y1, x, wffb, b_ff, g_ff, be_ff, m_ff, v_ff, y2);
  k_wtb<<<448, 256, 0, stream>>>(w_t, wbt);
  k_tconv<<<dim3(57, 16), 256, 0, stream>>>(y2, x, wbt, b_t, g_t, be_t, m_t,
                                            v_t, outp);
}